// Round 11
// baseline (3797.131 us; speedup 1.0000x reference)
//
#include <hip/hip_runtime.h>
#include <hip/hip_bf16.h>

#define DIM   4096
#define NH    32
#define NKV   8
#define HD    128
#define FFNH  11008
#define BATCH 4
#define SEQ   2048
#define MTOT  (BATCH*SEQ)   // 8192

using bf16x8_t = __attribute__((ext_vector_type(8))) short;
using f32x4_t  = __attribute__((ext_vector_type(4))) float;
using u16x4_t  = __attribute__((ext_vector_type(4))) unsigned short;

typedef const __attribute__((address_space(1))) unsigned int GlbU32;
typedef __attribute__((address_space(3))) unsigned int LdsU32;

__device__ __forceinline__ unsigned short f2b(float f) {
  union { float f; unsigned int u; } v; v.f = f;
  return (unsigned short)((v.u + 0x7fffu + ((v.u >> 16) & 1u)) >> 16);
}
__device__ __forceinline__ float b2f(unsigned short b) {
  union { unsigned int u; float f; } v; v.u = ((unsigned int)b) << 16;
  return v.f;
}
__device__ __forceinline__ void gll16(const void* g, void* l) {
  __builtin_amdgcn_global_load_lds((GlbU32*)g, (LdsU32*)l, 16, 0, 0);
}

#define VM8  asm volatile("s_waitcnt vmcnt(8)" ::: "memory")
#define VM4M asm volatile("s_waitcnt vmcnt(4)" ::: "memory")
#define VM0  asm volatile("s_waitcnt vmcnt(0)" ::: "memory")

// ---------------- fp32 -> bf16 bulk convert ----------------
__global__ __launch_bounds__(256)
void cvt_bf16_k(const float* __restrict__ src, unsigned short* __restrict__ dst)
{
  const size_t i = ((size_t)blockIdx.x * 256 + threadIdx.x) * 8;
  const float4 a = *(const float4*)&src[i];
  const float4 b = *(const float4*)&src[i + 4];
  union { int4 v; unsigned short u[8]; } o;
  o.u[0] = f2b(a.x); o.u[1] = f2b(a.y); o.u[2] = f2b(a.z); o.u[3] = f2b(a.w);
  o.u[4] = f2b(b.x); o.u[5] = f2b(b.y); o.u[6] = f2b(b.z); o.u[7] = f2b(b.w);
  *(int4*)&dst[i] = o.v;
}

// ---------------- RMSNorm: fp32 in -> bf16 out ----------------
__global__ __launch_bounds__(256)
void rmsnorm_k(const float* __restrict__ X, const float* __restrict__ gamma,
               unsigned short* __restrict__ Y)
{
  const int row = blockIdx.x, t = threadIdx.x;
  const float* xr = X + (size_t)row * DIM;
  float4 v[4];
  float ss = 0.f;
#pragma unroll
  for (int p = 0; p < 4; ++p) {
    v[p] = *(const float4*)&xr[p * 1024 + t * 4];
    ss += v[p].x*v[p].x + v[p].y*v[p].y + v[p].z*v[p].z + v[p].w*v[p].w;
  }
#pragma unroll
  for (int off = 32; off >= 1; off >>= 1) ss += __shfl_xor(ss, off, 64);
  __shared__ float red[4];
  if ((t & 63) == 0) red[t >> 6] = ss;
  __syncthreads();
  const float tot = red[0] + red[1] + red[2] + red[3];
  const float rn = rsqrtf(tot * (1.f / DIM) + 1e-6f);
  unsigned short* yr = Y + (size_t)row * DIM;
#pragma unroll
  for (int p = 0; p < 4; ++p) {
    const float4 gv = *(const float4*)&gamma[p * 1024 + t * 4];
    short4 o;
    o.x = (short)f2b(v[p].x * gv.x * rn);
    o.y = (short)f2b(v[p].y * gv.y * rn);
    o.z = (short)f2b(v[p].z * gv.z * rn);
    o.w = (short)f2b(v[p].w * gv.w * rn);
    *(short4*)&yr[p * 1024 + t * 4] = o;
  }
}

// ======================= 256x256 GEMM, 2 barriers / K=32 phase (round-6 proven) ===========
// MODE 0 additionally fuses RoPE into the Q/K epilogue (partner via shfl_xor(1)).
template<int MODE>
__global__ __launch_bounds__(512)
void gemm256(const unsigned short* __restrict__ A,
             const unsigned short* __restrict__ W,
             const unsigned short* __restrict__ W3p,
             const float* __restrict__ bias,
             const float* res,
             float* outF,
             unsigned short* __restrict__ outH,
             const unsigned short* __restrict__ wkp,
             const unsigned short* __restrict__ wvp,
             const float* __restrict__ bkp,
             const float* __restrict__ bvp,
             unsigned short* __restrict__ okp,
             unsigned short* __restrict__ ovp,
             const float* __restrict__ freqs,
             int K)
{
  __shared__ __align__(16) char smem[131072];
  const int t = threadIdx.x, lane = t & 63, wid = t >> 6;
  const int wr = wid >> 2, wc = wid & 3;
  const int G = gridDim.x, bid = blockIdx.x;
  const int wg = (bid & 7) * (G >> 3) + (bid >> 3);   // XCD-chunked
  const int NBN = G >> 5;                             // NBM = 32 (M = 8192)
  const int span = NBN << 3;                          // TMG = 8
  const int tmg = wg / span, rr = wg - tmg * span;
  const int tn = rr >> 3, tm = (tmg << 3) + (rr & 7);
  const int m0 = tm << 8;
  const int NSUB = K >> 5;

  const unsigned short *P1, *P2;
  const float* bp = bias;
  unsigned short* oh = outH;
  const float* ropef = nullptr;
  int nloc = 0, colsN = 4096;
  if constexpr (MODE == 0) {
    const int n0 = tn << 8;
    if (n0 < 4096)      { nloc = n0;        P1 = W   + (size_t)nloc * K; bp = bias; oh = outH; colsN = 4096; ropef = freqs; }
    else if (n0 < 5120) { nloc = n0 - 4096; P1 = wkp + (size_t)nloc * K; bp = bkp;  oh = okp;  colsN = 1024; ropef = freqs; }
    else                { nloc = n0 - 5120; P1 = wvp + (size_t)nloc * K; bp = bvp;  oh = ovp;  colsN = 1024; }
    P2 = P1 + (size_t)128 * K;
  } else if constexpr (MODE == 3) {
    const int n0w = tn << 7;
    P1 = W   + (size_t)n0w * K;
    P2 = W3p + (size_t)n0w * K;
    nloc = n0w;
  } else {
    const int n0 = tn << 8;
    P1 = W + (size_t)n0 * K;
    P2 = P1 + (size_t)128 * K;
    nloc = n0;
  }

  const int r0 = t >> 2, gg = t & 3;
  const int gsw = gg ^ ((r0 >> 1) & 3);

  auto stA = [&](int sig) {
    if (sig < NSUB) {
      const int slot = sig & 3;
      gll16(A + (size_t)(m0 + r0) * K + sig * 32 + gsw * 8,
            smem + slot * 16384 + wid * 1024);
      gll16(A + (size_t)(m0 + 128 + r0) * K + sig * 32 + gsw * 8,
            smem + slot * 16384 + 8192 + wid * 1024);
    }
  };
  auto stB = [&](int sig) {
    if (sig < NSUB) {
      const int slot = sig & 3;
      gll16(P1 + (size_t)r0 * K + sig * 32 + gsw * 8,
            smem + 65536 + slot * 16384 + wid * 1024);
      gll16(P2 + (size_t)r0 * K + sig * 32 + gsw * 8,
            smem + 65536 + slot * 16384 + 8192 + wid * 1024);
    }
  };
  auto rdA = [&](int slot, int mo) -> bf16x8_t {
    const int lrow = wr * 128 + mo + (lane & 15);
    const int g = (lane >> 4) ^ ((lrow >> 1) & 3);
    return *(const bf16x8_t*)(smem + slot * 16384 + lrow * 64 + g * 16);
  };
  auto rdB = [&](int slot, int nf) -> bf16x8_t {
    const int brow = wc * 64 + nf * 16 + (lane & 15);
    const int g = (lane >> 4) ^ ((brow >> 1) & 3);
    return *(const bf16x8_t*)(smem + 65536 + slot * 16384 + brow * 64 + g * 16);
  };

  f32x4_t acc[8][4];
#pragma unroll
  for (int i = 0; i < 8; ++i)
#pragma unroll
    for (int j = 0; j < 4; ++j) acc[i][j] = (f32x4_t)0.f;

  stA(0); stB(0); stA(1); stB(1); stA(2); stB(2);
  VM8;
  __builtin_amdgcn_s_barrier();

  for (int p = 0; p < NSUB; ++p) {
    const int slot = p & 3;
    bf16x8_t bfv[4], afv[8];
#pragma unroll
    for (int n = 0; n < 4; ++n) bfv[n] = rdB(slot, n);
#pragma unroll
    for (int m = 0; m < 8; ++m) afv[m] = rdA(slot, m * 16);
    stA(p + 3); stB(p + 3);
    __builtin_amdgcn_s_setprio(1);
#pragma unroll
    for (int m = 0; m < 8; ++m)
#pragma unroll
      for (int n = 0; n < 4; ++n)
        acc[m][n] = __builtin_amdgcn_mfma_f32_16x16x32_bf16(afv[m], bfv[n], acc[m][n], 0, 0, 0);
    __builtin_amdgcn_s_setprio(0);
    if (p < NSUB - 3)      { VM8; }
    else if (p == NSUB - 3){ VM4M; }
    else                   { VM0; }
    __builtin_amdgcn_s_barrier();
  }

  if constexpr (MODE == 0) {
#pragma unroll
    for (int ni = 0; ni < 4; ++ni) {
      const int col = nloc + wc * 64 + ni * 16 + (lane & 15);
      const float bv = bp[col];
      const int cin = col & 127;
#pragma unroll
      for (int mi = 0; mi < 8; ++mi) {
#pragma unroll
        for (int r = 0; r < 4; ++r) {
          const int row = m0 + wr * 128 + mi * 16 + (lane >> 4) * 4 + r;
          float vv = acc[mi][ni][r] + bv;
          if (ropef) {
            const float po = __shfl_xor(vv, 1, 64);
            const float fq = ropef[(row & (SEQ - 1)) * 64 + (cin >> 1)];
            float sn, cs;
            __sincosf(fq, &sn, &cs);
            vv = (col & 1) ? (po * sn + vv * cs) : (vv * cs - po * sn);
          }
          oh[(size_t)row * colsN + col] = f2b(vv);
        }
      }
    }
  } else if constexpr (MODE == 1 || MODE == 2) {
#pragma unroll
    for (int ni = 0; ni < 4; ++ni) {
      const int col = nloc + wc * 64 + ni * 16 + (lane & 15);
      float bv = 0.f;
      if constexpr (MODE == 1) bv = bias[col];
#pragma unroll
      for (int mi = 0; mi < 8; ++mi)
#pragma unroll
        for (int r = 0; r < 4; ++r) {
          const int row = m0 + wr * 128 + mi * 16 + (lane >> 4) * 4 + r;
          const size_t idx = (size_t)row * 4096 + col;
          outF[idx] = acc[mi][ni][r] + bv + res[idx];
        }
    }
  } else {
    if (wc >= 2) {
      const int widx = wr * 2 + (wc - 2);
#pragma unroll
      for (int ni = 0; ni < 4; ++ni)
#pragma unroll
        for (int mi = 0; mi < 8; ++mi)
#pragma unroll
          for (int r = 0; r < 4; ++r) {
            const int lrow = mi * 16 + (lane >> 4) * 4 + r;
            const int ncol = ni * 16 + (lane & 15);
            *(unsigned short*)(smem + widx * 16384 + lrow * 128 + ncol * 2) =
                f2b(acc[mi][ni][r]);
          }
    }
    __syncthreads();
    if (wc < 2) {
      const int widx = wr * 2 + wc;
#pragma unroll
      for (int ni = 0; ni < 4; ++ni)
#pragma unroll
        for (int mi = 0; mi < 8; ++mi)
#pragma unroll
          for (int r = 0; r < 4; ++r) {
            const int lrow = mi * 16 + (lane >> 4) * 4 + r;
            const int ncol = ni * 16 + (lane & 15);
            const float s3 = b2f(*(const unsigned short*)(smem + widx * 16384 + lrow * 128 + ncol * 2));
            const float s1 = acc[mi][ni][r];
            const float sig = 1.f / (1.f + __expf(-s1));
            const int row = m0 + wr * 128 + lrow;
            outH[(size_t)row * FFNH + nloc + wc * 64 + ncol] = f2b(s1 * sig * s3);
          }
    }
  }
}

// ---------------- Flash attention (non-causal, GQA 4:1) ----------------
// Swapped QK^T (lane owns one q), Q in registers, distance-2 pair prefetch.
// V: vectorized transpose — per thread 4x16B loads, in-reg transpose, 8 ds_write_b64
// into stride-68 rows (bank-spread); PV B-frags read as 2x b64. Ps split (no WAR).
__global__ __launch_bounds__(256)
void attn_k(const unsigned short* __restrict__ Q, const unsigned short* __restrict__ Kb,
            const unsigned short* __restrict__ Vb, unsigned short* __restrict__ O)
{
  __shared__ unsigned short Ks[4][4096];   // ring-4 K tiles (32x128 swizzled) 32 KB
  __shared__ unsigned short VtU[128 * 68]; // V^T pair, stride-68 rows      17 KB
  __shared__ unsigned short Ps[2][2560];   // per-wave 16q x 32kv, stride 40  10 KB
  const int t = threadIdx.x, lane = t & 63, wid = t >> 6;
  const int bx = blockIdx.x;
  const int qt = bx & 31, h = (bx >> 5) & 31, b = bx >> 10;
  const int kvh = h >> 2;
  const float rs = 0.08838834764831845f;   // 1/sqrt(128)
  constexpr int NPAIR = SEQ / 64;          // 32

  const int q0 = wid * 16;
  const int qc = lane & 15;                // this lane's q (softmax layout)

  // Q fragments in registers: B-operand of swapped QK^T
  bf16x8_t qf[4];
  {
    const unsigned short* qrow = Q + (size_t)(b * SEQ + qt * 64 + q0 + qc) * DIM
                                   + h * HD + (lane >> 4) * 8;
#pragma unroll
    for (int ks = 0; ks < 4; ++ks) qf[ks] = *(const bf16x8_t*)(qrow + ks * 32);
  }

  const unsigned short* Kbase = Kb + (size_t)(b * SEQ) * (NKV * HD) + kvh * HD;
  const unsigned short* Vbase = Vb + (size_t)(b * SEQ) * (NKV * HD) + kvh * HD;

  auto stK = [&](int kt, int slot) {
#pragma unroll
    for (int oo = 0; oo < 2; ++oo) {
      const int o = wid * 2 + oo;
      const int row = o * 4 + (lane >> 4);
      const int gl  = (lane & 15) ^ (row & 7);
      gll16(Kbase + (size_t)(kt * 32 + row) * (NKV * HD) + gl * 8, &Ks[slot][o * 512]);
    }
  };

  // V path: thread owns d-chunk c8 (8 dims) x kv-quad qq (4 kv of the 64-kv pair)
  const int c8 = t & 15, qq = t >> 4;
  const int d0 = c8 * 8, kv0 = qq * 4;
  auto ldV = [&](int kp, int4& w0, int4& w1, int4& w2, int4& w3) {
    const unsigned short* gp = Vbase + (size_t)(kp * 64 + kv0) * (NKV * HD) + d0;
    w0 = *(const int4*)gp;
    w1 = *(const int4*)(gp + NKV * HD);
    w2 = *(const int4*)(gp + 2 * NKV * HD);
    w3 = *(const int4*)(gp + 3 * NKV * HD);
  };
  auto wrV = [&](int4 w0, int4 w1, int4 w2, int4 w3) {
    union U { int4 v; unsigned short u[8]; };
    U a, bb, c, d;
    a.v = w0; bb.v = w1; c.v = w2; d.v = w3;
    const int cbase = (qq >> 1) * 8 + (qq & 1) * 4;
#pragma unroll
    for (int j = 0; j < 8; ++j) {
      u16x4_t w = { a.u[j], bb.u[j], c.u[j], d.u[j] };
      *(u16x4_t*)&VtU[(d0 + j) * 68 + cbase] = w;
    }
  };
  auto rdVf = [&](int tile, int nt2) -> bf16x8_t {
    const int d = nt2 * 16 + (lane & 15);
    const int c = (lane >> 4) + tile * 4;
    const unsigned short* pp = &VtU[d * 68 + c * 8];
    union { bf16x8_t v; u16x4_t h[2]; } u;
    u.h[0] = *(const u16x4_t*)pp;
    u.h[1] = *(const u16x4_t*)(pp + 4);
    return u.v;
  };

  // prologue: pairs 0 (K slots 0,1) and 1 (K slots 2,3)
  int4 a0, a1, a2, a3, b0, b1, b2, b3;
  stK(0, 0); stK(1, 1); ldV(0, a0, a1, a2, a3);
  stK(2, 2); stK(3, 3); ldV(1, b0, b1, b2, b3);

  f32x4_t oa[8];
#pragma unroll
  for (int i = 0; i < 8; ++i) oa[i] = (f32x4_t)0.f;
  float mrun = -1e30f, lrun = 0.f;         // per-lane state for q = qc
  const int pbase = wid * 640 + qc * 40;   // Ps row base (stride-40 ushorts)
  const int pwr   = pbase + (lane >> 4) * 4;

  auto pack2 = [&](float x, float y) -> unsigned int {
    return (unsigned int)f2b(x) | ((unsigned int)f2b(y) << 16);
  };

  auto pairIter = [&](int p, int sb, int4& w0, int4& w1, int4& w2, int4& w3) {
    if (p == NPAIR - 1) { VM0; } else { VM8; }   // pair p (and qf at p=0) landed
    wrV(w0, w1, w2, w3);
    asm volatile("s_waitcnt lgkmcnt(0)" ::: "memory");
    __builtin_amdgcn_s_barrier();                 // pair staged, visible to all waves

    // S^T: lane holds q=qc, 16 kv values; 16 MFMA
    f32x4_t st[4];
    st[0] = (f32x4_t)0.f; st[1] = (f32x4_t)0.f;
    st[2] = (f32x4_t)0.f; st[3] = (f32x4_t)0.f;
    const int kr0 = qc, kr1 = 16 + qc;
    __builtin_amdgcn_s_setprio(1);
#pragma unroll
    for (int ks = 0; ks < 4; ++ks) {
      const bf16x8_t k00 = *(const bf16x8_t*)&Ks[sb][(kr0 * 128 + ks * 32 + (lane >> 4) * 8) ^ ((kr0 & 7) << 3)];
      st[0] = __builtin_amdgcn_mfma_f32_16x16x32_bf16(k00, qf[ks], st[0], 0, 0, 0);
      const bf16x8_t k01 = *(const bf16x8_t*)&Ks[sb][(kr1 * 128 + ks * 32 + (lane >> 4) * 8) ^ ((kr1 & 7) << 3)];
      st[1] = __builtin_amdgcn_mfma_f32_16x16x32_bf16(k01, qf[ks], st[1], 0, 0, 0);
      const bf16x8_t k10 = *(const bf16x8_t*)&Ks[sb + 1][(kr0 * 128 + ks * 32 + (lane >> 4) * 8) ^ ((kr0 & 7) << 3)];
      st[2] = __builtin_amdgcn_mfma_f32_16x16x32_bf16(k10, qf[ks], st[2], 0, 0, 0);
      const bf16x8_t k11 = *(const bf16x8_t*)&Ks[sb + 1][(kr1 * 128 + ks * 32 + (lane >> 4) * 8) ^ ((kr1 & 7) << 3)];
      st[3] = __builtin_amdgcn_mfma_f32_16x16x32_bf16(k11, qf[ks], st[3], 0, 0, 0);
    }
    __builtin_amdgcn_s_setprio(0);

    // softmax: in-lane reduce + 2 shfl_xor
    float mx01 = fmaxf(fmaxf(st[0][0], st[0][1]), fmaxf(st[0][2], st[0][3]));
    float mx23 = fmaxf(fmaxf(st[1][0], st[1][1]), fmaxf(st[1][2], st[1][3]));
    float mx45 = fmaxf(fmaxf(st[2][0], st[2][1]), fmaxf(st[2][2], st[2][3]));
    float mx67 = fmaxf(fmaxf(st[3][0], st[3][1]), fmaxf(st[3][2], st[3][3]));
    float pm = fmaxf(fmaxf(mx01, mx23), fmaxf(mx45, mx67)) * rs;
    pm = fmaxf(pm, __shfl_xor(pm, 16, 64));
    pm = fmaxf(pm, __shfl_xor(pm, 32, 64));

    const int grow = __any(pm > mrun);
    if (grow) {
      const float mnew = fmaxf(mrun, pm);
      const float corr = __expf(mrun - mnew);
      mrun = mnew;
      lrun *= corr;
      float c4[4];
#pragma unroll
      for (int r = 0; r < 4; ++r) c4[r] = __shfl(corr, (lane >> 4) * 4 + r, 16);
#pragma unroll
      for (int i = 0; i < 8; ++i)
#pragma unroll
        for (int r = 0; r < 4; ++r) oa[i][r] *= c4[r];
    }

    float ssum = 0.f;
#pragma unroll
    for (int tt = 0; tt < 4; ++tt)
#pragma unroll
      for (int r = 0; r < 4; ++r) {
        st[tt][r] = __expf(st[tt][r] * rs - mrun);
        ssum += st[tt][r];
      }
    ssum += __shfl_xor(ssum, 16, 64);
    ssum += __shfl_xor(ssum, 32, 64);
    lrun += ssum;

    // P^T halves to separate buffers (no WAR wait)
    *(unsigned int*)&Ps[0][pwr]      = pack2(st[0][0], st[0][1]);
    *(unsigned int*)&Ps[0][pwr + 2]  = pack2(st[0][2], st[0][3]);
    *(unsigned int*)&Ps[0][pwr + 16] = pack2(st[1][0], st[1][1]);
    *(unsigned int*)&Ps[0][pwr + 18] = pack2(st[1][2], st[1][3]);
    *(unsigned int*)&Ps[1][pwr]      = pack2(st[2][0], st[2][1]);
    *(unsigned int*)&Ps[1][pwr + 2]  = pack2(st[2][2], st[2][3]);
    *(unsigned int*)&Ps[1][pwr + 16] = pack2(st[3][0], st[3][1]);
    *(unsigned int*)&Ps[1][pwr + 18] = pack2(st[3][2], st[3][3]);
    const bf16x8_t pa0 = *(const bf16x8_t*)&Ps[0][pbase + (lane >> 4) * 8];
    const bf16x8_t pa1 = *(const bf16x8_t*)&Ps[1][pbase + (lane >> 4) * 8];

    __builtin_amdgcn_s_setprio(1);
#pragma unroll
    for (int nt2 = 0; nt2 < 8; ++nt2) {
      const bf16x8_t vf0 = rdVf(0, nt2);
      oa[nt2] = __builtin_amdgcn_mfma_f32_16x16x32_bf16(pa0, vf0, oa[nt2], 0, 0, 0);
      const bf16x8_t vf1 = rdVf(1, nt2);
      oa[nt2] = __builtin_amdgcn_mfma_f32_16x16x32_bf16(pa1, vf1, oa[nt2], 0, 0, 0);
    }
    __builtin_amdgcn_s_setprio(0);
    __builtin_amdgcn_s_barrier();                 // all waves done with Ks[sb..sb+1], VtU
    if (p + 2 < NPAIR) {
      stK(2 * p + 4, sb); stK(2 * p + 5, sb + 1);
      ldV(p + 2, w0, w1, w2, w3);
    }
  };

  for (int j = 0; j < NPAIR / 2; ++j) {
    pairIter(2 * j,     0, a0, a1, a2, a3);
    pairIter(2 * j + 1, 2, b0, b1, b2, b3);
  }

  // broadcast l (q-layout) into oa row layout, normalize, store
  float inv[4];
#pragma unroll
  for (int r = 0; r < 4; ++r) inv[r] = 1.f / __shfl(lrun, (lane >> 4) * 4 + r, 16);
#pragma unroll
  for (int nt2 = 0; nt2 < 8; ++nt2) {
    const int col = h * HD + nt2 * 16 + (lane & 15);
#pragma unroll
    for (int r = 0; r < 4; ++r) {
      const int row = qt * 64 + q0 + (lane >> 4) * 4 + r;
      O[(size_t)(b * SEQ + row) * DIM + col] = f2b(oa[nt2][r] * inv[r]);
    }
  }
}

// ---------------- launch ----------------
extern "C" void kernel_launch(void* const* d_in, const int* in_sizes, int n_in,
                              void* d_out, int out_size, void* d_ws, size_t ws_size,
                              hipStream_t stream)
{
  (void)in_sizes; (void)n_in; (void)out_size; (void)ws_size;
  const float* x   = (const float*)d_in[0];
  const float* fr  = (const float*)d_in[1];
  const float* ga  = (const float*)d_in[3];
  const float* gf  = (const float*)d_in[4];
  const float* wq  = (const float*)d_in[5];
  const float* wqb = (const float*)d_in[6];
  const float* wk  = (const float*)d_in[7];
  const float* wkb = (const float*)d_in[8];
  const float* wv  = (const float*)d_in[9];
  const float* wvb = (const float*)d_in[10];
  const float* wo  = (const float*)d_in[11];
  const float* wob = (const float*)d_in[12];
  const float* w1  = (const float*)d_in[13];
  const float* w3  = (const float*)d_in[14];
  const float* w2  = (const float*)d_in[15];
  float* out = (float*)d_out;

  constexpr size_t MB = 1ull << 20;
  char* ws = (char*)d_ws;
  unsigned short* xn = (unsigned short*)(ws);              // [0,64) MiB
  unsigned short* qb = (unsigned short*)(ws + 64*MB);      // [64,128)
  unsigned short* kb = (unsigned short*)(ws + 128*MB);     // [128,144)
  unsigned short* vb = (unsigned short*)(ws + 144*MB);     // [144,160)
  unsigned short* ao = (unsigned short*)(ws + 160*MB);     // [160,224)
  unsigned short* hn = (unsigned short*)(ws + 224*MB);     // [224,288)
  unsigned short* g  = (unsigned short*)(ws);              // [0,172) alias (dead by FFN time)
  unsigned short* wscr = (unsigned short*)(ws + 288*MB);   // JIT bf16 weights
  unsigned short* wqB = wscr;                               // 32 MiB
  unsigned short* wkB = wscr + 16*MB;                       // 8 MiB
  unsigned short* wvB = wscr + 20*MB;                       // 8 MiB
  unsigned short* woB = wscr;                               // 32 MiB (after QKV)
  unsigned short* w1B = wscr;                               // 90 MiB
  unsigned short* w3B = wscr + 45*MB;                       // 90 MiB
  unsigned short* w2B = wscr;                               // 90 MiB

  rmsnorm_k<<<MTOT, 256, 0, stream>>>(x, ga, xn);
  cvt_bf16_k<<<(NH*HD*DIM)/2048,  256, 0, stream>>>(wq, wqB);
  cvt_bf16_k<<<(NKV*HD*DIM)/2048, 256, 0, stream>>>(wk, wkB);
  cvt_bf16_k<<<(NKV*HD*DIM)/2048, 256, 0, stream>>>(wv, wvB);
  gemm256<0><<<(MTOT/256)*((DIM+2*NKV*HD)/256), 512, 0, stream>>>(
      xn, wqB, nullptr, wqb, nullptr, nullptr, qb,
      wkB, wvB, wkb, wvb, kb, vb, fr, DIM);
  attn_k<<<BATCH*NH*(SEQ/64), 256, 0, stream>>>(qb, kb, vb, ao);
  cvt_bf16_k<<<(DIM*DIM)/2048, 256, 0, stream>>>(wo, woB);
  gemm256<1><<<(MTOT/256)*(DIM/256), 512, 0, stream>>>(
      ao, woB, nullptr, wob, x, out, nullptr,
      nullptr, nullptr, nullptr, nullptr, nullptr, nullptr, nullptr, DIM);
  rmsnorm_k<<<MTOT, 256, 0, stream>>>(out, gf, hn);
  cvt_bf16_k<<<(FFNH*DIM)/2048, 256, 0, stream>>>(w1, w1B);
  cvt_bf16_k<<<(FFNH*DIM)/2048, 256, 0, stream>>>(w3, w3B);
  gemm256<3><<<(MTOT/256)*(FFNH/128), 512, 0, stream>>>(
      hn, w1B, w3B, nullptr, nullptr, nullptr, g,
      nullptr, nullptr, nullptr, nullptr, nullptr, nullptr, nullptr, DIM);
  cvt_bf16_k<<<(FFNH*DIM)/2048, 256, 0, stream>>>(w2, w2B);
  gemm256<2><<<(MTOT/256)*(DIM/256), 512, 0, stream>>>(
      g, w2B, nullptr, nullptr, out, out, nullptr,
      nullptr, nullptr, nullptr, nullptr, nullptr, nullptr, nullptr, FFNH);
}

// Round 12
// 3702.510 us; speedup vs baseline: 1.0256x; 1.0256x over previous
//
#include <hip/hip_runtime.h>
#include <hip/hip_bf16.h>

#define DIM   4096
#define NH    32
#define NKV   8
#define HD    128
#define FFNH  11008
#define BATCH 4
#define SEQ   2048
#define MTOT  (BATCH*SEQ)   // 8192

using bf16x8_t = __attribute__((ext_vector_type(8))) short;
using f32x4_t  = __attribute__((ext_vector_type(4))) float;

typedef const __attribute__((address_space(1))) unsigned int GlbU32;
typedef __attribute__((address_space(3))) unsigned int LdsU32;

__device__ __forceinline__ unsigned short f2b(float f) {
  union { float f; unsigned int u; } v; v.f = f;
  return (unsigned short)((v.u + 0x7fffu + ((v.u >> 16) & 1u)) >> 16);
}
__device__ __forceinline__ float b2f(unsigned short b) {
  union { unsigned int u; float f; } v; v.u = ((unsigned int)b) << 16;
  return v.f;
}
__device__ __forceinline__ void gll16(const void* g, void* l) {
  __builtin_amdgcn_global_load_lds((GlbU32*)g, (LdsU32*)l, 16, 0, 0);
}

#define VM8  asm volatile("s_waitcnt vmcnt(8)" ::: "memory")
#define VM4M asm volatile("s_waitcnt vmcnt(4)" ::: "memory")
#define VM0  asm volatile("s_waitcnt vmcnt(0)" ::: "memory")

// ---------------- fp32 -> bf16 bulk convert ----------------
__global__ __launch_bounds__(256)
void cvt_bf16_k(const float* __restrict__ src, unsigned short* __restrict__ dst)
{
  const size_t i = ((size_t)blockIdx.x * 256 + threadIdx.x) * 8;
  const float4 a = *(const float4*)&src[i];
  const float4 b = *(const float4*)&src[i + 4];
  union { int4 v; unsigned short u[8]; } o;
  o.u[0] = f2b(a.x); o.u[1] = f2b(a.y); o.u[2] = f2b(a.z); o.u[3] = f2b(a.w);
  o.u[4] = f2b(b.x); o.u[5] = f2b(b.y); o.u[6] = f2b(b.z); o.u[7] = f2b(b.w);
  *(int4*)&dst[i] = o.v;
}

// ---------------- RMSNorm: fp32 in -> bf16 out ----------------
__global__ __launch_bounds__(256)
void rmsnorm_k(const float* __restrict__ X, const float* __restrict__ gamma,
               unsigned short* __restrict__ Y)
{
  const int row = blockIdx.x, t = threadIdx.x;
  const float* xr = X + (size_t)row * DIM;
  float4 v[4];
  float ss = 0.f;
#pragma unroll
  for (int p = 0; p < 4; ++p) {
    v[p] = *(const float4*)&xr[p * 1024 + t * 4];
    ss += v[p].x*v[p].x + v[p].y*v[p].y + v[p].z*v[p].z + v[p].w*v[p].w;
  }
#pragma unroll
  for (int off = 32; off >= 1; off >>= 1) ss += __shfl_xor(ss, off, 64);
  __shared__ float red[4];
  if ((t & 63) == 0) red[t >> 6] = ss;
  __syncthreads();
  const float tot = red[0] + red[1] + red[2] + red[3];
  const float rn = rsqrtf(tot * (1.f / DIM) + 1e-6f);
  unsigned short* yr = Y + (size_t)row * DIM;
#pragma unroll
  for (int p = 0; p < 4; ++p) {
    const float4 gv = *(const float4*)&gamma[p * 1024 + t * 4];
    short4 o;
    o.x = (short)f2b(v[p].x * gv.x * rn);
    o.y = (short)f2b(v[p].y * gv.y * rn);
    o.z = (short)f2b(v[p].z * gv.z * rn);
    o.w = (short)f2b(v[p].w * gv.w * rn);
    *(short4*)&yr[p * 1024 + t * 4] = o;
  }
}

// ======================= 256x256 GEMM, 2 barriers / K=32 phase (round-6 proven) ===========
// MODE 0 additionally fuses RoPE into the Q/K epilogue (partner via shfl_xor(1)).
template<int MODE>
__global__ __launch_bounds__(512)
void gemm256(const unsigned short* __restrict__ A,
             const unsigned short* __restrict__ W,
             const unsigned short* __restrict__ W3p,
             const float* __restrict__ bias,
             const float* res,
             float* outF,
             unsigned short* __restrict__ outH,
             const unsigned short* __restrict__ wkp,
             const unsigned short* __restrict__ wvp,
             const float* __restrict__ bkp,
             const float* __restrict__ bvp,
             unsigned short* __restrict__ okp,
             unsigned short* __restrict__ ovp,
             const float* __restrict__ freqs,
             int K)
{
  __shared__ __align__(16) char smem[131072];
  const int t = threadIdx.x, lane = t & 63, wid = t >> 6;
  const int wr = wid >> 2, wc = wid & 3;
  const int G = gridDim.x, bid = blockIdx.x;
  const int wg = (bid & 7) * (G >> 3) + (bid >> 3);   // XCD-chunked
  const int NBN = G >> 5;                             // NBM = 32 (M = 8192)
  const int span = NBN << 3;                          // TMG = 8
  const int tmg = wg / span, rr = wg - tmg * span;
  const int tn = rr >> 3, tm = (tmg << 3) + (rr & 7);
  const int m0 = tm << 8;
  const int NSUB = K >> 5;

  const unsigned short *P1, *P2;
  const float* bp = bias;
  unsigned short* oh = outH;
  const float* ropef = nullptr;
  int nloc = 0, colsN = 4096;
  if constexpr (MODE == 0) {
    const int n0 = tn << 8;
    if (n0 < 4096)      { nloc = n0;        P1 = W   + (size_t)nloc * K; bp = bias; oh = outH; colsN = 4096; ropef = freqs; }
    else if (n0 < 5120) { nloc = n0 - 4096; P1 = wkp + (size_t)nloc * K; bp = bkp;  oh = okp;  colsN = 1024; ropef = freqs; }
    else                { nloc = n0 - 5120; P1 = wvp + (size_t)nloc * K; bp = bvp;  oh = ovp;  colsN = 1024; }
    P2 = P1 + (size_t)128 * K;
  } else if constexpr (MODE == 3) {
    const int n0w = tn << 7;
    P1 = W   + (size_t)n0w * K;
    P2 = W3p + (size_t)n0w * K;
    nloc = n0w;
  } else {
    const int n0 = tn << 8;
    P1 = W + (size_t)n0 * K;
    P2 = P1 + (size_t)128 * K;
    nloc = n0;
  }

  const int r0 = t >> 2, gg = t & 3;
  const int gsw = gg ^ ((r0 >> 1) & 3);

  auto stA = [&](int sig) {
    if (sig < NSUB) {
      const int slot = sig & 3;
      gll16(A + (size_t)(m0 + r0) * K + sig * 32 + gsw * 8,
            smem + slot * 16384 + wid * 1024);
      gll16(A + (size_t)(m0 + 128 + r0) * K + sig * 32 + gsw * 8,
            smem + slot * 16384 + 8192 + wid * 1024);
    }
  };
  auto stB = [&](int sig) {
    if (sig < NSUB) {
      const int slot = sig & 3;
      gll16(P1 + (size_t)r0 * K + sig * 32 + gsw * 8,
            smem + 65536 + slot * 16384 + wid * 1024);
      gll16(P2 + (size_t)r0 * K + sig * 32 + gsw * 8,
            smem + 65536 + slot * 16384 + 8192 + wid * 1024);
    }
  };
  auto rdA = [&](int slot, int mo) -> bf16x8_t {
    const int lrow = wr * 128 + mo + (lane & 15);
    const int g = (lane >> 4) ^ ((lrow >> 1) & 3);
    return *(const bf16x8_t*)(smem + slot * 16384 + lrow * 64 + g * 16);
  };
  auto rdB = [&](int slot, int nf) -> bf16x8_t {
    const int brow = wc * 64 + nf * 16 + (lane & 15);
    const int g = (lane >> 4) ^ ((brow >> 1) & 3);
    return *(const bf16x8_t*)(smem + 65536 + slot * 16384 + brow * 64 + g * 16);
  };

  f32x4_t acc[8][4];
#pragma unroll
  for (int i = 0; i < 8; ++i)
#pragma unroll
    for (int j = 0; j < 4; ++j) acc[i][j] = (f32x4_t)0.f;

  stA(0); stB(0); stA(1); stB(1); stA(2); stB(2);
  VM8;
  __builtin_amdgcn_s_barrier();

  for (int p = 0; p < NSUB; ++p) {
    const int slot = p & 3;
    bf16x8_t bfv[4], afv[8];
#pragma unroll
    for (int n = 0; n < 4; ++n) bfv[n] = rdB(slot, n);
#pragma unroll
    for (int m = 0; m < 8; ++m) afv[m] = rdA(slot, m * 16);
    stA(p + 3); stB(p + 3);
    __builtin_amdgcn_s_setprio(1);
#pragma unroll
    for (int m = 0; m < 8; ++m)
#pragma unroll
      for (int n = 0; n < 4; ++n)
        acc[m][n] = __builtin_amdgcn_mfma_f32_16x16x32_bf16(afv[m], bfv[n], acc[m][n], 0, 0, 0);
    __builtin_amdgcn_s_setprio(0);
    if (p < NSUB - 3)      { VM8; }
    else if (p == NSUB - 3){ VM4M; }
    else                   { VM0; }
    __builtin_amdgcn_s_barrier();
  }

  if constexpr (MODE == 0) {
#pragma unroll
    for (int ni = 0; ni < 4; ++ni) {
      const int col = nloc + wc * 64 + ni * 16 + (lane & 15);
      const float bv = bp[col];
      const int cin = col & 127;
#pragma unroll
      for (int mi = 0; mi < 8; ++mi) {
#pragma unroll
        for (int r = 0; r < 4; ++r) {
          const int row = m0 + wr * 128 + mi * 16 + (lane >> 4) * 4 + r;
          float vv = acc[mi][ni][r] + bv;
          if (ropef) {
            const float po = __shfl_xor(vv, 1, 64);
            const float fq = ropef[(row & (SEQ - 1)) * 64 + (cin >> 1)];
            float sn, cs;
            __sincosf(fq, &sn, &cs);
            vv = (col & 1) ? (po * sn + vv * cs) : (vv * cs - po * sn);
          }
          oh[(size_t)row * colsN + col] = f2b(vv);
        }
      }
    }
  } else if constexpr (MODE == 1 || MODE == 2) {
#pragma unroll
    for (int ni = 0; ni < 4; ++ni) {
      const int col = nloc + wc * 64 + ni * 16 + (lane & 15);
      float bv = 0.f;
      if constexpr (MODE == 1) bv = bias[col];
#pragma unroll
      for (int mi = 0; mi < 8; ++mi)
#pragma unroll
        for (int r = 0; r < 4; ++r) {
          const int row = m0 + wr * 128 + mi * 16 + (lane >> 4) * 4 + r;
          const size_t idx = (size_t)row * 4096 + col;
          outF[idx] = acc[mi][ni][r] + bv + res[idx];
        }
    }
  } else {
    if (wc >= 2) {
      const int widx = wr * 2 + (wc - 2);
#pragma unroll
      for (int ni = 0; ni < 4; ++ni)
#pragma unroll
        for (int mi = 0; mi < 8; ++mi)
#pragma unroll
          for (int r = 0; r < 4; ++r) {
            const int lrow = mi * 16 + (lane >> 4) * 4 + r;
            const int ncol = ni * 16 + (lane & 15);
            *(unsigned short*)(smem + widx * 16384 + lrow * 128 + ncol * 2) =
                f2b(acc[mi][ni][r]);
          }
    }
    __syncthreads();
    if (wc < 2) {
      const int widx = wr * 2 + wc;
#pragma unroll
      for (int ni = 0; ni < 4; ++ni)
#pragma unroll
        for (int mi = 0; mi < 8; ++mi)
#pragma unroll
          for (int r = 0; r < 4; ++r) {
            const int lrow = mi * 16 + (lane >> 4) * 4 + r;
            const int ncol = ni * 16 + (lane & 15);
            const float s3 = b2f(*(const unsigned short*)(smem + widx * 16384 + lrow * 128 + ncol * 2));
            const float s1 = acc[mi][ni][r];
            const float sig = 1.f / (1.f + __expf(-s1));
            const int row = m0 + wr * 128 + lrow;
            outH[(size_t)row * FFNH + nloc + wc * 64 + ncol] = f2b(s1 * sig * s3);
          }
    }
  }
}

// ---------------- Flash attention (round-10 proven version) ----------------
// Swapped QK^T (lane owns one q), Q fragments in REGISTERS (no Qs LDS),
// Ps halved to 16q x 32kv (stride-40 rows, u32-packed writes, lgkm WAR guard).
// LDS 53 KB -> 3 blocks/CU. Distance-2 K/V pair prefetch (ring-4 K, vmcnt(8)).
__global__ __launch_bounds__(256, 3)
void attn_k(const unsigned short* __restrict__ Q, const unsigned short* __restrict__ Kb,
            const unsigned short* __restrict__ Vb, unsigned short* __restrict__ O)
{
  __shared__ unsigned short Ks[4][4096];   // ring-4 K tiles (32x128 swizzled) 32 KB
  __shared__ unsigned short Vt[2][4096];   // V^T pair, written from regs      16 KB
  __shared__ unsigned short Ps[2560];      // per-wave 16q x 32kv, stride 40    5 KB
  const int t = threadIdx.x, lane = t & 63, wid = t >> 6;
  const int bx = blockIdx.x;
  const int qt = bx & 31, h = (bx >> 5) & 31, b = bx >> 10;
  const int kvh = h >> 2;
  const float rs = 0.08838834764831845f;   // 1/sqrt(128)
  constexpr int NPAIR = SEQ / 64;          // 32

  const int q0 = wid * 16;
  const int qc = lane & 15;                // this lane's q (softmax layout)

  // Q fragments in registers: B-operand of swapped QK^T
  bf16x8_t qf[4];
  {
    const unsigned short* qrow = Q + (size_t)(b * SEQ + qt * 64 + q0 + qc) * DIM
                                   + h * HD + (lane >> 4) * 8;
#pragma unroll
    for (int ks = 0; ks < 4; ++ks) qf[ks] = *(const bf16x8_t*)(qrow + ks * 32);
  }

  const unsigned short* Kbase = Kb + (size_t)(b * SEQ) * (NKV * HD) + kvh * HD;
  const unsigned short* Vbase = Vb + (size_t)(b * SEQ) * (NKV * HD) + kvh * HD;

  auto stK = [&](int kt, int slot) {
#pragma unroll
    for (int oo = 0; oo < 2; ++oo) {
      const int o = wid * 2 + oo;
      const int row = o * 4 + (lane >> 4);
      const int gl  = (lane & 15) ^ (row & 7);
      gll16(Kbase + (size_t)(kt * 32 + row) * (NKV * HD) + gl * 8, &Ks[slot][o * 512]);
    }
  };
  const int kv = t >> 3, dc = (t & 7) << 4;
  const int colv = kv ^ ((t & 3) << 3);
  auto ldV = [&](int kt, int4& lo, int4& hi) {
    const unsigned short* gp = Vbase + (size_t)(kt * 32 + kv) * (NKV * HD) + dc;
    lo = *(const int4*)gp;
    hi = *(const int4*)(gp + 8);
  };
  auto wrV = [&](int slot, int4 vlo, int4 vhi) {
    union { int4 v; unsigned short u[8]; } lo, hi;
    lo.v = vlo; hi.v = vhi;
#pragma unroll
    for (int j = 0; j < 8; ++j) Vt[slot][(dc + j) * 32 + colv] = lo.u[j];
#pragma unroll
    for (int j = 0; j < 8; ++j) Vt[slot][(dc + 8 + j) * 32 + colv] = hi.u[j];
  };

  // prologue: pairs 0 (slots 0,1 / regset A) and 1 (slots 2,3 / regset B)
  int4 a0l, a0h, a1l, a1h, b0l, b0h, b1l, b1h;
  stK(0, 0); ldV(0, a0l, a0h); stK(1, 1); ldV(1, a1l, a1h);
  stK(2, 2); ldV(2, b0l, b0h); stK(3, 3); ldV(3, b1l, b1h);

  f32x4_t oa[8];
#pragma unroll
  for (int i = 0; i < 8; ++i) oa[i] = (f32x4_t)0.f;
  float mrun = -1e30f, lrun = 0.f;         // per-lane state for q = qc
  const int pbase = wid * 640 + qc * 40;   // Ps row base (stride-40 ushorts)
  const int pwr   = pbase + (lane >> 4) * 4;

  auto pack2 = [&](float x, float y) -> unsigned int {
    return (unsigned int)f2b(x) | ((unsigned int)f2b(y) << 16);
  };

  auto pairIter = [&](int p, int sb, int4& l0, int4& h0, int4& l1, int4& h1) {
    if (p == NPAIR - 1) { VM0; } else { VM8; }   // pair p (and qf at p=0) landed
    wrV(0, l0, h0);
    wrV(1, l1, h1);
    asm volatile("s_waitcnt lgkmcnt(0)" ::: "memory");
    __builtin_amdgcn_s_barrier();                 // pair staged, visible to all waves

    // S^T: lane holds q=qc, 16 kv values; 16 MFMA
    f32x4_t st[4];
    st[0] = (f32x4_t)0.f; st[1] = (f32x4_t)0.f;
    st[2] = (f32x4_t)0.f; st[3] = (f32x4_t)0.f;
    const int kr0 = qc, kr1 = 16 + qc;
    __builtin_amdgcn_s_setprio(1);
#pragma unroll
    for (int ks = 0; ks < 4; ++ks) {
      const bf16x8_t k00 = *(const bf16x8_t*)&Ks[sb][(kr0 * 128 + ks * 32 + (lane >> 4) * 8) ^ ((kr0 & 7) << 3)];
      st[0] = __builtin_amdgcn_mfma_f32_16x16x32_bf16(k00, qf[ks], st[0], 0, 0, 0);
      const bf16x8_t k01 = *(const bf16x8_t*)&Ks[sb][(kr1 * 128 + ks * 32 + (lane >> 4) * 8) ^ ((kr1 & 7) << 3)];
      st[1] = __builtin_amdgcn_mfma_f32_16x16x32_bf16(k01, qf[ks], st[1], 0, 0, 0);
      const bf16x8_t k10 = *(const bf16x8_t*)&Ks[sb + 1][(kr0 * 128 + ks * 32 + (lane >> 4) * 8) ^ ((kr0 & 7) << 3)];
      st[2] = __builtin_amdgcn_mfma_f32_16x16x32_bf16(k10, qf[ks], st[2], 0, 0, 0);
      const bf16x8_t k11 = *(const bf16x8_t*)&Ks[sb + 1][(kr1 * 128 + ks * 32 + (lane >> 4) * 8) ^ ((kr1 & 7) << 3)];
      st[3] = __builtin_amdgcn_mfma_f32_16x16x32_bf16(k11, qf[ks], st[3], 0, 0, 0);
    }
    __builtin_amdgcn_s_setprio(0);

    // softmax: in-lane reduce + 2 shfl_xor
    float mx01 = fmaxf(fmaxf(st[0][0], st[0][1]), fmaxf(st[0][2], st[0][3]));
    float mx23 = fmaxf(fmaxf(st[1][0], st[1][1]), fmaxf(st[1][2], st[1][3]));
    float mx45 = fmaxf(fmaxf(st[2][0], st[2][1]), fmaxf(st[2][2], st[2][3]));
    float mx67 = fmaxf(fmaxf(st[3][0], st[3][1]), fmaxf(st[3][2], st[3][3]));
    float pm = fmaxf(fmaxf(mx01, mx23), fmaxf(mx45, mx67)) * rs;
    pm = fmaxf(pm, __shfl_xor(pm, 16, 64));
    pm = fmaxf(pm, __shfl_xor(pm, 32, 64));

    const int grow = __any(pm > mrun);
    if (grow) {
      const float mnew = fmaxf(mrun, pm);
      const float corr = __expf(mrun - mnew);
      mrun = mnew;
      lrun *= corr;
      float c4[4];
#pragma unroll
      for (int r = 0; r < 4; ++r) c4[r] = __shfl(corr, (lane >> 4) * 4 + r, 16);
#pragma unroll
      for (int i = 0; i < 8; ++i)
#pragma unroll
        for (int r = 0; r < 4; ++r) oa[i][r] *= c4[r];
    }

    float ssum = 0.f;
#pragma unroll
    for (int tt = 0; tt < 4; ++tt)
#pragma unroll
      for (int r = 0; r < 4; ++r) {
        st[tt][r] = __expf(st[tt][r] * rs - mrun);
        ssum += st[tt][r];
      }
    ssum += __shfl_xor(ssum, 16, 64);
    ssum += __shfl_xor(ssum, 32, 64);
    lrun += ssum;

    // P^T half 0 (kv 0..31): packed u32 writes, read pa0
    *(unsigned int*)&Ps[pwr]      = pack2(st[0][0], st[0][1]);
    *(unsigned int*)&Ps[pwr + 2]  = pack2(st[0][2], st[0][3]);
    *(unsigned int*)&Ps[pwr + 16] = pack2(st[1][0], st[1][1]);
    *(unsigned int*)&Ps[pwr + 18] = pack2(st[1][2], st[1][3]);
    const bf16x8_t pa0 = *(const bf16x8_t*)&Ps[pbase + (lane >> 4) * 8];
    asm volatile("s_waitcnt lgkmcnt(0)" ::: "memory");   // pa0 read drained (WAR guard)
    // P^T half 1 (kv 32..63) overwrites the same region, read pa1
    *(unsigned int*)&Ps[pwr]      = pack2(st[2][0], st[2][1]);
    *(unsigned int*)&Ps[pwr + 2]  = pack2(st[2][2], st[2][3]);
    *(unsigned int*)&Ps[pwr + 16] = pack2(st[3][0], st[3][1]);
    *(unsigned int*)&Ps[pwr + 18] = pack2(st[3][2], st[3][3]);
    const bf16x8_t pa1 = *(const bf16x8_t*)&Ps[pbase + (lane >> 4) * 8];

    __builtin_amdgcn_s_setprio(1);
#pragma unroll
    for (int nt2 = 0; nt2 < 8; ++nt2) {
      const bf16x8_t vf0 = *(const bf16x8_t*)&Vt[0][(nt2 * 16 + (lane & 15)) * 32 + (((lane >> 4) ^ (nt2 & 3)) << 3)];
      oa[nt2] = __builtin_amdgcn_mfma_f32_16x16x32_bf16(pa0, vf0, oa[nt2], 0, 0, 0);
      const bf16x8_t vf1 = *(const bf16x8_t*)&Vt[1][(nt2 * 16 + (lane & 15)) * 32 + (((lane >> 4) ^ (nt2 & 3)) << 3)];
      oa[nt2] = __builtin_amdgcn_mfma_f32_16x16x32_bf16(pa1, vf1, oa[nt2], 0, 0, 0);
    }
    __builtin_amdgcn_s_setprio(0);
    __builtin_amdgcn_s_barrier();                 // all waves done with Ks[sb..sb+1], Vt
    if (p + 2 < NPAIR) {
      stK(2 * p + 4, sb);     ldV(2 * p + 4, l0, h0);
      stK(2 * p + 5, sb + 1); ldV(2 * p + 5, l1, h1);
    }
  };

  for (int j = 0; j < NPAIR / 2; ++j) {
    pairIter(2 * j,     0, a0l, a0h, a1l, a1h);
    pairIter(2 * j + 1, 2, b0l, b0h, b1l, b1h);
  }

  // broadcast l (q-layout) into oa row layout, normalize, store
  float inv[4];
#pragma unroll
  for (int r = 0; r < 4; ++r) inv[r] = 1.f / __shfl(lrun, (lane >> 4) * 4 + r, 16);
#pragma unroll
  for (int nt2 = 0; nt2 < 8; ++nt2) {
    const int col = h * HD + nt2 * 16 + (lane & 15);
#pragma unroll
    for (int r = 0; r < 4; ++r) {
      const int row = qt * 64 + q0 + (lane >> 4) * 4 + r;
      O[(size_t)(b * SEQ + row) * DIM + col] = f2b(oa[nt2][r] * inv[r]);
    }
  }
}

// ---------------- launch ----------------
extern "C" void kernel_launch(void* const* d_in, const int* in_sizes, int n_in,
                              void* d_out, int out_size, void* d_ws, size_t ws_size,
                              hipStream_t stream)
{
  (void)in_sizes; (void)n_in; (void)out_size; (void)ws_size;
  const float* x   = (const float*)d_in[0];
  const float* fr  = (const float*)d_in[1];
  const float* ga  = (const float*)d_in[3];
  const float* gf  = (const float*)d_in[4];
  const float* wq  = (const float*)d_in[5];
  const float* wqb = (const float*)d_in[6];
  const float* wk  = (const float*)d_in[7];
  const float* wkb = (const float*)d_in[8];
  const float* wv  = (const float*)d_in[9];
  const float* wvb = (const float*)d_in[10];
  const float* wo  = (const float*)d_in[11];
  const float* wob = (const float*)d_in[12];
  const float* w1  = (const float*)d_in[13];
  const float* w3  = (const float*)d_in[14];
  const float* w2  = (const float*)d_in[15];
  float* out = (float*)d_out;

  constexpr size_t MB = 1ull << 20;
  char* ws = (char*)d_ws;
  unsigned short* xn = (unsigned short*)(ws);              // [0,64) MiB
  unsigned short* qb = (unsigned short*)(ws + 64*MB);      // [64,128)
  unsigned short* kb = (unsigned short*)(ws + 128*MB);     // [128,144)
  unsigned short* vb = (unsigned short*)(ws + 144*MB);     // [144,160)
  unsigned short* ao = (unsigned short*)(ws + 160*MB);     // [160,224)
  unsigned short* hn = (unsigned short*)(ws + 224*MB);     // [224,288)
  unsigned short* g  = (unsigned short*)(ws);              // [0,172) alias (dead by FFN time)
  unsigned short* wscr = (unsigned short*)(ws + 288*MB);   // JIT bf16 weights
  unsigned short* wqB = wscr;                               // 32 MiB
  unsigned short* wkB = wscr + 16*MB;                       // 8 MiB
  unsigned short* wvB = wscr + 20*MB;                       // 8 MiB
  unsigned short* woB = wscr;                               // 32 MiB (after QKV)
  unsigned short* w1B = wscr;                               // 90 MiB
  unsigned short* w3B = wscr + 45*MB;                       // 90 MiB
  unsigned short* w2B = wscr;                               // 90 MiB

  rmsnorm_k<<<MTOT, 256, 0, stream>>>(x, ga, xn);
  cvt_bf16_k<<<(NH*HD*DIM)/2048,  256, 0, stream>>>(wq, wqB);
  cvt_bf16_k<<<(NKV*HD*DIM)/2048, 256, 0, stream>>>(wk, wkB);
  cvt_bf16_k<<<(NKV*HD*DIM)/2048, 256, 0, stream>>>(wv, wvB);
  gemm256<0><<<(MTOT/256)*((DIM+2*NKV*HD)/256), 512, 0, stream>>>(
      xn, wqB, nullptr, wqb, nullptr, nullptr, qb,
      wkB, wvB, wkb, wvb, kb, vb, fr, DIM);
  attn_k<<<BATCH*NH*(SEQ/64), 256, 0, stream>>>(qb, kb, vb, ao);
  cvt_bf16_k<<<(DIM*DIM)/2048, 256, 0, stream>>>(wo, woB);
  gemm256<1><<<(MTOT/256)*(DIM/256), 512, 0, stream>>>(
      ao, woB, nullptr, wob, x, out, nullptr,
      nullptr, nullptr, nullptr, nullptr, nullptr, nullptr, nullptr, DIM);
  rmsnorm_k<<<MTOT, 256, 0, stream>>>(out, gf, hn);
  cvt_bf16_k<<<(FFNH*DIM)/2048, 256, 0, stream>>>(w1, w1B);
  cvt_bf16_k<<<(FFNH*DIM)/2048, 256, 0, stream>>>(w3, w3B);
  gemm256<3><<<(MTOT/256)*(FFNH/128), 512, 0, stream>>>(
      hn, w1B, w3B, nullptr, nullptr, nullptr, g,
      nullptr, nullptr, nullptr, nullptr, nullptr, nullptr, nullptr, DIM);
  cvt_bf16_k<<<(FFNH*DIM)/2048, 256, 0, stream>>>(w2, w2B);
  gemm256<2><<<(MTOT/256)*(DIM/256), 512, 0, stream>>>(
      g, w2B, nullptr, nullptr, out, out, nullptr,
      nullptr, nullptr, nullptr, nullptr, nullptr, nullptr, nullptr, FFNH);
}

// Round 13
// 3632.388 us; speedup vs baseline: 1.0454x; 1.0193x over previous
//
#include <hip/hip_runtime.h>
#include <hip/hip_bf16.h>

#define DIM   4096
#define NH    32
#define NKV   8
#define HD    128
#define FFNH  11008
#define BATCH 4
#define SEQ   2048
#define MTOT  (BATCH*SEQ)   // 8192

using bf16x8_t = __attribute__((ext_vector_type(8))) short;
using f32x4_t  = __attribute__((ext_vector_type(4))) float;

typedef const __attribute__((address_space(1))) unsigned int GlbU32;
typedef __attribute__((address_space(3))) unsigned int LdsU32;

__device__ __forceinline__ unsigned short f2b(float f) {
  union { float f; unsigned int u; } v; v.f = f;
  return (unsigned short)((v.u + 0x7fffu + ((v.u >> 16) & 1u)) >> 16);
}
__device__ __forceinline__ float b2f(unsigned short b) {
  union { unsigned int u; float f; } v; v.u = ((unsigned int)b) << 16;
  return v.f;
}
__device__ __forceinline__ void gll16(const void* g, void* l) {
  __builtin_amdgcn_global_load_lds((GlbU32*)g, (LdsU32*)l, 16, 0, 0);
}

#define VM8  asm volatile("s_waitcnt vmcnt(8)" ::: "memory")
#define VM4M asm volatile("s_waitcnt vmcnt(4)" ::: "memory")
#define VM0  asm volatile("s_waitcnt vmcnt(0)" ::: "memory")

// ---------------- fp32 -> bf16 bulk convert ----------------
__global__ __launch_bounds__(256)
void cvt_bf16_k(const float* __restrict__ src, unsigned short* __restrict__ dst)
{
  const size_t i = ((size_t)blockIdx.x * 256 + threadIdx.x) * 8;
  const float4 a = *(const float4*)&src[i];
  const float4 b = *(const float4*)&src[i + 4];
  union { int4 v; unsigned short u[8]; } o;
  o.u[0] = f2b(a.x); o.u[1] = f2b(a.y); o.u[2] = f2b(a.z); o.u[3] = f2b(a.w);
  o.u[4] = f2b(b.x); o.u[5] = f2b(b.y); o.u[6] = f2b(b.z); o.u[7] = f2b(b.w);
  *(int4*)&dst[i] = o.v;
}

// ---------------- RMSNorm: fp32 in -> bf16 out ----------------
__global__ __launch_bounds__(256)
void rmsnorm_k(const float* __restrict__ X, const float* __restrict__ gamma,
               unsigned short* __restrict__ Y)
{
  const int row = blockIdx.x, t = threadIdx.x;
  const float* xr = X + (size_t)row * DIM;
  float4 v[4];
  float ss = 0.f;
#pragma unroll
  for (int p = 0; p < 4; ++p) {
    v[p] = *(const float4*)&xr[p * 1024 + t * 4];
    ss += v[p].x*v[p].x + v[p].y*v[p].y + v[p].z*v[p].z + v[p].w*v[p].w;
  }
#pragma unroll
  for (int off = 32; off >= 1; off >>= 1) ss += __shfl_xor(ss, off, 64);
  __shared__ float red[4];
  if ((t & 63) == 0) red[t >> 6] = ss;
  __syncthreads();
  const float tot = red[0] + red[1] + red[2] + red[3];
  const float rn = rsqrtf(tot * (1.f / DIM) + 1e-6f);
  unsigned short* yr = Y + (size_t)row * DIM;
#pragma unroll
  for (int p = 0; p < 4; ++p) {
    const float4 gv = *(const float4*)&gamma[p * 1024 + t * 4];
    short4 o;
    o.x = (short)f2b(v[p].x * gv.x * rn);
    o.y = (short)f2b(v[p].y * gv.y * rn);
    o.z = (short)f2b(v[p].z * gv.z * rn);
    o.w = (short)f2b(v[p].w * gv.w * rn);
    *(short4*)&yr[p * 1024 + t * 4] = o;
  }
}

// ---------------- RoPE in-place on bf16 [rows][NHT*128] ----------------
template<int NHT>
__global__ __launch_bounds__(256)
void rope_k(unsigned short* __restrict__ buf, const float* __restrict__ fr)
{
  const int u = blockIdx.x * 256 + threadIdx.x;
  const int per_row = NHT * 16;
  const int row  = u / per_row;
  const int rem  = u - row * per_row;
  const int head = rem >> 4;
  const int i4   = (rem & 15) << 2;
  const int s    = row & (SEQ - 1);
  unsigned short* p = buf + (size_t)row * (NHT * HD) + head * HD + i4 * 2;
  union { int4 v; unsigned short u16[8]; } d;
  d.v = *(const int4*)p;
  const float4 f = *(const float4*)&fr[s * 64 + i4];
  const float fa[4] = {f.x, f.y, f.z, f.w};
#pragma unroll
  for (int i = 0; i < 4; ++i) {
    float sn, c;
    __sincosf(fa[i], &sn, &c);
    const float x0 = b2f(d.u16[2*i]), x1 = b2f(d.u16[2*i+1]);
    d.u16[2*i]   = f2b(x0 * c - x1 * sn);
    d.u16[2*i+1] = f2b(x0 * sn + x1 * c);
  }
  *(int4*)p = d.v;
}

// ======================= 256x256 GEMM, 2 barriers / K=32 phase (round-6 proven) ===========
template<int MODE>
__global__ __launch_bounds__(512)
void gemm256(const unsigned short* __restrict__ A,
             const unsigned short* __restrict__ W,
             const unsigned short* __restrict__ W3p,
             const float* __restrict__ bias,
             const float* res,
             float* outF,
             unsigned short* __restrict__ outH,
             const unsigned short* __restrict__ wkp,
             const unsigned short* __restrict__ wvp,
             const float* __restrict__ bkp,
             const float* __restrict__ bvp,
             unsigned short* __restrict__ okp,
             unsigned short* __restrict__ ovp,
             int K)
{
  __shared__ __align__(16) char smem[131072];
  const int t = threadIdx.x, lane = t & 63, wid = t >> 6;
  const int wr = wid >> 2, wc = wid & 3;
  const int G = gridDim.x, bid = blockIdx.x;
  const int wg = (bid & 7) * (G >> 3) + (bid >> 3);   // XCD-chunked
  const int NBN = G >> 5;                             // NBM = 32 (M = 8192)
  const int span = NBN << 3;                          // TMG = 8
  const int tmg = wg / span, rr = wg - tmg * span;
  const int tn = rr >> 3, tm = (tmg << 3) + (rr & 7);
  const int m0 = tm << 8;
  const int NSUB = K >> 5;

  const unsigned short *P1, *P2;
  const float* bp = bias;
  unsigned short* oh = outH;
  int nloc = 0, colsN = 4096;
  if constexpr (MODE == 0) {
    const int n0 = tn << 8;
    if (n0 < 4096)      { nloc = n0;        P1 = W   + (size_t)nloc * K; bp = bias; oh = outH; colsN = 4096; }
    else if (n0 < 5120) { nloc = n0 - 4096; P1 = wkp + (size_t)nloc * K; bp = bkp;  oh = okp;  colsN = 1024; }
    else                { nloc = n0 - 5120; P1 = wvp + (size_t)nloc * K; bp = bvp;  oh = ovp;  colsN = 1024; }
    P2 = P1 + (size_t)128 * K;
  } else if constexpr (MODE == 3) {
    const int n0w = tn << 7;
    P1 = W   + (size_t)n0w * K;
    P2 = W3p + (size_t)n0w * K;
    nloc = n0w;
  } else {
    const int n0 = tn << 8;
    P1 = W + (size_t)n0 * K;
    P2 = P1 + (size_t)128 * K;
    nloc = n0;
  }

  const int r0 = t >> 2, gg = t & 3;
  const int gsw = gg ^ ((r0 >> 1) & 3);

  auto stA = [&](int sig) {
    if (sig < NSUB) {
      const int slot = sig & 3;
      gll16(A + (size_t)(m0 + r0) * K + sig * 32 + gsw * 8,
            smem + slot * 16384 + wid * 1024);
      gll16(A + (size_t)(m0 + 128 + r0) * K + sig * 32 + gsw * 8,
            smem + slot * 16384 + 8192 + wid * 1024);
    }
  };
  auto stB = [&](int sig) {
    if (sig < NSUB) {
      const int slot = sig & 3;
      gll16(P1 + (size_t)r0 * K + sig * 32 + gsw * 8,
            smem + 65536 + slot * 16384 + wid * 1024);
      gll16(P2 + (size_t)r0 * K + sig * 32 + gsw * 8,
            smem + 65536 + slot * 16384 + 8192 + wid * 1024);
    }
  };
  auto rdA = [&](int slot, int mo) -> bf16x8_t {
    const int lrow = wr * 128 + mo + (lane & 15);
    const int g = (lane >> 4) ^ ((lrow >> 1) & 3);
    return *(const bf16x8_t*)(smem + slot * 16384 + lrow * 64 + g * 16);
  };
  auto rdB = [&](int slot, int nf) -> bf16x8_t {
    const int brow = wc * 64 + nf * 16 + (lane & 15);
    const int g = (lane >> 4) ^ ((brow >> 1) & 3);
    return *(const bf16x8_t*)(smem + 65536 + slot * 16384 + brow * 64 + g * 16);
  };

  f32x4_t acc[8][4];
#pragma unroll
  for (int i = 0; i < 8; ++i)
#pragma unroll
    for (int j = 0; j < 4; ++j) acc[i][j] = (f32x4_t)0.f;

  stA(0); stB(0); stA(1); stB(1); stA(2); stB(2);
  VM8;
  __builtin_amdgcn_s_barrier();

  for (int p = 0; p < NSUB; ++p) {
    const int slot = p & 3;
    bf16x8_t bfv[4], afv[8];
#pragma unroll
    for (int n = 0; n < 4; ++n) bfv[n] = rdB(slot, n);
#pragma unroll
    for (int m = 0; m < 8; ++m) afv[m] = rdA(slot, m * 16);
    stA(p + 3); stB(p + 3);
    __builtin_amdgcn_s_setprio(1);
#pragma unroll
    for (int m = 0; m < 8; ++m)
#pragma unroll
      for (int n = 0; n < 4; ++n)
        acc[m][n] = __builtin_amdgcn_mfma_f32_16x16x32_bf16(afv[m], bfv[n], acc[m][n], 0, 0, 0);
    __builtin_amdgcn_s_setprio(0);
    if (p < NSUB - 3)      { VM8; }
    else if (p == NSUB - 3){ VM4M; }
    else                   { VM0; }
    __builtin_amdgcn_s_barrier();
  }

  if constexpr (MODE == 0) {
#pragma unroll
    for (int ni = 0; ni < 4; ++ni) {
      const int col = nloc + wc * 64 + ni * 16 + (lane & 15);
      const float bv = bp[col];
#pragma unroll
      for (int mi = 0; mi < 8; ++mi)
#pragma unroll
        for (int r = 0; r < 4; ++r) {
          const int row = m0 + wr * 128 + mi * 16 + (lane >> 4) * 4 + r;
          oh[(size_t)row * colsN + col] = f2b(acc[mi][ni][r] + bv);
        }
    }
  } else if constexpr (MODE == 1 || MODE == 2) {
#pragma unroll
    for (int ni = 0; ni < 4; ++ni) {
      const int col = nloc + wc * 64 + ni * 16 + (lane & 15);
      float bv = 0.f;
      if constexpr (MODE == 1) bv = bias[col];
#pragma unroll
      for (int mi = 0; mi < 8; ++mi)
#pragma unroll
        for (int r = 0; r < 4; ++r) {
          const int row = m0 + wr * 128 + mi * 16 + (lane >> 4) * 4 + r;
          const size_t idx = (size_t)row * 4096 + col;
          outF[idx] = acc[mi][ni][r] + bv + res[idx];
        }
    }
  } else {
    if (wc >= 2) {
      const int widx = wr * 2 + (wc - 2);
#pragma unroll
      for (int ni = 0; ni < 4; ++ni)
#pragma unroll
        for (int mi = 0; mi < 8; ++mi)
#pragma unroll
          for (int r = 0; r < 4; ++r) {
            const int lrow = mi * 16 + (lane >> 4) * 4 + r;
            const int ncol = ni * 16 + (lane & 15);
            *(unsigned short*)(smem + widx * 16384 + lrow * 128 + ncol * 2) =
                f2b(acc[mi][ni][r]);
          }
    }
    __syncthreads();
    if (wc < 2) {
      const int widx = wr * 2 + wc;
#pragma unroll
      for (int ni = 0; ni < 4; ++ni)
#pragma unroll
        for (int mi = 0; mi < 8; ++mi)
#pragma unroll
          for (int r = 0; r < 4; ++r) {
            const int lrow = mi * 16 + (lane >> 4) * 4 + r;
            const int ncol = ni * 16 + (lane & 15);
            const float s3 = b2f(*(const unsigned short*)(smem + widx * 16384 + lrow * 128 + ncol * 2));
            const float s1 = acc[mi][ni][r];
            const float sig = 1.f / (1.f + __expf(-s1));
            const int row = m0 + wr * 128 + lrow;
            outH[(size_t)row * FFNH + nloc + wc * 64 + ncol] = f2b(s1 * sig * s3);
          }
    }
  }
}

// ---------------- Flash attention (round-10 proven) + weight-cvt tail ----------------
// Swapped QK^T (lane owns one q), Q in registers, Ps half-reuse w/ lgkm WAR guard,
// distance-2 K/V pair prefetch (ring-4 K, counted vmcnt(8)). After the O store,
// each block converts its grid-stride slice of wo|w1|w3 fp32->bf16 (hidden under
// other blocks' attention compute; stream order guarantees readiness).
__global__ __launch_bounds__(256, 3)
void attn_k(const unsigned short* __restrict__ Q, const unsigned short* __restrict__ Kb,
            const unsigned short* __restrict__ Vb, unsigned short* __restrict__ O,
            const float* __restrict__ woS, unsigned short* __restrict__ woD,
            const float* __restrict__ w1S, unsigned short* __restrict__ w1D,
            const float* __restrict__ w3S, unsigned short* __restrict__ w3D)
{
  __shared__ unsigned short Ks[4][4096];   // ring-4 K tiles (32x128 swizzled) 32 KB
  __shared__ unsigned short Vt[2][4096];   // V^T pair, written from regs      16 KB
  __shared__ unsigned short Ps[2560];      // per-wave 16q x 32kv, stride 40    5 KB
  const int t = threadIdx.x, lane = t & 63, wid = t >> 6;
  const int bx = blockIdx.x;
  const int qt = bx & 31, h = (bx >> 5) & 31, b = bx >> 10;
  const int kvh = h >> 2;
  const float rs = 0.08838834764831845f;   // 1/sqrt(128)
  constexpr int NPAIR = SEQ / 64;          // 32

  const int q0 = wid * 16;
  const int qc = lane & 15;                // this lane's q (softmax layout)

  // Q fragments in registers: B-operand of swapped QK^T
  bf16x8_t qf[4];
  {
    const unsigned short* qrow = Q + (size_t)(b * SEQ + qt * 64 + q0 + qc) * DIM
                                   + h * HD + (lane >> 4) * 8;
#pragma unroll
    for (int ks = 0; ks < 4; ++ks) qf[ks] = *(const bf16x8_t*)(qrow + ks * 32);
  }

  const unsigned short* Kbase = Kb + (size_t)(b * SEQ) * (NKV * HD) + kvh * HD;
  const unsigned short* Vbase = Vb + (size_t)(b * SEQ) * (NKV * HD) + kvh * HD;

  auto stK = [&](int kt, int slot) {
#pragma unroll
    for (int oo = 0; oo < 2; ++oo) {
      const int o = wid * 2 + oo;
      const int row = o * 4 + (lane >> 4);
      const int gl  = (lane & 15) ^ (row & 7);
      gll16(Kbase + (size_t)(kt * 32 + row) * (NKV * HD) + gl * 8, &Ks[slot][o * 512]);
    }
  };
  const int kv = t >> 3, dc = (t & 7) << 4;
  const int colv = kv ^ ((t & 3) << 3);
  auto ldV = [&](int kt, int4& lo, int4& hi) {
    const unsigned short* gp = Vbase + (size_t)(kt * 32 + kv) * (NKV * HD) + dc;
    lo = *(const int4*)gp;
    hi = *(const int4*)(gp + 8);
  };
  auto wrV = [&](int slot, int4 vlo, int4 vhi) {
    union { int4 v; unsigned short u[8]; } lo, hi;
    lo.v = vlo; hi.v = vhi;
#pragma unroll
    for (int j = 0; j < 8; ++j) Vt[slot][(dc + j) * 32 + colv] = lo.u[j];
#pragma unroll
    for (int j = 0; j < 8; ++j) Vt[slot][(dc + 8 + j) * 32 + colv] = hi.u[j];
  };

  // prologue: pairs 0 (slots 0,1 / regset A) and 1 (slots 2,3 / regset B)
  int4 a0l, a0h, a1l, a1h, b0l, b0h, b1l, b1h;
  stK(0, 0); ldV(0, a0l, a0h); stK(1, 1); ldV(1, a1l, a1h);
  stK(2, 2); ldV(2, b0l, b0h); stK(3, 3); ldV(3, b1l, b1h);

  f32x4_t oa[8];
#pragma unroll
  for (int i = 0; i < 8; ++i) oa[i] = (f32x4_t)0.f;
  float mrun = -1e30f, lrun = 0.f;         // per-lane state for q = qc
  const int pbase = wid * 640 + qc * 40;   // Ps row base (stride-40 ushorts)
  const int pwr   = pbase + (lane >> 4) * 4;

  auto pack2 = [&](float x, float y) -> unsigned int {
    return (unsigned int)f2b(x) | ((unsigned int)f2b(y) << 16);
  };

  auto pairIter = [&](int p, int sb, int4& l0, int4& h0, int4& l1, int4& h1) {
    if (p == NPAIR - 1) { VM0; } else { VM8; }   // pair p (and qf at p=0) landed
    wrV(0, l0, h0);
    wrV(1, l1, h1);
    asm volatile("s_waitcnt lgkmcnt(0)" ::: "memory");
    __builtin_amdgcn_s_barrier();                 // pair staged, visible to all waves

    // S^T: lane holds q=qc, 16 kv values; 16 MFMA
    f32x4_t st[4];
    st[0] = (f32x4_t)0.f; st[1] = (f32x4_t)0.f;
    st[2] = (f32x4_t)0.f; st[3] = (f32x4_t)0.f;
    const int kr0 = qc, kr1 = 16 + qc;
    __builtin_amdgcn_s_setprio(1);
#pragma unroll
    for (int ks = 0; ks < 4; ++ks) {
      const bf16x8_t k00 = *(const bf16x8_t*)&Ks[sb][(kr0 * 128 + ks * 32 + (lane >> 4) * 8) ^ ((kr0 & 7) << 3)];
      st[0] = __builtin_amdgcn_mfma_f32_16x16x32_bf16(k00, qf[ks], st[0], 0, 0, 0);
      const bf16x8_t k01 = *(const bf16x8_t*)&Ks[sb][(kr1 * 128 + ks * 32 + (lane >> 4) * 8) ^ ((kr1 & 7) << 3)];
      st[1] = __builtin_amdgcn_mfma_f32_16x16x32_bf16(k01, qf[ks], st[1], 0, 0, 0);
      const bf16x8_t k10 = *(const bf16x8_t*)&Ks[sb + 1][(kr0 * 128 + ks * 32 + (lane >> 4) * 8) ^ ((kr0 & 7) << 3)];
      st[2] = __builtin_amdgcn_mfma_f32_16x16x32_bf16(k10, qf[ks], st[2], 0, 0, 0);
      const bf16x8_t k11 = *(const bf16x8_t*)&Ks[sb + 1][(kr1 * 128 + ks * 32 + (lane >> 4) * 8) ^ ((kr1 & 7) << 3)];
      st[3] = __builtin_amdgcn_mfma_f32_16x16x32_bf16(k11, qf[ks], st[3], 0, 0, 0);
    }
    __builtin_amdgcn_s_setprio(0);

    // softmax: in-lane reduce + 2 shfl_xor
    float mx01 = fmaxf(fmaxf(st[0][0], st[0][1]), fmaxf(st[0][2], st[0][3]));
    float mx23 = fmaxf(fmaxf(st[1][0], st[1][1]), fmaxf(st[1][2], st[1][3]));
    float mx45 = fmaxf(fmaxf(st[2][0], st[2][1]), fmaxf(st[2][2], st[2][3]));
    float mx67 = fmaxf(fmaxf(st[3][0], st[3][1]), fmaxf(st[3][2], st[3][3]));
    float pm = fmaxf(fmaxf(mx01, mx23), fmaxf(mx45, mx67)) * rs;
    pm = fmaxf(pm, __shfl_xor(pm, 16, 64));
    pm = fmaxf(pm, __shfl_xor(pm, 32, 64));

    const int grow = __any(pm > mrun);
    if (grow) {
      const float mnew = fmaxf(mrun, pm);
      const float corr = __expf(mrun - mnew);
      mrun = mnew;
      lrun *= corr;
      float c4[4];
#pragma unroll
      for (int r = 0; r < 4; ++r) c4[r] = __shfl(corr, (lane >> 4) * 4 + r, 16);
#pragma unroll
      for (int i = 0; i < 8; ++i)
#pragma unroll
        for (int r = 0; r < 4; ++r) oa[i][r] *= c4[r];
    }

    float ssum = 0.f;
#pragma unroll
    for (int tt = 0; tt < 4; ++tt)
#pragma unroll
      for (int r = 0; r < 4; ++r) {
        st[tt][r] = __expf(st[tt][r] * rs - mrun);
        ssum += st[tt][r];
      }
    ssum += __shfl_xor(ssum, 16, 64);
    ssum += __shfl_xor(ssum, 32, 64);
    lrun += ssum;

    // P^T half 0 (kv 0..31): packed u32 writes, read pa0
    *(unsigned int*)&Ps[pwr]      = pack2(st[0][0], st[0][1]);
    *(unsigned int*)&Ps[pwr + 2]  = pack2(st[0][2], st[0][3]);
    *(unsigned int*)&Ps[pwr + 16] = pack2(st[1][0], st[1][1]);
    *(unsigned int*)&Ps[pwr + 18] = pack2(st[1][2], st[1][3]);
    const bf16x8_t pa0 = *(const bf16x8_t*)&Ps[pbase + (lane >> 4) * 8];
    asm volatile("s_waitcnt lgkmcnt(0)" ::: "memory");   // pa0 read drained (WAR guard)
    // P^T half 1 (kv 32..63) overwrites the same region, read pa1
    *(unsigned int*)&Ps[pwr]      = pack2(st[2][0], st[2][1]);
    *(unsigned int*)&Ps[pwr + 2]  = pack2(st[2][2], st[2][3]);
    *(unsigned int*)&Ps[pwr + 16] = pack2(st[3][0], st[3][1]);
    *(unsigned int*)&Ps[pwr + 18] = pack2(st[3][2], st[3][3]);
    const bf16x8_t pa1 = *(const bf16x8_t*)&Ps[pbase + (lane >> 4) * 8];

    __builtin_amdgcn_s_setprio(1);
#pragma unroll
    for (int nt2 = 0; nt2 < 8; ++nt2) {
      const bf16x8_t vf0 = *(const bf16x8_t*)&Vt[0][(nt2 * 16 + (lane & 15)) * 32 + (((lane >> 4) ^ (nt2 & 3)) << 3)];
      oa[nt2] = __builtin_amdgcn_mfma_f32_16x16x32_bf16(pa0, vf0, oa[nt2], 0, 0, 0);
      const bf16x8_t vf1 = *(const bf16x8_t*)&Vt[1][(nt2 * 16 + (lane & 15)) * 32 + (((lane >> 4) ^ (nt2 & 3)) << 3)];
      oa[nt2] = __builtin_amdgcn_mfma_f32_16x16x32_bf16(pa1, vf1, oa[nt2], 0, 0, 0);
    }
    __builtin_amdgcn_s_setprio(0);
    __builtin_amdgcn_s_barrier();                 // all waves done with Ks[sb..sb+1], Vt
    if (p + 2 < NPAIR) {
      stK(2 * p + 4, sb);     ldV(2 * p + 4, l0, h0);
      stK(2 * p + 5, sb + 1); ldV(2 * p + 5, l1, h1);
    }
  };

  for (int j = 0; j < NPAIR / 2; ++j) {
    pairIter(2 * j,     0, a0l, a0h, a1l, a1h);
    pairIter(2 * j + 1, 2, b0l, b0h, b1l, b1h);
  }

  // broadcast l (q-layout) into oa row layout, normalize, store
  float inv[4];
#pragma unroll
  for (int r = 0; r < 4; ++r) inv[r] = 1.f / __shfl(lrun, (lane >> 4) * 4 + r, 16);
#pragma unroll
  for (int nt2 = 0; nt2 < 8; ++nt2) {
    const int col = h * HD + nt2 * 16 + (lane & 15);
#pragma unroll
    for (int r = 0; r < 4; ++r) {
      const int row = qt * 64 + q0 + (lane >> 4) * 4 + r;
      O[(size_t)(b * SEQ + row) * DIM + col] = f2b(oa[nt2][r] * inv[r]);
    }
  }

  // ---- weight-conversion tail: wo | w1 | w3 fp32 -> bf16 ----
  // boundaries: wo = 16,777,216 elems; +w1 45,088,768 -> 61,865,984; +w3 -> 106,954,752
  {
    const size_t gt = (size_t)bx * 256 + t;
    for (size_t e = gt * 8; e < 106954752ull; e += 8ull * 1048576ull) {
      const float* src; unsigned short* dst; size_t o;
      if (e < 16777216ull)      { src = woS; dst = woD; o = e; }
      else if (e < 61865984ull) { src = w1S; dst = w1D; o = e - 16777216ull; }
      else                      { src = w3S; dst = w3D; o = e - 61865984ull; }
      const float4 va = *(const float4*)&src[o];
      const float4 vb = *(const float4*)&src[o + 4];
      union { int4 v; unsigned short u[8]; } ov;
      ov.u[0] = f2b(va.x); ov.u[1] = f2b(va.y); ov.u[2] = f2b(va.z); ov.u[3] = f2b(va.w);
      ov.u[4] = f2b(vb.x); ov.u[5] = f2b(vb.y); ov.u[6] = f2b(vb.z); ov.u[7] = f2b(vb.w);
      *(int4*)&dst[o] = ov.v;
    }
  }
}

// ---------------- launch ----------------
extern "C" void kernel_launch(void* const* d_in, const int* in_sizes, int n_in,
                              void* d_out, int out_size, void* d_ws, size_t ws_size,
                              hipStream_t stream)
{
  (void)in_sizes; (void)n_in; (void)out_size; (void)ws_size;
  const float* x   = (const float*)d_in[0];
  const float* fr  = (const float*)d_in[1];
  const float* ga  = (const float*)d_in[3];
  const float* gf  = (const float*)d_in[4];
  const float* wq  = (const float*)d_in[5];
  const float* wqb = (const float*)d_in[6];
  const float* wk  = (const float*)d_in[7];
  const float* wkb = (const float*)d_in[8];
  const float* wv  = (const float*)d_in[9];
  const float* wvb = (const float*)d_in[10];
  const float* wo  = (const float*)d_in[11];
  const float* wob = (const float*)d_in[12];
  const float* w1  = (const float*)d_in[13];
  const float* w3  = (const float*)d_in[14];
  const float* w2  = (const float*)d_in[15];
  float* out = (float*)d_out;

  constexpr size_t MB = 1ull << 20;
  char* ws = (char*)d_ws;
  unsigned short* xn = (unsigned short*)(ws);              // [0,64) MiB
  unsigned short* qb = (unsigned short*)(ws + 64*MB);      // [64,128)
  unsigned short* kb = (unsigned short*)(ws + 128*MB);     // [128,144)
  unsigned short* vb = (unsigned short*)(ws + 144*MB);     // [144,160)
  unsigned short* ao = (unsigned short*)(ws + 160*MB);     // [160,224)
  unsigned short* hn = (unsigned short*)(ws + 224*MB);     // [224,288)
  unsigned short* g  = (unsigned short*)(ws);              // [0,172) alias (dead by FFN time)
  unsigned short* wscr = (unsigned short*)(ws + 288*MB);   // JIT bf16 weights
  unsigned short* wqB = wscr;                               // 32 MiB
  unsigned short* wkB = wscr + 16*MB;                       // 8 MiB (elem offsets)
  unsigned short* wvB = wscr + 20*MB;                       // 8 MiB
  unsigned short* woB = (unsigned short*)(ws);              // 32 MiB, in dead xn (attn tail fills)
  unsigned short* w1B = wscr;                               // 86 MiB (attn tail fills)
  unsigned short* w3B = wscr + 46*MB;                       // 86 MiB (attn tail fills)
  unsigned short* w2B = wscr;                               // 86 MiB (cvt after w13; aliases w1B)

  rmsnorm_k<<<MTOT, 256, 0, stream>>>(x, ga, xn);
  cvt_bf16_k<<<(NH*HD*DIM)/2048,  256, 0, stream>>>(wq, wqB);
  cvt_bf16_k<<<(NKV*HD*DIM)/2048, 256, 0, stream>>>(wk, wkB);
  cvt_bf16_k<<<(NKV*HD*DIM)/2048, 256, 0, stream>>>(wv, wvB);
  gemm256<0><<<(MTOT/256)*((DIM+2*NKV*HD)/256), 512, 0, stream>>>(
      xn, wqB, nullptr, wqb, nullptr, nullptr, qb,
      wkB, wvB, wkb, wvb, kb, vb, DIM);
  rope_k<NH><<<(MTOT*NH*16)/256,  256, 0, stream>>>(qb, fr);
  rope_k<NKV><<<(MTOT*NKV*16)/256,256, 0, stream>>>(kb, fr);
  attn_k<<<BATCH*NH*(SEQ/64), 256, 0, stream>>>(qb, kb, vb, ao,
      wo, woB, w1, w1B, w3, w3B);
  gemm256<1><<<(MTOT/256)*(DIM/256), 512, 0, stream>>>(
      ao, woB, nullptr, wob, x, out, nullptr,
      nullptr, nullptr, nullptr, nullptr, nullptr, nullptr, DIM);
  rmsnorm_k<<<MTOT, 256, 0, stream>>>(out, gf, hn);
  gemm256<3><<<(MTOT/256)*(FFNH/128), 512, 0, stream>>>(
      hn, w1B, w3B, nullptr, nullptr, nullptr, g,
      nullptr, nullptr, nullptr, nullptr, nullptr, nullptr, DIM);
  cvt_bf16_k<<<(FFNH*DIM)/2048, 256, 0, stream>>>(w2, w2B);
  gemm256<2><<<(MTOT/256)*(DIM/256), 512, 0, stream>>>(
      g, w2B, nullptr, nullptr, out, out, nullptr,
      nullptr, nullptr, nullptr, nullptr, nullptr, nullptr, FFNH);
}

// Round 14
// 3466.167 us; speedup vs baseline: 1.0955x; 1.0480x over previous
//
#include <hip/hip_runtime.h>
#include <hip/hip_bf16.h>

#define DIM   4096
#define NH    32
#define NKV   8
#define HD    128
#define FFNH  11008
#define BATCH 4
#define SEQ   2048
#define MTOT  (BATCH*SEQ)   // 8192

using bf16x8_t = __attribute__((ext_vector_type(8))) short;
using f32x4_t  = __attribute__((ext_vector_type(4))) float;

typedef const __attribute__((address_space(1))) unsigned int GlbU32;
typedef __attribute__((address_space(3))) unsigned int LdsU32;

__device__ __forceinline__ unsigned short f2b(float f) {
  union { float f; unsigned int u; } v; v.f = f;
  return (unsigned short)((v.u + 0x7fffu + ((v.u >> 16) & 1u)) >> 16);
}
__device__ __forceinline__ float b2f(unsigned short b) {
  union { unsigned int u; float f; } v; v.u = ((unsigned int)b) << 16;
  return v.f;
}
__device__ __forceinline__ void gll16(const void* g, void* l) {
  __builtin_amdgcn_global_load_lds((GlbU32*)g, (LdsU32*)l, 16, 0, 0);
}

#define VM8  asm volatile("s_waitcnt vmcnt(8)" ::: "memory")
#define VM4M asm volatile("s_waitcnt vmcnt(4)" ::: "memory")
#define VM0  asm volatile("s_waitcnt vmcnt(0)" ::: "memory")

// ---------------- fp32 -> bf16 bulk convert ----------------
__global__ __launch_bounds__(256)
void cvt_bf16_k(const float* __restrict__ src, unsigned short* __restrict__ dst)
{
  const size_t i = ((size_t)blockIdx.x * 256 + threadIdx.x) * 8;
  const float4 a = *(const float4*)&src[i];
  const float4 b = *(const float4*)&src[i + 4];
  union { int4 v; unsigned short u[8]; } o;
  o.u[0] = f2b(a.x); o.u[1] = f2b(a.y); o.u[2] = f2b(a.z); o.u[3] = f2b(a.w);
  o.u[4] = f2b(b.x); o.u[5] = f2b(b.y); o.u[6] = f2b(b.z); o.u[7] = f2b(b.w);
  *(int4*)&dst[i] = o.v;
}

// ---------------- RMSNorm: fp32 in -> bf16 out ----------------
__global__ __launch_bounds__(256)
void rmsnorm_k(const float* __restrict__ X, const float* __restrict__ gamma,
               unsigned short* __restrict__ Y)
{
  const int row = blockIdx.x, t = threadIdx.x;
  const float* xr = X + (size_t)row * DIM;
  float4 v[4];
  float ss = 0.f;
#pragma unroll
  for (int p = 0; p < 4; ++p) {
    v[p] = *(const float4*)&xr[p * 1024 + t * 4];
    ss += v[p].x*v[p].x + v[p].y*v[p].y + v[p].z*v[p].z + v[p].w*v[p].w;
  }
#pragma unroll
  for (int off = 32; off >= 1; off >>= 1) ss += __shfl_xor(ss, off, 64);
  __shared__ float red[4];
  if ((t & 63) == 0) red[t >> 6] = ss;
  __syncthreads();
  const float tot = red[0] + red[1] + red[2] + red[3];
  const float rn = rsqrtf(tot * (1.f / DIM) + 1e-6f);
  unsigned short* yr = Y + (size_t)row * DIM;
#pragma unroll
  for (int p = 0; p < 4; ++p) {
    const float4 gv = *(const float4*)&gamma[p * 1024 + t * 4];
    short4 o;
    o.x = (short)f2b(v[p].x * gv.x * rn);
    o.y = (short)f2b(v[p].y * gv.y * rn);
    o.z = (short)f2b(v[p].z * gv.z * rn);
    o.w = (short)f2b(v[p].w * gv.w * rn);
    *(short4*)&yr[p * 1024 + t * 4] = o;
  }
}

// ---------------- RoPE in-place on bf16 [rows][NHT*128] ----------------
template<int NHT>
__global__ __launch_bounds__(256)
void rope_k(unsigned short* __restrict__ buf, const float* __restrict__ fr)
{
  const int u = blockIdx.x * 256 + threadIdx.x;
  const int per_row = NHT * 16;
  const int row  = u / per_row;
  const int rem  = u - row * per_row;
  const int head = rem >> 4;
  const int i4   = (rem & 15) << 2;
  const int s    = row & (SEQ - 1);
  unsigned short* p = buf + (size_t)row * (NHT * HD) + head * HD + i4 * 2;
  union { int4 v; unsigned short u16[8]; } d;
  d.v = *(const int4*)p;
  const float4 f = *(const float4*)&fr[s * 64 + i4];
  const float fa[4] = {f.x, f.y, f.z, f.w};
#pragma unroll
  for (int i = 0; i < 4; ++i) {
    float sn, c;
    __sincosf(fa[i], &sn, &c);
    const float x0 = b2f(d.u16[2*i]), x1 = b2f(d.u16[2*i+1]);
    d.u16[2*i]   = f2b(x0 * c - x1 * sn);
    d.u16[2*i+1] = f2b(x0 * sn + x1 * c);
  }
  *(int4*)p = d.v;
}

// ======================= 256x256 GEMM, 2 barriers / K=32 phase (round-6 proven) ===========
template<int MODE>
__global__ __launch_bounds__(512)
void gemm256(const unsigned short* __restrict__ A,
             const unsigned short* __restrict__ W,
             const unsigned short* __restrict__ W3p,
             const float* __restrict__ bias,
             const float* res,
             float* outF,
             unsigned short* __restrict__ outH,
             const unsigned short* __restrict__ wkp,
             const unsigned short* __restrict__ wvp,
             const float* __restrict__ bkp,
             const float* __restrict__ bvp,
             unsigned short* __restrict__ okp,
             unsigned short* __restrict__ ovp,
             int K)
{
  __shared__ __align__(16) char smem[131072];
  const int t = threadIdx.x, lane = t & 63, wid = t >> 6;
  const int wr = wid >> 2, wc = wid & 3;
  const int G = gridDim.x, bid = blockIdx.x;
  const int wg = (bid & 7) * (G >> 3) + (bid >> 3);   // XCD-chunked
  const int NBN = G >> 5;                             // NBM = 32 (M = 8192)
  const int span = NBN << 3;                          // TMG = 8
  const int tmg = wg / span, rr = wg - tmg * span;
  const int tn = rr >> 3, tm = (tmg << 3) + (rr & 7);
  const int m0 = tm << 8;
  const int NSUB = K >> 5;

  const unsigned short *P1, *P2;
  const float* bp = bias;
  unsigned short* oh = outH;
  int nloc = 0, colsN = 4096;
  if constexpr (MODE == 0) {
    const int n0 = tn << 8;
    if (n0 < 4096)      { nloc = n0;        P1 = W   + (size_t)nloc * K; bp = bias; oh = outH; colsN = 4096; }
    else if (n0 < 5120) { nloc = n0 - 4096; P1 = wkp + (size_t)nloc * K; bp = bkp;  oh = okp;  colsN = 1024; }
    else                { nloc = n0 - 5120; P1 = wvp + (size_t)nloc * K; bp = bvp;  oh = ovp;  colsN = 1024; }
    P2 = P1 + (size_t)128 * K;
  } else if constexpr (MODE == 3) {
    const int n0w = tn << 7;
    P1 = W   + (size_t)n0w * K;
    P2 = W3p + (size_t)n0w * K;
    nloc = n0w;
  } else {
    const int n0 = tn << 8;
    P1 = W + (size_t)n0 * K;
    P2 = P1 + (size_t)128 * K;
    nloc = n0;
  }

  const int r0 = t >> 2, gg = t & 3;
  const int gsw = gg ^ ((r0 >> 1) & 3);

  auto stA = [&](int sig) {
    if (sig < NSUB) {
      const int slot = sig & 3;
      gll16(A + (size_t)(m0 + r0) * K + sig * 32 + gsw * 8,
            smem + slot * 16384 + wid * 1024);
      gll16(A + (size_t)(m0 + 128 + r0) * K + sig * 32 + gsw * 8,
            smem + slot * 16384 + 8192 + wid * 1024);
    }
  };
  auto stB = [&](int sig) {
    if (sig < NSUB) {
      const int slot = sig & 3;
      gll16(P1 + (size_t)r0 * K + sig * 32 + gsw * 8,
            smem + 65536 + slot * 16384 + wid * 1024);
      gll16(P2 + (size_t)r0 * K + sig * 32 + gsw * 8,
            smem + 65536 + slot * 16384 + 8192 + wid * 1024);
    }
  };
  auto rdA = [&](int slot, int mo) -> bf16x8_t {
    const int lrow = wr * 128 + mo + (lane & 15);
    const int g = (lane >> 4) ^ ((lrow >> 1) & 3);
    return *(const bf16x8_t*)(smem + slot * 16384 + lrow * 64 + g * 16);
  };
  auto rdB = [&](int slot, int nf) -> bf16x8_t {
    const int brow = wc * 64 + nf * 16 + (lane & 15);
    const int g = (lane >> 4) ^ ((brow >> 1) & 3);
    return *(const bf16x8_t*)(smem + 65536 + slot * 16384 + brow * 64 + g * 16);
  };

  f32x4_t acc[8][4];
#pragma unroll
  for (int i = 0; i < 8; ++i)
#pragma unroll
    for (int j = 0; j < 4; ++j) acc[i][j] = (f32x4_t)0.f;

  stA(0); stB(0); stA(1); stB(1); stA(2); stB(2);
  VM8;
  __builtin_amdgcn_s_barrier();

  for (int p = 0; p < NSUB; ++p) {
    const int slot = p & 3;
    bf16x8_t bfv[4], afv[8];
#pragma unroll
    for (int n = 0; n < 4; ++n) bfv[n] = rdB(slot, n);
#pragma unroll
    for (int m = 0; m < 8; ++m) afv[m] = rdA(slot, m * 16);
    stA(p + 3); stB(p + 3);
    __builtin_amdgcn_s_setprio(1);
#pragma unroll
    for (int m = 0; m < 8; ++m)
#pragma unroll
      for (int n = 0; n < 4; ++n)
        acc[m][n] = __builtin_amdgcn_mfma_f32_16x16x32_bf16(afv[m], bfv[n], acc[m][n], 0, 0, 0);
    __builtin_amdgcn_s_setprio(0);
    if (p < NSUB - 3)      { VM8; }
    else if (p == NSUB - 3){ VM4M; }
    else                   { VM0; }
    __builtin_amdgcn_s_barrier();
  }

  if constexpr (MODE == 0) {
#pragma unroll
    for (int ni = 0; ni < 4; ++ni) {
      const int col = nloc + wc * 64 + ni * 16 + (lane & 15);
      const float bv = bp[col];
#pragma unroll
      for (int mi = 0; mi < 8; ++mi)
#pragma unroll
        for (int r = 0; r < 4; ++r) {
          const int row = m0 + wr * 128 + mi * 16 + (lane >> 4) * 4 + r;
          oh[(size_t)row * colsN + col] = f2b(acc[mi][ni][r] + bv);
        }
    }
  } else if constexpr (MODE == 1 || MODE == 2) {
#pragma unroll
    for (int ni = 0; ni < 4; ++ni) {
      const int col = nloc + wc * 64 + ni * 16 + (lane & 15);
      float bv = 0.f;
      if constexpr (MODE == 1) bv = bias[col];
#pragma unroll
      for (int mi = 0; mi < 8; ++mi)
#pragma unroll
        for (int r = 0; r < 4; ++r) {
          const int row = m0 + wr * 128 + mi * 16 + (lane >> 4) * 4 + r;
          const size_t idx = (size_t)row * 4096 + col;
          outF[idx] = acc[mi][ni][r] + bv + res[idx];
        }
    }
  } else {
    if (wc >= 2) {
      const int widx = wr * 2 + (wc - 2);
#pragma unroll
      for (int ni = 0; ni < 4; ++ni)
#pragma unroll
        for (int mi = 0; mi < 8; ++mi)
#pragma unroll
          for (int r = 0; r < 4; ++r) {
            const int lrow = mi * 16 + (lane >> 4) * 4 + r;
            const int ncol = ni * 16 + (lane & 15);
            *(unsigned short*)(smem + widx * 16384 + lrow * 128 + ncol * 2) =
                f2b(acc[mi][ni][r]);
          }
    }
    __syncthreads();
    if (wc < 2) {
      const int widx = wr * 2 + wc;
#pragma unroll
      for (int ni = 0; ni < 4; ++ni)
#pragma unroll
        for (int mi = 0; mi < 8; ++mi)
#pragma unroll
          for (int r = 0; r < 4; ++r) {
            const int lrow = mi * 16 + (lane >> 4) * 4 + r;
            const int ncol = ni * 16 + (lane & 15);
            const float s3 = b2f(*(const unsigned short*)(smem + widx * 16384 + lrow * 128 + ncol * 2));
            const float s1 = acc[mi][ni][r];
            const float sig = 1.f / (1.f + __expf(-s1));
            const int row = m0 + wr * 128 + lrow;
            outH[(size_t)row * FFNH + nloc + wc * 64 + ncol] = f2b(s1 * sig * s3);
          }
    }
  }
}

// ---------------- Flash attention: QBLK=128, 8 waves, 2 blocks/CU + cvt tail ----------------
// Per-wave inner structure identical to the round-10 proven version (swapped QK^T,
// Q in regs, Ps half-reuse w/ lgkm WAR guard). K/V staging amortized over 128 q-rows:
// stK = 1 gll16/thread, ldV = 1 int4/thread; 4 vmem ops/pair -> counted vmcnt(4).
__global__ __launch_bounds__(512, 4)
void attn_k(const unsigned short* __restrict__ Q, const unsigned short* __restrict__ Kb,
            const unsigned short* __restrict__ Vb, unsigned short* __restrict__ O,
            const float* __restrict__ woS, unsigned short* __restrict__ woD,
            const float* __restrict__ w1S, unsigned short* __restrict__ w1D,
            const float* __restrict__ w3S, unsigned short* __restrict__ w3D)
{
  __shared__ unsigned short Ks[4][4096];   // ring-4 K tiles (32x128 swizzled) 32 KB
  __shared__ unsigned short Vt[2][4096];   // V^T pair                          16 KB
  __shared__ unsigned short Ps[5120];      // 8 waves x 16q x 32kv stride 40    10 KB
  const int t = threadIdx.x, lane = t & 63, wid = t >> 6;   // wid 0..7
  const int bx = blockIdx.x;
  const int qt = bx & 15, h = (bx >> 4) & 31, b = bx >> 9;
  const int kvh = h >> 2;
  const float rs = 0.08838834764831845f;   // 1/sqrt(128)
  constexpr int NPAIR = SEQ / 64;          // 32

  const int q0 = wid * 16;                 // 0..112
  const int qc = lane & 15;                // this lane's q (softmax layout)

  // Q fragments in registers: B-operand of swapped QK^T (issued first = oldest vmem)
  bf16x8_t qf[4];
  {
    const unsigned short* qrow = Q + (size_t)(b * SEQ + qt * 128 + q0 + qc) * DIM
                                   + h * HD + (lane >> 4) * 8;
#pragma unroll
    for (int ks = 0; ks < 4; ++ks) qf[ks] = *(const bf16x8_t*)(qrow + ks * 32);
  }

  const unsigned short* Kbase = Kb + (size_t)(b * SEQ) * (NKV * HD) + kvh * HD;
  const unsigned short* Vbase = Vb + (size_t)(b * SEQ) * (NKV * HD) + kvh * HD;

  auto stK = [&](int kt, int slot) {       // 512 threads x 16B = 8KB tile
    const int row = t >> 4;                // 0..31
    const int gl  = (t & 15) ^ (row & 7);  // pre-swizzled source granule
    gll16(Kbase + (size_t)(kt * 32 + row) * (NKV * HD) + gl * 8, &Ks[slot][(size_t)t * 8]);
  };
  const int kv = t >> 4;                   // 0..31
  const int d0 = (t & 15) * 8;             // 0..120 (8-row span, never crosses 16)
  const int colv = kv ^ (((d0 >> 4) & 3) << 3);
  auto ldV = [&](int kt, int4& w) {
    w = *(const int4*)(Vbase + (size_t)(kt * 32 + kv) * (NKV * HD) + d0);
  };
  auto wrV = [&](int slot, int4 w) {
    union { int4 v; unsigned short u[8]; } u; u.v = w;
#pragma unroll
    for (int j = 0; j < 8; ++j) Vt[slot][(d0 + j) * 32 + colv] = u.u[j];
  };

  // prologue: pair 0 (K slots 0,1) and pair 1 (K slots 2,3)
  int4 a0, a1, b0, b1;
  stK(0, 0); stK(1, 1); ldV(0, a0); ldV(1, a1);
  stK(2, 2); stK(3, 3); ldV(2, b0); ldV(3, b1);

  f32x4_t oa[8];
#pragma unroll
  for (int i = 0; i < 8; ++i) oa[i] = (f32x4_t)0.f;
  float mrun = -1e30f, lrun = 0.f;         // per-lane state for q = qc
  const int pbase = wid * 640 + qc * 40;   // Ps row base (stride-40 ushorts)
  const int pwr   = pbase + (lane >> 4) * 4;

  auto pack2 = [&](float x, float y) -> unsigned int {
    return (unsigned int)f2b(x) | ((unsigned int)f2b(y) << 16);
  };

  auto pairIter = [&](int p, int sb, int4& l0, int4& l1) {
    if (p == NPAIR - 1) { VM0; } else { VM4M; }   // pair p (and qf at p=0) landed
    wrV(0, l0);
    wrV(1, l1);
    asm volatile("s_waitcnt lgkmcnt(0)" ::: "memory");
    __builtin_amdgcn_s_barrier();                 // pair staged, visible to all waves

    // S^T: lane holds q=qc, 16 kv values; 16 MFMA
    f32x4_t st[4];
    st[0] = (f32x4_t)0.f; st[1] = (f32x4_t)0.f;
    st[2] = (f32x4_t)0.f; st[3] = (f32x4_t)0.f;
    const int kr0 = qc, kr1 = 16 + qc;
    __builtin_amdgcn_s_setprio(1);
#pragma unroll
    for (int ks = 0; ks < 4; ++ks) {
      const bf16x8_t k00 = *(const bf16x8_t*)&Ks[sb][(kr0 * 128 + ks * 32 + (lane >> 4) * 8) ^ ((kr0 & 7) << 3)];
      st[0] = __builtin_amdgcn_mfma_f32_16x16x32_bf16(k00, qf[ks], st[0], 0, 0, 0);
      const bf16x8_t k01 = *(const bf16x8_t*)&Ks[sb][(kr1 * 128 + ks * 32 + (lane >> 4) * 8) ^ ((kr1 & 7) << 3)];
      st[1] = __builtin_amdgcn_mfma_f32_16x16x32_bf16(k01, qf[ks], st[1], 0, 0, 0);
      const bf16x8_t k10 = *(const bf16x8_t*)&Ks[sb + 1][(kr0 * 128 + ks * 32 + (lane >> 4) * 8) ^ ((kr0 & 7) << 3)];
      st[2] = __builtin_amdgcn_mfma_f32_16x16x32_bf16(k10, qf[ks], st[2], 0, 0, 0);
      const bf16x8_t k11 = *(const bf16x8_t*)&Ks[sb + 1][(kr1 * 128 + ks * 32 + (lane >> 4) * 8) ^ ((kr1 & 7) << 3)];
      st[3] = __builtin_amdgcn_mfma_f32_16x16x32_bf16(k11, qf[ks], st[3], 0, 0, 0);
    }
    __builtin_amdgcn_s_setprio(0);

    // softmax: in-lane reduce + 2 shfl_xor
    float mx01 = fmaxf(fmaxf(st[0][0], st[0][1]), fmaxf(st[0][2], st[0][3]));
    float mx23 = fmaxf(fmaxf(st[1][0], st[1][1]), fmaxf(st[1][2], st[1][3]));
    float mx45 = fmaxf(fmaxf(st[2][0], st[2][1]), fmaxf(st[2][2], st[2][3]));
    float mx67 = fmaxf(fmaxf(st[3][0], st[3][1]), fmaxf(st[3][2], st[3][3]));
    float pm = fmaxf(fmaxf(mx01, mx23), fmaxf(mx45, mx67)) * rs;
    pm = fmaxf(pm, __shfl_xor(pm, 16, 64));
    pm = fmaxf(pm, __shfl_xor(pm, 32, 64));

    const int grow = __any(pm > mrun);
    if (grow) {
      const float mnew = fmaxf(mrun, pm);
      const float corr = __expf(mrun - mnew);
      mrun = mnew;
      lrun *= corr;
      float c4[4];
#pragma unroll
      for (int r = 0; r < 4; ++r) c4[r] = __shfl(corr, (lane >> 4) * 4 + r, 16);
#pragma unroll
      for (int i = 0; i < 8; ++i)
#pragma unroll
        for (int r = 0; r < 4; ++r) oa[i][r] *= c4[r];
    }

    float ssum = 0.f;
#pragma unroll
    for (int tt = 0; tt < 4; ++tt)
#pragma unroll
      for (int r = 0; r < 4; ++r) {
        st[tt][r] = __expf(st[tt][r] * rs - mrun);
        ssum += st[tt][r];
      }
    ssum += __shfl_xor(ssum, 16, 64);
    ssum += __shfl_xor(ssum, 32, 64);
    lrun += ssum;

    // P^T half 0 (kv 0..31): packed u32 writes, read pa0
    *(unsigned int*)&Ps[pwr]      = pack2(st[0][0], st[0][1]);
    *(unsigned int*)&Ps[pwr + 2]  = pack2(st[0][2], st[0][3]);
    *(unsigned int*)&Ps[pwr + 16] = pack2(st[1][0], st[1][1]);
    *(unsigned int*)&Ps[pwr + 18] = pack2(st[1][2], st[1][3]);
    const bf16x8_t pa0 = *(const bf16x8_t*)&Ps[pbase + (lane >> 4) * 8];
    asm volatile("s_waitcnt lgkmcnt(0)" ::: "memory");   // pa0 read drained (WAR guard)
    // P^T half 1 (kv 32..63) overwrites the same region, read pa1
    *(unsigned int*)&Ps[pwr]      = pack2(st[2][0], st[2][1]);
    *(unsigned int*)&Ps[pwr + 2]  = pack2(st[2][2], st[2][3]);
    *(unsigned int*)&Ps[pwr + 16] = pack2(st[3][0], st[3][1]);
    *(unsigned int*)&Ps[pwr + 18] = pack2(st[3][2], st[3][3]);
    const bf16x8_t pa1 = *(const bf16x8_t*)&Ps[pbase + (lane >> 4) * 8];

    __builtin_amdgcn_s_setprio(1);
#pragma unroll
    for (int nt2 = 0; nt2 < 8; ++nt2) {
      const bf16x8_t vf0 = *(const bf16x8_t*)&Vt[0][(nt2 * 16 + (lane & 15)) * 32 + (((lane >> 4) ^ (nt2 & 3)) << 3)];
      oa[nt2] = __builtin_amdgcn_mfma_f32_16x16x32_bf16(pa0, vf0, oa[nt2], 0, 0, 0);
      const bf16x8_t vf1 = *(const bf16x8_t*)&Vt[1][(nt2 * 16 + (lane & 15)) * 32 + (((lane >> 4) ^ (nt2 & 3)) << 3)];
      oa[nt2] = __builtin_amdgcn_mfma_f32_16x16x32_bf16(pa1, vf1, oa[nt2], 0, 0, 0);
    }
    __builtin_amdgcn_s_setprio(0);
    __builtin_amdgcn_s_barrier();                 // all waves done with Ks[sb..sb+1], Vt
    if (p + 2 < NPAIR) {
      stK(2 * p + 4, sb);     stK(2 * p + 5, sb + 1);
      ldV(2 * p + 4, l0);     ldV(2 * p + 5, l1);
    }
  };

  for (int j = 0; j < NPAIR / 2; ++j) {
    pairIter(2 * j,     0, a0, a1);
    pairIter(2 * j + 1, 2, b0, b1);
  }

  // broadcast l (q-layout) into oa row layout, normalize, store
  float inv[4];
#pragma unroll
  for (int r = 0; r < 4; ++r) inv[r] = 1.f / __shfl(lrun, (lane >> 4) * 4 + r, 16);
#pragma unroll
  for (int nt2 = 0; nt2 < 8; ++nt2) {
    const int col = h * HD + nt2 * 16 + (lane & 15);
#pragma unroll
    for (int r = 0; r < 4; ++r) {
      const int row = qt * 128 + q0 + (lane >> 4) * 4 + r;
      O[(size_t)(b * SEQ + row) * DIM + col] = f2b(oa[nt2][r] * inv[r]);
    }
  }

  // ---- weight-conversion tail: wo | w1 | w3 fp32 -> bf16 ----
  // boundaries: wo = 16,777,216 elems; +w1 45,088,768 -> 61,865,984; +w3 -> 106,954,752
  {
    const size_t gt = (size_t)bx * 512 + t;     // 2048 blocks x 512 = 1,048,576 threads
    for (size_t e = gt * 8; e < 106954752ull; e += 8ull * 1048576ull) {
      const float* src; unsigned short* dst; size_t o;
      if (e < 16777216ull)      { src = woS; dst = woD; o = e; }
      else if (e < 61865984ull) { src = w1S; dst = w1D; o = e - 16777216ull; }
      else                      { src = w3S; dst = w3D; o = e - 61865984ull; }
      const float4 va = *(const float4*)&src[o];
      const float4 vb = *(const float4*)&src[o + 4];
      union { int4 v; unsigned short u[8]; } ov;
      ov.u[0] = f2b(va.x); ov.u[1] = f2b(va.y); ov.u[2] = f2b(va.z); ov.u[3] = f2b(va.w);
      ov.u[4] = f2b(vb.x); ov.u[5] = f2b(vb.y); ov.u[6] = f2b(vb.z); ov.u[7] = f2b(vb.w);
      *(int4*)&dst[o] = ov.v;
    }
  }
}

// ---------------- launch ----------------
extern "C" void kernel_launch(void* const* d_in, const int* in_sizes, int n_in,
                              void* d_out, int out_size, void* d_ws, size_t ws_size,
                              hipStream_t stream)
{
  (void)in_sizes; (void)n_in; (void)out_size; (void)ws_size;
  const float* x   = (const float*)d_in[0];
  const float* fr  = (const float*)d_in[1];
  const float* ga  = (const float*)d_in[3];
  const float* gf  = (const float*)d_in[4];
  const float* wq  = (const float*)d_in[5];
  const float* wqb = (const float*)d_in[6];
  const float* wk  = (const float*)d_in[7];
  const float* wkb = (const float*)d_in[8];
  const float* wv  = (const float*)d_in[9];
  const float* wvb = (const float*)d_in[10];
  const float* wo  = (const float*)d_in[11];
  const float* wob = (const float*)d_in[12];
  const float* w1  = (const float*)d_in[13];
  const float* w3  = (const float*)d_in[14];
  const float* w2  = (const float*)d_in[15];
  float* out = (float*)d_out;

  constexpr size_t MB = 1ull << 20;
  char* ws = (char*)d_ws;
  unsigned short* xn = (unsigned short*)(ws);              // [0,64) MiB
  unsigned short* qb = (unsigned short*)(ws + 64*MB);      // [64,128)
  unsigned short* kb = (unsigned short*)(ws + 128*MB);     // [128,144)
  unsigned short* vb = (unsigned short*)(ws + 144*MB);     // [144,160)
  unsigned short* ao = (unsigned short*)(ws + 160*MB);     // [160,224)
  unsigned short* hn = (unsigned short*)(ws + 224*MB);     // [224,288)
  unsigned short* g  = (unsigned short*)(ws);              // [0,172) alias (dead by FFN time)
  unsigned short* wscr = (unsigned short*)(ws + 288*MB);   // JIT bf16 weights
  unsigned short* wqB = wscr;                               // 32 MiB
  unsigned short* wkB = wscr + 16*MB;                       // 8 MiB (elem offsets)
  unsigned short* wvB = wscr + 20*MB;                       // 8 MiB
  unsigned short* woB = (unsigned short*)(ws);              // 32 MiB, in dead xn (attn tail fills)
  unsigned short* w1B = wscr;                               // 86 MiB (attn tail fills)
  unsigned short* w3B = wscr + 46*MB;                       // 86 MiB (attn tail fills)
  unsigned short* w2B = wscr;                               // 86 MiB (cvt after w13; aliases w1B)

  rmsnorm_k<<<MTOT, 256, 0, stream>>>(x, ga, xn);
  cvt_bf16_k<<<(NH*HD*DIM)/2048,  256, 0, stream>>>(wq, wqB);
  cvt_bf16_k<<<(NKV*HD*DIM)/2048, 256, 0, stream>>>(wk, wkB);
  cvt_bf16_k<<<(NKV*HD*DIM)/2048, 256, 0, stream>>>(wv, wvB);
  gemm256<0><<<(MTOT/256)*((DIM+2*NKV*HD)/256), 512, 0, stream>>>(
      xn, wqB, nullptr, wqb, nullptr, nullptr, qb,
      wkB, wvB, wkb, wvb, kb, vb, DIM);
  rope_k<NH><<<(MTOT*NH*16)/256,  256, 0, stream>>>(qb, fr);
  rope_k<NKV><<<(MTOT*NKV*16)/256,256, 0, stream>>>(kb, fr);
  attn_k<<<BATCH*NH*(SEQ/128), 512, 0, stream>>>(qb, kb, vb, ao,
      wo, woB, w1, w1B, w3, w3B);
  gemm256<1><<<(MTOT/256)*(DIM/256), 512, 0, stream>>>(
      ao, woB, nullptr, wob, x, out, nullptr,
      nullptr, nullptr, nullptr, nullptr, nullptr, nullptr, DIM);
  rmsnorm_k<<<MTOT, 256, 0, stream>>>(out, gf, hn);
  gemm256<3><<<(MTOT/256)*(FFNH/128), 512, 0, stream>>>(
      hn, w1B, w3B, nullptr, nullptr, nullptr, g,
      nullptr, nullptr, nullptr, nullptr, nullptr, nullptr, DIM);
  cvt_bf16_k<<<(FFNH*DIM)/2048, 256, 0, stream>>>(w2, w2B);
  gemm256<2><<<(MTOT/256)*(DIM/256), 512, 0, stream>>>(
      g, w2B, nullptr, nullptr, out, out, nullptr,
      nullptr, nullptr, nullptr, nullptr, nullptr, nullptr, FFNH);
}

// Round 16
// 3459.263 us; speedup vs baseline: 1.0977x; 1.0020x over previous
//
#include <hip/hip_runtime.h>
#include <hip/hip_bf16.h>

#define DIM   4096
#define NH    32
#define NKV   8
#define HD    128
#define FFNH  11008
#define BATCH 4
#define SEQ   2048
#define MTOT  (BATCH*SEQ)   // 8192

using bf16x8_t = __attribute__((ext_vector_type(8))) short;
using f32x4_t  = __attribute__((ext_vector_type(4))) float;

typedef const __attribute__((address_space(1))) unsigned int GlbU32;
typedef __attribute__((address_space(3))) unsigned int LdsU32;

__device__ __forceinline__ unsigned short f2b(float f) {
  union { float f; unsigned int u; } v; v.f = f;
  return (unsigned short)((v.u + 0x7fffu + ((v.u >> 16) & 1u)) >> 16);
}
__device__ __forceinline__ float b2f(unsigned short b) {
  union { unsigned int u; float f; } v; v.u = ((unsigned int)b) << 16;
  return v.f;
}
__device__ __forceinline__ void gll16(const void* g, void* l) {
  __builtin_amdgcn_global_load_lds((GlbU32*)g, (LdsU32*)l, 16, 0, 0);
}

#define VM8  asm volatile("s_waitcnt vmcnt(8)" ::: "memory")
#define VM4M asm volatile("s_waitcnt vmcnt(4)" ::: "memory")
#define VM0  asm volatile("s_waitcnt vmcnt(0)" ::: "memory")

// ---------------- fp32 -> bf16 bulk convert ----------------
__global__ __launch_bounds__(256)
void cvt_bf16_k(const float* __restrict__ src, unsigned short* __restrict__ dst)
{
  const size_t i = ((size_t)blockIdx.x * 256 + threadIdx.x) * 8;
  const float4 a = *(const float4*)&src[i];
  const float4 b = *(const float4*)&src[i + 4];
  union { int4 v; unsigned short u[8]; } o;
  o.u[0] = f2b(a.x); o.u[1] = f2b(a.y); o.u[2] = f2b(a.z); o.u[3] = f2b(a.w);
  o.u[4] = f2b(b.x); o.u[5] = f2b(b.y); o.u[6] = f2b(b.z); o.u[7] = f2b(b.w);
  *(int4*)&dst[i] = o.v;
}

// ---------------- RMSNorm: fp32 in -> bf16 out ----------------
__global__ __launch_bounds__(256)
void rmsnorm_k(const float* __restrict__ X, const float* __restrict__ gamma,
               unsigned short* __restrict__ Y)
{
  const int row = blockIdx.x, t = threadIdx.x;
  const float* xr = X + (size_t)row * DIM;
  float4 v[4];
  float ss = 0.f;
#pragma unroll
  for (int p = 0; p < 4; ++p) {
    v[p] = *(const float4*)&xr[p * 1024 + t * 4];
    ss += v[p].x*v[p].x + v[p].y*v[p].y + v[p].z*v[p].z + v[p].w*v[p].w;
  }
#pragma unroll
  for (int off = 32; off >= 1; off >>= 1) ss += __shfl_xor(ss, off, 64);
  __shared__ float red[4];
  if ((t & 63) == 0) red[t >> 6] = ss;
  __syncthreads();
  const float tot = red[0] + red[1] + red[2] + red[3];
  const float rn = rsqrtf(tot * (1.f / DIM) + 1e-6f);
  unsigned short* yr = Y + (size_t)row * DIM;
#pragma unroll
  for (int p = 0; p < 4; ++p) {
    const float4 gv = *(const float4*)&gamma[p * 1024 + t * 4];
    short4 o;
    o.x = (short)f2b(v[p].x * gv.x * rn);
    o.y = (short)f2b(v[p].y * gv.y * rn);
    o.z = (short)f2b(v[p].z * gv.z * rn);
    o.w = (short)f2b(v[p].w * gv.w * rn);
    *(short4*)&yr[p * 1024 + t * 4] = o;
  }
}

// ---------------- RoPE in-place on bf16 [rows][NHT*128] ----------------
template<int NHT>
__global__ __launch_bounds__(256)
void rope_k(unsigned short* __restrict__ buf, const float* __restrict__ fr)
{
  const int u = blockIdx.x * 256 + threadIdx.x;
  const int per_row = NHT * 16;
  const int row  = u / per_row;
  const int rem  = u - row * per_row;
  const int head = rem >> 4;
  const int i4   = (rem & 15) << 2;
  const int s    = row & (SEQ - 1);
  unsigned short* p = buf + (size_t)row * (NHT * HD) + head * HD + i4 * 2;
  union { int4 v; unsigned short u16[8]; } d;
  d.v = *(const int4*)p;
  const float4 f = *(const float4*)&fr[s * 64 + i4];
  const float fa[4] = {f.x, f.y, f.z, f.w};
#pragma unroll
  for (int i = 0; i < 4; ++i) {
    float sn, c;
    __sincosf(fa[i], &sn, &c);
    const float x0 = b2f(d.u16[2*i]), x1 = b2f(d.u16[2*i+1]);
    d.u16[2*i]   = f2b(x0 * c - x1 * sn);
    d.u16[2*i+1] = f2b(x0 * sn + x1 * c);
  }
  *(int4*)p = d.v;
}

// ======================= 256x256 GEMM, 2 barriers / K=32 phase (round-6 proven) ===========
// MODE 3 optionally converts w2 fp32->bf16 as a grid-stride tail (hidden under
// staggered block completion); stream order guarantees w2B ready before w2-gemm.
template<int MODE>
__global__ __launch_bounds__(512)
void gemm256(const unsigned short* __restrict__ A,
             const unsigned short* __restrict__ W,
             const unsigned short* __restrict__ W3p,
             const float* __restrict__ bias,
             const float* res,
             float* outF,
             unsigned short* __restrict__ outH,
             const unsigned short* __restrict__ wkp,
             const unsigned short* __restrict__ wvp,
             const float* __restrict__ bkp,
             const float* __restrict__ bvp,
             unsigned short* __restrict__ okp,
             unsigned short* __restrict__ ovp,
             const float* __restrict__ tailS,
             unsigned short* __restrict__ tailD,
             int K)
{
  __shared__ __align__(16) char smem[131072];
  const int t = threadIdx.x, lane = t & 63, wid = t >> 6;
  const int wr = wid >> 2, wc = wid & 3;
  const int G = gridDim.x, bid = blockIdx.x;
  const int wg = (bid & 7) * (G >> 3) + (bid >> 3);   // XCD-chunked
  const int NBN = G >> 5;                             // NBM = 32 (M = 8192)
  const int span = NBN << 3;                          // TMG = 8
  const int tmg = wg / span, rr = wg - tmg * span;
  const int tn = rr >> 3, tm = (tmg << 3) + (rr & 7);
  const int m0 = tm << 8;
  const int NSUB = K >> 5;

  const unsigned short *P1, *P2;
  const float* bp = bias;
  unsigned short* oh = outH;
  int nloc = 0, colsN = 4096;
  if constexpr (MODE == 0) {
    const int n0 = tn << 8;
    if (n0 < 4096)      { nloc = n0;        P1 = W   + (size_t)nloc * K; bp = bias; oh = outH; colsN = 4096; }
    else if (n0 < 5120) { nloc = n0 - 4096; P1 = wkp + (size_t)nloc * K; bp = bkp;  oh = okp;  colsN = 1024; }
    else                { nloc = n0 - 5120; P1 = wvp + (size_t)nloc * K; bp = bvp;  oh = ovp;  colsN = 1024; }
    P2 = P1 + (size_t)128 * K;
  } else if constexpr (MODE == 3) {
    const int n0w = tn << 7;
    P1 = W   + (size_t)n0w * K;
    P2 = W3p + (size_t)n0w * K;
    nloc = n0w;
  } else {
    const int n0 = tn << 8;
    P1 = W + (size_t)n0 * K;
    P2 = P1 + (size_t)128 * K;
    nloc = n0;
  }

  const int r0 = t >> 2, gg = t & 3;
  const int gsw = gg ^ ((r0 >> 1) & 3);

  auto stA = [&](int sig) {
    if (sig < NSUB) {
      const int slot = sig & 3;
      gll16(A + (size_t)(m0 + r0) * K + sig * 32 + gsw * 8,
            smem + slot * 16384 + wid * 1024);
      gll16(A + (size_t)(m0 + 128 + r0) * K + sig * 32 + gsw * 8,
            smem + slot * 16384 + 8192 + wid * 1024);
    }
  };
  auto stB = [&](int sig) {
    if (sig < NSUB) {
      const int slot = sig & 3;
      gll16(P1 + (size_t)r0 * K + sig * 32 + gsw * 8,
            smem + 65536 + slot * 16384 + wid * 1024);
      gll16(P2 + (size_t)r0 * K + sig * 32 + gsw * 8,
            smem + 65536 + slot * 16384 + 8192 + wid * 1024);
    }
  };
  auto rdA = [&](int slot, int mo) -> bf16x8_t {
    const int lrow = wr * 128 + mo + (lane & 15);
    const int g = (lane >> 4) ^ ((lrow >> 1) & 3);
    return *(const bf16x8_t*)(smem + slot * 16384 + lrow * 64 + g * 16);
  };
  auto rdB = [&](int slot, int nf) -> bf16x8_t {
    const int brow = wc * 64 + nf * 16 + (lane & 15);
    const int g = (lane >> 4) ^ ((brow >> 1) & 3);
    return *(const bf16x8_t*)(smem + 65536 + slot * 16384 + brow * 64 + g * 16);
  };

  f32x4_t acc[8][4];
#pragma unroll
  for (int i = 0; i < 8; ++i)
#pragma unroll
    for (int j = 0; j < 4; ++j) acc[i][j] = (f32x4_t)0.f;

  stA(0); stB(0); stA(1); stB(1); stA(2); stB(2);
  VM8;
  __builtin_amdgcn_s_barrier();

  for (int p = 0; p < NSUB; ++p) {
    const int slot = p & 3;
    bf16x8_t bfv[4], afv[8];
#pragma unroll
    for (int n = 0; n < 4; ++n) bfv[n] = rdB(slot, n);
#pragma unroll
    for (int m = 0; m < 8; ++m) afv[m] = rdA(slot, m * 16);
    stA(p + 3); stB(p + 3);
    __builtin_amdgcn_s_setprio(1);
#pragma unroll
    for (int m = 0; m < 8; ++m)
#pragma unroll
      for (int n = 0; n < 4; ++n)
        acc[m][n] = __builtin_amdgcn_mfma_f32_16x16x32_bf16(afv[m], bfv[n], acc[m][n], 0, 0, 0);
    __builtin_amdgcn_s_setprio(0);
    if (p < NSUB - 3)      { VM8; }
    else if (p == NSUB - 3){ VM4M; }
    else                   { VM0; }
    __builtin_amdgcn_s_barrier();
  }

  if constexpr (MODE == 0) {
#pragma unroll
    for (int ni = 0; ni < 4; ++ni) {
      const int col = nloc + wc * 64 + ni * 16 + (lane & 15);
      const float bv = bp[col];
#pragma unroll
      for (int mi = 0; mi < 8; ++mi)
#pragma unroll
        for (int r = 0; r < 4; ++r) {
          const int row = m0 + wr * 128 + mi * 16 + (lane >> 4) * 4 + r;
          oh[(size_t)row * colsN + col] = f2b(acc[mi][ni][r] + bv);
        }
    }
  } else if constexpr (MODE == 1 || MODE == 2) {
#pragma unroll
    for (int ni = 0; ni < 4; ++ni) {
      const int col = nloc + wc * 64 + ni * 16 + (lane & 15);
      float bv = 0.f;
      if constexpr (MODE == 1) bv = bias[col];
#pragma unroll
      for (int mi = 0; mi < 8; ++mi)
#pragma unroll
        for (int r = 0; r < 4; ++r) {
          const int row = m0 + wr * 128 + mi * 16 + (lane >> 4) * 4 + r;
          const size_t idx = (size_t)row * 4096 + col;
          outF[idx] = acc[mi][ni][r] + bv + res[idx];
        }
    }
  } else {
    if (wc >= 2) {
      const int widx = wr * 2 + (wc - 2);
#pragma unroll
      for (int ni = 0; ni < 4; ++ni)
#pragma unroll
        for (int mi = 0; mi < 8; ++mi)
#pragma unroll
          for (int r = 0; r < 4; ++r) {
            const int lrow = mi * 16 + (lane >> 4) * 4 + r;
            const int ncol = ni * 16 + (lane & 15);
            *(unsigned short*)(smem + widx * 16384 + lrow * 128 + ncol * 2) =
                f2b(acc[mi][ni][r]);
          }
    }
    __syncthreads();
    if (wc < 2) {
      const int widx = wr * 2 + wc;
#pragma unroll
      for (int ni = 0; ni < 4; ++ni)
#pragma unroll
        for (int mi = 0; mi < 8; ++mi)
#pragma unroll
          for (int r = 0; r < 4; ++r) {
            const int lrow = mi * 16 + (lane >> 4) * 4 + r;
            const int ncol = ni * 16 + (lane & 15);
            const float s3 = b2f(*(const unsigned short*)(smem + widx * 16384 + lrow * 128 + ncol * 2));
            const float s1 = acc[mi][ni][r];
            const float sig = 1.f / (1.f + __expf(-s1));
            const int row = m0 + wr * 128 + lrow;
            outH[(size_t)row * FFNH + nloc + wc * 64 + ncol] = f2b(s1 * sig * s3);
          }
    }
    // optional w2 fp32->bf16 tail (45,088,768 elems over 2752x512 threads, 4 iters)
    if (tailS) {
      const size_t gt = (size_t)bid * 512 + t;
      for (size_t e = gt * 8; e < 45088768ull; e += 8ull * 1409024ull) {
        const float4 va = *(const float4*)&tailS[e];
        const float4 vb = *(const float4*)&tailS[e + 4];
        union { int4 v; unsigned short u[8]; } ov;
        ov.u[0] = f2b(va.x); ov.u[1] = f2b(va.y); ov.u[2] = f2b(va.z); ov.u[3] = f2b(va.w);
        ov.u[4] = f2b(vb.x); ov.u[5] = f2b(vb.y); ov.u[6] = f2b(vb.z); ov.u[7] = f2b(vb.w);
        *(int4*)&tailD[e] = ov.v;
      }
    }
  }
}

// ---------------- Flash attention: QBLK=128, 8 waves (round-14 proven) + cvt tail ----------------
__global__ __launch_bounds__(512, 4)
void attn_k(const unsigned short* __restrict__ Q, const unsigned short* __restrict__ Kb,
            const unsigned short* __restrict__ Vb, unsigned short* __restrict__ O,
            const float* __restrict__ woS, unsigned short* __restrict__ woD,
            const float* __restrict__ w1S, unsigned short* __restrict__ w1D,
            const float* __restrict__ w3S, unsigned short* __restrict__ w3D)
{
  __shared__ unsigned short Ks[4][4096];   // ring-4 K tiles (32x128 swizzled) 32 KB
  __shared__ unsigned short Vt[2][4096];   // V^T pair                          16 KB
  __shared__ unsigned short Ps[5120];      // 8 waves x 16q x 32kv stride 40    10 KB
  const int t = threadIdx.x, lane = t & 63, wid = t >> 6;   // wid 0..7
  const int bx = blockIdx.x;
  const int qt = bx & 15, h = (bx >> 4) & 31, b = bx >> 9;
  const int kvh = h >> 2;
  const float rs = 0.08838834764831845f;   // 1/sqrt(128)
  constexpr int NPAIR = SEQ / 64;          // 32

  const int q0 = wid * 16;                 // 0..112
  const int qc = lane & 15;                // this lane's q (softmax layout)

  // Q fragments in registers: B-operand of swapped QK^T (issued first = oldest vmem)
  bf16x8_t qf[4];
  {
    const unsigned short* qrow = Q + (size_t)(b * SEQ + qt * 128 + q0 + qc) * DIM
                                   + h * HD + (lane >> 4) * 8;
#pragma unroll
    for (int ks = 0; ks < 4; ++ks) qf[ks] = *(const bf16x8_t*)(qrow + ks * 32);
  }

  const unsigned short* Kbase = Kb + (size_t)(b * SEQ) * (NKV * HD) + kvh * HD;
  const unsigned short* Vbase = Vb + (size_t)(b * SEQ) * (NKV * HD) + kvh * HD;

  auto stK = [&](int kt, int slot) {       // 512 threads x 16B = 8KB tile
    const int row = t >> 4;                // 0..31
    const int gl  = (t & 15) ^ (row & 7);  // pre-swizzled source granule
    gll16(Kbase + (size_t)(kt * 32 + row) * (NKV * HD) + gl * 8, &Ks[slot][(size_t)t * 8]);
  };
  const int kv = t >> 4;                   // 0..31
  const int d0 = (t & 15) * 8;             // 0..120 (8-row span, never crosses 16)
  const int colv = kv ^ (((d0 >> 4) & 3) << 3);
  auto ldV = [&](int kt, int4& w) {
    w = *(const int4*)(Vbase + (size_t)(kt * 32 + kv) * (NKV * HD) + d0);
  };
  auto wrV = [&](int slot, int4 w) {
    union { int4 v; unsigned short u[8]; } u; u.v = w;
#pragma unroll
    for (int j = 0; j < 8; ++j) Vt[slot][(d0 + j) * 32 + colv] = u.u[j];
  };

  // prologue: pair 0 (K slots 0,1) and pair 1 (K slots 2,3)
  int4 a0, a1, b0, b1;
  stK(0, 0); stK(1, 1); ldV(0, a0); ldV(1, a1);
  stK(2, 2); stK(3, 3); ldV(2, b0); ldV(3, b1);

  f32x4_t oa[8];
#pragma unroll
  for (int i = 0; i < 8; ++i) oa[i] = (f32x4_t)0.f;
  float mrun = -1e30f, lrun = 0.f;         // per-lane state for q = qc
  const int pbase = wid * 640 + qc * 40;   // Ps row base (stride-40 ushorts)
  const int pwr   = pbase + (lane >> 4) * 4;

  auto pack2 = [&](float x, float y) -> unsigned int {
    return (unsigned int)f2b(x) | ((unsigned int)f2b(y) << 16);
  };

  auto pairIter = [&](int p, int sb, int4& l0, int4& l1) {
    if (p == NPAIR - 1) { VM0; } else { VM4M; }   // pair p (and qf at p=0) landed
    wrV(0, l0);
    wrV(1, l1);
    asm volatile("s_waitcnt lgkmcnt(0)" ::: "memory");
    __builtin_amdgcn_s_barrier();                 // pair staged, visible to all waves

    // S^T: lane holds q=qc, 16 kv values; 16 MFMA
    f32x4_t st[4];
    st[0] = (f32x4_t)0.f; st[1] = (f32x4_t)0.f;
    st[2] = (f32x4_t)0.f; st[3] = (f32x4_t)0.f;
    const int kr0 = qc, kr1 = 16 + qc;
    __builtin_amdgcn_s_setprio(1);
#pragma unroll
    for (int ks = 0; ks < 4; ++ks) {
      const bf16x8_t k00 = *(const bf16x8_t*)&Ks[sb][(kr0 * 128 + ks * 32 + (lane >> 4) * 8) ^ ((kr0 & 7) << 3)];
      st[0] = __builtin_amdgcn_mfma_f32_16x16x32_bf16(k00, qf[ks], st[0], 0, 0, 0);
      const bf16x8_t k01 = *(const bf16x8_t*)&Ks[sb][(kr1 * 128 + ks * 32 + (lane >> 4) * 8) ^ ((kr1 & 7) << 3)];
      st[1] = __builtin_amdgcn_mfma_f32_16x16x32_bf16(k01, qf[ks], st[1], 0, 0, 0);
      const bf16x8_t k10 = *(const bf16x8_t*)&Ks[sb + 1][(kr0 * 128 + ks * 32 + (lane >> 4) * 8) ^ ((kr0 & 7) << 3)];
      st[2] = __builtin_amdgcn_mfma_f32_16x16x32_bf16(k10, qf[ks], st[2], 0, 0, 0);
      const bf16x8_t k11 = *(const bf16x8_t*)&Ks[sb + 1][(kr1 * 128 + ks * 32 + (lane >> 4) * 8) ^ ((kr1 & 7) << 3)];
      st[3] = __builtin_amdgcn_mfma_f32_16x16x32_bf16(k11, qf[ks], st[3], 0, 0, 0);
    }
    __builtin_amdgcn_s_setprio(0);

    // softmax: in-lane reduce + 2 shfl_xor
    float mx01 = fmaxf(fmaxf(st[0][0], st[0][1]), fmaxf(st[0][2], st[0][3]));
    float mx23 = fmaxf(fmaxf(st[1][0], st[1][1]), fmaxf(st[1][2], st[1][3]));
    float mx45 = fmaxf(fmaxf(st[2][0], st[2][1]), fmaxf(st[2][2], st[2][3]));
    float mx67 = fmaxf(fmaxf(st[3][0], st[3][1]), fmaxf(st[3][2], st[3][3]));
    float pm = fmaxf(fmaxf(mx01, mx23), fmaxf(mx45, mx67)) * rs;
    pm = fmaxf(pm, __shfl_xor(pm, 16, 64));
    pm = fmaxf(pm, __shfl_xor(pm, 32, 64));

    const int grow = __any(pm > mrun);
    if (grow) {
      const float mnew = fmaxf(mrun, pm);
      const float corr = __expf(mrun - mnew);
      mrun = mnew;
      lrun *= corr;
      float c4[4];
#pragma unroll
      for (int r = 0; r < 4; ++r) c4[r] = __shfl(corr, (lane >> 4) * 4 + r, 16);
#pragma unroll
      for (int i = 0; i < 8; ++i)
#pragma unroll
        for (int r = 0; r < 4; ++r) oa[i][r] *= c4[r];
    }

    float ssum = 0.f;
#pragma unroll
    for (int tt = 0; tt < 4; ++tt)
#pragma unroll
      for (int r = 0; r < 4; ++r) {
        st[tt][r] = __expf(st[tt][r] * rs - mrun);
        ssum += st[tt][r];
      }
    ssum += __shfl_xor(ssum, 16, 64);
    ssum += __shfl_xor(ssum, 32, 64);
    lrun += ssum;

    // P^T half 0 (kv 0..31): packed u32 writes, read pa0
    *(unsigned int*)&Ps[pwr]      = pack2(st[0][0], st[0][1]);
    *(unsigned int*)&Ps[pwr + 2]  = pack2(st[0][2], st[0][3]);
    *(unsigned int*)&Ps[pwr + 16] = pack2(st[1][0], st[1][1]);
    *(unsigned int*)&Ps[pwr + 18] = pack2(st[1][2], st[1][3]);
    const bf16x8_t pa0 = *(const bf16x8_t*)&Ps[pbase + (lane >> 4) * 8];
    asm volatile("s_waitcnt lgkmcnt(0)" ::: "memory");   // pa0 read drained (WAR guard)
    // P^T half 1 (kv 32..63) overwrites the same region, read pa1
    *(unsigned int*)&Ps[pwr]      = pack2(st[2][0], st[2][1]);
    *(unsigned int*)&Ps[pwr + 2]  = pack2(st[2][2], st[2][3]);
    *(unsigned int*)&Ps[pwr + 16] = pack2(st[3][0], st[3][1]);
    *(unsigned int*)&Ps[pwr + 18] = pack2(st[3][2], st[3][3]);
    const bf16x8_t pa1 = *(const bf16x8_t*)&Ps[pbase + (lane >> 4) * 8];

    __builtin_amdgcn_s_setprio(1);
#pragma unroll
    for (int nt2 = 0; nt2 < 8; ++nt2) {
      const bf16x8_t vf0 = *(const bf16x8_t*)&Vt[0][(nt2 * 16 + (lane & 15)) * 32 + (((lane >> 4) ^ (nt2 & 3)) << 3)];
      oa[nt2] = __builtin_amdgcn_mfma_f32_16x16x32_bf16(pa0, vf0, oa[nt2], 0, 0, 0);
      const bf16x8_t vf1 = *(const bf16x8_t*)&Vt[1][(nt2 * 16 + (lane & 15)) * 32 + (((lane >> 4) ^ (nt2 & 3)) << 3)];
      oa[nt2] = __builtin_amdgcn_mfma_f32_16x16x32_bf16(pa1, vf1, oa[nt2], 0, 0, 0);
    }
    __builtin_amdgcn_s_setprio(0);
    __builtin_amdgcn_s_barrier();                 // all waves done with Ks[sb..sb+1], Vt
    if (p + 2 < NPAIR) {
      stK(2 * p + 4, sb);     stK(2 * p + 5, sb + 1);
      ldV(2 * p + 4, l0);     ldV(2 * p + 5, l1);
    }
  };

  for (int j = 0; j < NPAIR / 2; ++j) {
    pairIter(2 * j,     0, a0, a1);
    pairIter(2 * j + 1, 2, b0, b1);
  }

  // broadcast l (q-layout) into oa row layout, normalize, store
  float inv[4];
#pragma unroll
  for (int r = 0; r < 4; ++r) inv[r] = 1.f / __shfl(lrun, (lane >> 4) * 4 + r, 16);
#pragma unroll
  for (int nt2 = 0; nt2 < 8; ++nt2) {
    const int col = h * HD + nt2 * 16 + (lane & 15);
#pragma unroll
    for (int r = 0; r < 4; ++r) {
      const int row = qt * 128 + q0 + (lane >> 4) * 4 + r;
      O[(size_t)(b * SEQ + row) * DIM + col] = f2b(oa[nt2][r] * inv[r]);
    }
  }

  // ---- weight-conversion tail: wo | w1 | w3 fp32 -> bf16 ----
  // boundaries: wo = 16,777,216 elems; +w1 45,088,768 -> 61,865,984; +w3 -> 106,954,752
  {
    const size_t gt = (size_t)bx * 512 + t;     // 2048 blocks x 512 = 1,048,576 threads
    for (size_t e = gt * 8; e < 106954752ull; e += 8ull * 1048576ull) {
      const float* src; unsigned short* dst; size_t o;
      if (e < 16777216ull)      { src = woS; dst = woD; o = e; }
      else if (e < 61865984ull) { src = w1S; dst = w1D; o = e - 16777216ull; }
      else                      { src = w3S; dst = w3D; o = e - 61865984ull; }
      const float4 va = *(const float4*)&src[o];
      const float4 vb = *(const float4*)&src[o + 4];
      union { int4 v; unsigned short u[8]; } ov;
      ov.u[0] = f2b(va.x); ov.u[1] = f2b(va.y); ov.u[2] = f2b(va.z); ov.u[3] = f2b(va.w);
      ov.u[4] = f2b(vb.x); ov.u[5] = f2b(vb.y); ov.u[6] = f2b(vb.z); ov.u[7] = f2b(vb.w);
      *(int4*)&dst[o] = ov.v;
    }
  }
}

// ---------------- launch ----------------
extern "C" void kernel_launch(void* const* d_in, const int* in_sizes, int n_in,
                              void* d_out, int out_size, void* d_ws, size_t ws_size,
                              hipStream_t stream)
{
  (void)in_sizes; (void)n_in; (void)out_size;
  const float* x   = (const float*)d_in[0];
  const float* fr  = (const float*)d_in[1];
  const float* ga  = (const float*)d_in[3];
  const float* gf  = (const float*)d_in[4];
  const float* wq  = (const float*)d_in[5];
  const float* wqb = (const float*)d_in[6];
  const float* wk  = (const float*)d_in[7];
  const float* wkb = (const float*)d_in[8];
  const float* wv  = (const float*)d_in[9];
  const float* wvb = (const float*)d_in[10];
  const float* wo  = (const float*)d_in[11];
  const float* wob = (const float*)d_in[12];
  const float* w1  = (const float*)d_in[13];
  const float* w3  = (const float*)d_in[14];
  const float* w2  = (const float*)d_in[15];
  float* out = (float*)d_out;

  constexpr size_t MB = 1ull << 20;
  char* ws = (char*)d_ws;
  unsigned short* xn = (unsigned short*)(ws);              // [0,64) MiB
  unsigned short* qb = (unsigned short*)(ws + 64*MB);      // [64,128)
  unsigned short* kb = (unsigned short*)(ws + 128*MB);     // [128,144)
  unsigned short* vb = (unsigned short*)(ws + 144*MB);     // [144,160)
  unsigned short* ao = (unsigned short*)(ws + 160*MB);     // [160,224)
  unsigned short* hn = (unsigned short*)(ws + 224*MB);     // [224,288)
  unsigned short* g  = (unsigned short*)(ws);              // [0,172) alias (dead by FFN time)
  unsigned short* wscr = (unsigned short*)(ws + 288*MB);   // JIT bf16 weights
  unsigned short* wqB = wscr;                               // bytes [288,320)
  unsigned short* wkB = wscr + 16*MB;                       // bytes [320,328)
  unsigned short* wvB = wscr + 20*MB;                       // bytes [328,336)
  unsigned short* woB = (unsigned short*)(ws);              // 32 MiB, in dead xn (attn tail fills)
  unsigned short* w1B = wscr;                               // bytes [288,374) (attn tail fills)
  unsigned short* w3B = wscr + 46*MB;                       // bytes [380,466) (attn tail fills)
  const bool bigws = ws_size >= 560ull * MB;
  unsigned short* w2B = bigws ? (unsigned short*)(ws + 466*MB)  // bytes [466,552) (w13 tail fills)
                              : wscr;                           // alias w1B (dedicated cvt after w13)

  rmsnorm_k<<<MTOT, 256, 0, stream>>>(x, ga, xn);
  cvt_bf16_k<<<(NH*HD*DIM)/2048,  256, 0, stream>>>(wq, wqB);
  cvt_bf16_k<<<(NKV*HD*DIM)/2048, 256, 0, stream>>>(wk, wkB);
  cvt_bf16_k<<<(NKV*HD*DIM)/2048, 256, 0, stream>>>(wv, wvB);
  gemm256<0><<<(MTOT/256)*((DIM+2*NKV*HD)/256), 512, 0, stream>>>(
      xn, wqB, nullptr, wqb, nullptr, nullptr, qb,
      wkB, wvB, wkb, wvb, kb, vb, nullptr, nullptr, DIM);
  rope_k<NH><<<(MTOT*NH*16)/256,  256, 0, stream>>>(qb, fr);
  rope_k<NKV><<<(MTOT*NKV*16)/256,256, 0, stream>>>(kb, fr);
  attn_k<<<BATCH*NH*(SEQ/128), 512, 0, stream>>>(qb, kb, vb, ao,
      wo, woB, w1, w1B, w3, w3B);
  gemm256<1><<<(MTOT/256)*(DIM/256), 512, 0, stream>>>(
      ao, woB, nullptr, wob, x, out, nullptr,
      nullptr, nullptr, nullptr, nullptr, nullptr, nullptr, nullptr, nullptr, DIM);
  rmsnorm_k<<<MTOT, 256, 0, stream>>>(out, gf, hn);
  gemm256<3><<<(MTOT/256)*(FFNH/128), 512, 0, stream>>>(
      hn, w1B, w3B, nullptr, nullptr, nullptr, g,
      nullptr, nullptr, nullptr, nullptr, nullptr, nullptr,
      bigws ? w2 : nullptr, bigws ? w2B : nullptr, DIM);
  if (!bigws)
    cvt_bf16_k<<<(FFNH*DIM)/2048, 256, 0, stream>>>(w2, w2B);
  gemm256<2><<<(MTOT/256)*(DIM/256), 512, 0, stream>>>(
      g, w2B, nullptr, nullptr, out, out, nullptr,
      nullptr, nullptr, nullptr, nullptr, nullptr, nullptr, nullptr, nullptr, FFNH);
}

// Round 17
// 3412.226 us; speedup vs baseline: 1.1128x; 1.0138x over previous
//
#include <hip/hip_runtime.h>
#include <hip/hip_bf16.h>

#define DIM   4096
#define NH    32
#define NKV   8
#define HD    128
#define FFNH  11008
#define BATCH 4
#define SEQ   2048
#define MTOT  (BATCH*SEQ)   // 8192

using bf16x8_t = __attribute__((ext_vector_type(8))) short;
using f32x4_t  = __attribute__((ext_vector_type(4))) float;

typedef const __attribute__((address_space(1))) unsigned int GlbU32;
typedef __attribute__((address_space(3))) unsigned int LdsU32;

__device__ __forceinline__ unsigned short f2b(float f) {
  union { float f; unsigned int u; } v; v.f = f;
  return (unsigned short)((v.u + 0x7fffu + ((v.u >> 16) & 1u)) >> 16);
}
__device__ __forceinline__ float b2f(unsigned short b) {
  union { unsigned int u; float f; } v; v.u = ((unsigned int)b) << 16;
  return v.f;
}
__device__ __forceinline__ void gll16(const void* g, void* l) {
  __builtin_amdgcn_global_load_lds((GlbU32*)g, (LdsU32*)l, 16, 0, 0);
}

#define VM8  asm volatile("s_waitcnt vmcnt(8)" ::: "memory")
#define VM4M asm volatile("s_waitcnt vmcnt(4)" ::: "memory")
#define VM0  asm volatile("s_waitcnt vmcnt(0)" ::: "memory")

// ---------------- fp32 -> bf16 bulk convert ----------------
__global__ __launch_bounds__(256)
void cvt_bf16_k(const float* __restrict__ src, unsigned short* __restrict__ dst)
{
  const size_t i = ((size_t)blockIdx.x * 256 + threadIdx.x) * 8;
  const float4 a = *(const float4*)&src[i];
  const float4 b = *(const float4*)&src[i + 4];
  union { int4 v; unsigned short u[8]; } o;
  o.u[0] = f2b(a.x); o.u[1] = f2b(a.y); o.u[2] = f2b(a.z); o.u[3] = f2b(a.w);
  o.u[4] = f2b(b.x); o.u[5] = f2b(b.y); o.u[6] = f2b(b.z); o.u[7] = f2b(b.w);
  *(int4*)&dst[i] = o.v;
}

// ---------------- RMSNorm: fp32 in -> bf16 out ----------------
__global__ __launch_bounds__(256)
void rmsnorm_k(const float* __restrict__ X, const float* __restrict__ gamma,
               unsigned short* __restrict__ Y)
{
  const int row = blockIdx.x, t = threadIdx.x;
  const float* xr = X + (size_t)row * DIM;
  float4 v[4];
  float ss = 0.f;
#pragma unroll
  for (int p = 0; p < 4; ++p) {
    v[p] = *(const float4*)&xr[p * 1024 + t * 4];
    ss += v[p].x*v[p].x + v[p].y*v[p].y + v[p].z*v[p].z + v[p].w*v[p].w;
  }
#pragma unroll
  for (int off = 32; off >= 1; off >>= 1) ss += __shfl_xor(ss, off, 64);
  __shared__ float red[4];
  if ((t & 63) == 0) red[t >> 6] = ss;
  __syncthreads();
  const float tot = red[0] + red[1] + red[2] + red[3];
  const float rn = rsqrtf(tot * (1.f / DIM) + 1e-6f);
  unsigned short* yr = Y + (size_t)row * DIM;
#pragma unroll
  for (int p = 0; p < 4; ++p) {
    const float4 gv = *(const float4*)&gamma[p * 1024 + t * 4];
    short4 o;
    o.x = (short)f2b(v[p].x * gv.x * rn);
    o.y = (short)f2b(v[p].y * gv.y * rn);
    o.z = (short)f2b(v[p].z * gv.z * rn);
    o.w = (short)f2b(v[p].w * gv.w * rn);
    *(short4*)&yr[p * 1024 + t * 4] = o;
  }
}

// ---------------- RoPE in-place on bf16 [rows][NHT*128] ----------------
template<int NHT>
__global__ __launch_bounds__(256)
void rope_k(unsigned short* __restrict__ buf, const float* __restrict__ fr)
{
  const int u = blockIdx.x * 256 + threadIdx.x;
  const int per_row = NHT * 16;
  const int row  = u / per_row;
  const int rem  = u - row * per_row;
  const int head = rem >> 4;
  const int i4   = (rem & 15) << 2;
  const int s    = row & (SEQ - 1);
  unsigned short* p = buf + (size_t)row * (NHT * HD) + head * HD + i4 * 2;
  union { int4 v; unsigned short u16[8]; } d;
  d.v = *(const int4*)p;
  const float4 f = *(const float4*)&fr[s * 64 + i4];
  const float fa[4] = {f.x, f.y, f.z, f.w};
#pragma unroll
  for (int i = 0; i < 4; ++i) {
    float sn, c;
    __sincosf(fa[i], &sn, &c);
    const float x0 = b2f(d.u16[2*i]), x1 = b2f(d.u16[2*i+1]);
    d.u16[2*i]   = f2b(x0 * c - x1 * sn);
    d.u16[2*i+1] = f2b(x0 * sn + x1 * c);
  }
  *(int4*)p = d.v;
}

// ======================= 256x256 GEMM, 2 barriers / K=32 phase (round-6 proven) ===========
// MODE 3: w2 fp32->bf16 cvt interleaved into phases 0..3 (hidden under the K-loop;
// vmcnt ledger safe: sigma(p+1) is always >=9th-oldest vmem op at the VM8 wait).
template<int MODE>
__global__ __launch_bounds__(512)
void gemm256(const unsigned short* __restrict__ A,
             const unsigned short* __restrict__ W,
             const unsigned short* __restrict__ W3p,
             const float* __restrict__ bias,
             const float* res,
             float* outF,
             unsigned short* __restrict__ outH,
             const unsigned short* __restrict__ wkp,
             const unsigned short* __restrict__ wvp,
             const float* __restrict__ bkp,
             const float* __restrict__ bvp,
             unsigned short* __restrict__ okp,
             unsigned short* __restrict__ ovp,
             const float* __restrict__ tailS,
             unsigned short* __restrict__ tailD,
             int K)
{
  __shared__ __align__(16) char smem[131072];
  const int t = threadIdx.x, lane = t & 63, wid = t >> 6;
  const int wr = wid >> 2, wc = wid & 3;
  const int G = gridDim.x, bid = blockIdx.x;
  const int wg = (bid & 7) * (G >> 3) + (bid >> 3);   // XCD-chunked
  const int NBN = G >> 5;                             // NBM = 32 (M = 8192)
  const int span = NBN << 3;                          // TMG = 8
  const int tmg = wg / span, rr = wg - tmg * span;
  const int tn = rr >> 3, tm = (tmg << 3) + (rr & 7);
  const int m0 = tm << 8;
  const int NSUB = K >> 5;

  const unsigned short *P1, *P2;
  const float* bp = bias;
  unsigned short* oh = outH;
  int nloc = 0, colsN = 4096;
  if constexpr (MODE == 0) {
    const int n0 = tn << 8;
    if (n0 < 4096)      { nloc = n0;        P1 = W   + (size_t)nloc * K; bp = bias; oh = outH; colsN = 4096; }
    else if (n0 < 5120) { nloc = n0 - 4096; P1 = wkp + (size_t)nloc * K; bp = bkp;  oh = okp;  colsN = 1024; }
    else                { nloc = n0 - 5120; P1 = wvp + (size_t)nloc * K; bp = bvp;  oh = ovp;  colsN = 1024; }
    P2 = P1 + (size_t)128 * K;
  } else if constexpr (MODE == 3) {
    const int n0w = tn << 7;
    P1 = W   + (size_t)n0w * K;
    P2 = W3p + (size_t)n0w * K;
    nloc = n0w;
  } else {
    const int n0 = tn << 8;
    P1 = W + (size_t)n0 * K;
    P2 = P1 + (size_t)128 * K;
    nloc = n0;
  }

  const int r0 = t >> 2, gg = t & 3;
  const int gsw = gg ^ ((r0 >> 1) & 3);

  auto stA = [&](int sig) {
    if (sig < NSUB) {
      const int slot = sig & 3;
      gll16(A + (size_t)(m0 + r0) * K + sig * 32 + gsw * 8,
            smem + slot * 16384 + wid * 1024);
      gll16(A + (size_t)(m0 + 128 + r0) * K + sig * 32 + gsw * 8,
            smem + slot * 16384 + 8192 + wid * 1024);
    }
  };
  auto stB = [&](int sig) {
    if (sig < NSUB) {
      const int slot = sig & 3;
      gll16(P1 + (size_t)r0 * K + sig * 32 + gsw * 8,
            smem + 65536 + slot * 16384 + wid * 1024);
      gll16(P2 + (size_t)r0 * K + sig * 32 + gsw * 8,
            smem + 65536 + slot * 16384 + 8192 + wid * 1024);
    }
  };
  auto rdA = [&](int slot, int mo) -> bf16x8_t {
    const int lrow = wr * 128 + mo + (lane & 15);
    const int g = (lane >> 4) ^ ((lrow >> 1) & 3);
    return *(const bf16x8_t*)(smem + slot * 16384 + lrow * 64 + g * 16);
  };
  auto rdB = [&](int slot, int nf) -> bf16x8_t {
    const int brow = wc * 64 + nf * 16 + (lane & 15);
    const int g = (lane >> 4) ^ ((brow >> 1) & 3);
    return *(const bf16x8_t*)(smem + 65536 + slot * 16384 + brow * 64 + g * 16);
  };

  f32x4_t acc[8][4];
#pragma unroll
  for (int i = 0; i < 8; ++i)
#pragma unroll
    for (int j = 0; j < 4; ++j) acc[i][j] = (f32x4_t)0.f;

  stA(0); stB(0); stA(1); stB(1); stA(2); stB(2);
  VM8;
  __builtin_amdgcn_s_barrier();

  for (int p = 0; p < NSUB; ++p) {
    const int slot = p & 3;
    bf16x8_t bfv[4], afv[8];
#pragma unroll
    for (int n = 0; n < 4; ++n) bfv[n] = rdB(slot, n);
#pragma unroll
    for (int m = 0; m < 8; ++m) afv[m] = rdA(slot, m * 16);
    if constexpr (MODE == 3) {
      // interleaved w2 cvt chunk (phases 0..3; 2752x512 threads x 8 elems x 4 = exact)
      if (tailS && p < 4) {
        const size_t e = ((size_t)bid * 512 + t) * 8 + (size_t)p * 11272192ull;
        const float4 va = *(const float4*)&tailS[e];
        const float4 vb = *(const float4*)&tailS[e + 4];
        union { int4 v; unsigned short u[8]; } ov;
        ov.u[0] = f2b(va.x); ov.u[1] = f2b(va.y); ov.u[2] = f2b(va.z); ov.u[3] = f2b(va.w);
        ov.u[4] = f2b(vb.x); ov.u[5] = f2b(vb.y); ov.u[6] = f2b(vb.z); ov.u[7] = f2b(vb.w);
        *(int4*)&tailD[e] = ov.v;
      }
    }
    stA(p + 3); stB(p + 3);
    __builtin_amdgcn_s_setprio(1);
#pragma unroll
    for (int m = 0; m < 8; ++m)
#pragma unroll
      for (int n = 0; n < 4; ++n)
        acc[m][n] = __builtin_amdgcn_mfma_f32_16x16x32_bf16(afv[m], bfv[n], acc[m][n], 0, 0, 0);
    __builtin_amdgcn_s_setprio(0);
    if (p < NSUB - 3)      { VM8; }
    else if (p == NSUB - 3){ VM4M; }
    else                   { VM0; }
    __builtin_amdgcn_s_barrier();
  }

  if constexpr (MODE == 0) {
#pragma unroll
    for (int ni = 0; ni < 4; ++ni) {
      const int col = nloc + wc * 64 + ni * 16 + (lane & 15);
      const float bv = bp[col];
#pragma unroll
      for (int mi = 0; mi < 8; ++mi)
#pragma unroll
        for (int r = 0; r < 4; ++r) {
          const int row = m0 + wr * 128 + mi * 16 + (lane >> 4) * 4 + r;
          oh[(size_t)row * colsN + col] = f2b(acc[mi][ni][r] + bv);
        }
    }
  } else if constexpr (MODE == 1 || MODE == 2) {
#pragma unroll
    for (int ni = 0; ni < 4; ++ni) {
      const int col = nloc + wc * 64 + ni * 16 + (lane & 15);
      float bv = 0.f;
      if constexpr (MODE == 1) bv = bias[col];
#pragma unroll
      for (int mi = 0; mi < 8; ++mi)
#pragma unroll
        for (int r = 0; r < 4; ++r) {
          const int row = m0 + wr * 128 + mi * 16 + (lane >> 4) * 4 + r;
          const size_t idx = (size_t)row * 4096 + col;
          outF[idx] = acc[mi][ni][r] + bv + res[idx];
        }
    }
  } else {
    if (wc >= 2) {
      const int widx = wr * 2 + (wc - 2);
#pragma unroll
      for (int ni = 0; ni < 4; ++ni)
#pragma unroll
        for (int mi = 0; mi < 8; ++mi)
#pragma unroll
          for (int r = 0; r < 4; ++r) {
            const int lrow = mi * 16 + (lane >> 4) * 4 + r;
            const int ncol = ni * 16 + (lane & 15);
            *(unsigned short*)(smem + widx * 16384 + lrow * 128 + ncol * 2) =
                f2b(acc[mi][ni][r]);
          }
    }
    __syncthreads();
    if (wc < 2) {
      const int widx = wr * 2 + wc;
#pragma unroll
      for (int ni = 0; ni < 4; ++ni)
#pragma unroll
        for (int mi = 0; mi < 8; ++mi)
#pragma unroll
          for (int r = 0; r < 4; ++r) {
            const int lrow = mi * 16 + (lane >> 4) * 4 + r;
            const int ncol = ni * 16 + (lane & 15);
            const float s3 = b2f(*(const unsigned short*)(smem + widx * 16384 + lrow * 128 + ncol * 2));
            const float s1 = acc[mi][ni][r];
            const float sig = 1.f / (1.f + __expf(-s1));
            const int row = m0 + wr * 128 + lrow;
            outH[(size_t)row * FFNH + nloc + wc * 64 + ncol] = f2b(s1 * sig * s3);
          }
    }
  }
}

// ---------------- Flash attention: QBLK=128, 8 waves (round-14 proven) ----------------
// wo|w1|w3 cvt interleaved into pairs 0..12 (hidden under pair latency; vmcnt
// ledger safe: pair p's loads are always >=5th-oldest at the VM4 wait).
__global__ __launch_bounds__(512, 4)
void attn_k(const unsigned short* __restrict__ Q, const unsigned short* __restrict__ Kb,
            const unsigned short* __restrict__ Vb, unsigned short* __restrict__ O,
            const float* __restrict__ woS, unsigned short* __restrict__ woD,
            const float* __restrict__ w1S, unsigned short* __restrict__ w1D,
            const float* __restrict__ w3S, unsigned short* __restrict__ w3D)
{
  __shared__ unsigned short Ks[4][4096];   // ring-4 K tiles (32x128 swizzled) 32 KB
  __shared__ unsigned short Vt[2][4096];   // V^T pair                          16 KB
  __shared__ unsigned short Ps[5120];      // 8 waves x 16q x 32kv stride 40    10 KB
  const int t = threadIdx.x, lane = t & 63, wid = t >> 6;   // wid 0..7
  const int bx = blockIdx.x;
  const int qt = bx & 15, h = (bx >> 4) & 31, b = bx >> 9;
  const int kvh = h >> 2;
  const float rs = 0.08838834764831845f;   // 1/sqrt(128)
  constexpr int NPAIR = SEQ / 64;          // 32

  const int q0 = wid * 16;                 // 0..112
  const int qc = lane & 15;                // this lane's q (softmax layout)

  // Q fragments in registers: B-operand of swapped QK^T (issued first = oldest vmem)
  bf16x8_t qf[4];
  {
    const unsigned short* qrow = Q + (size_t)(b * SEQ + qt * 128 + q0 + qc) * DIM
                                   + h * HD + (lane >> 4) * 8;
#pragma unroll
    for (int ks = 0; ks < 4; ++ks) qf[ks] = *(const bf16x8_t*)(qrow + ks * 32);
  }

  const unsigned short* Kbase = Kb + (size_t)(b * SEQ) * (NKV * HD) + kvh * HD;
  const unsigned short* Vbase = Vb + (size_t)(b * SEQ) * (NKV * HD) + kvh * HD;

  auto stK = [&](int kt, int slot) {       // 512 threads x 16B = 8KB tile
    const int row = t >> 4;                // 0..31
    const int gl  = (t & 15) ^ (row & 7);  // pre-swizzled source granule
    gll16(Kbase + (size_t)(kt * 32 + row) * (NKV * HD) + gl * 8, &Ks[slot][(size_t)t * 8]);
  };
  const int kv = t >> 4;                   // 0..31
  const int d0 = (t & 15) * 8;             // 0..120 (8-row span, never crosses 16)
  const int colv = kv ^ (((d0 >> 4) & 3) << 3);
  auto ldV = [&](int kt, int4& w) {
    w = *(const int4*)(Vbase + (size_t)(kt * 32 + kv) * (NKV * HD) + d0);
  };
  auto wrV = [&](int slot, int4 w) {
    union { int4 v; unsigned short u[8]; } u; u.v = w;
#pragma unroll
    for (int j = 0; j < 8; ++j) Vt[slot][(d0 + j) * 32 + colv] = u.u[j];
  };

  // prologue: pair 0 (K slots 0,1) and pair 1 (K slots 2,3)
  int4 a0, a1, b0, b1;
  stK(0, 0); stK(1, 1); ldV(0, a0); ldV(1, a1);
  stK(2, 2); stK(3, 3); ldV(2, b0); ldV(3, b1);

  f32x4_t oa[8];
#pragma unroll
  for (int i = 0; i < 8; ++i) oa[i] = (f32x4_t)0.f;
  float mrun = -1e30f, lrun = 0.f;         // per-lane state for q = qc
  const int pbase = wid * 640 + qc * 40;   // Ps row base (stride-40 ushorts)
  const int pwr   = pbase + (lane >> 4) * 4;

  auto pack2 = [&](float x, float y) -> unsigned int {
    return (unsigned int)f2b(x) | ((unsigned int)f2b(y) << 16);
  };

  auto pairIter = [&](int p, int sb, int4& l0, int4& l1) {
    if (p == NPAIR - 1) { VM0; } else { VM4M; }   // pair p (and qf at p=0) landed
    wrV(0, l0);
    wrV(1, l1);
    asm volatile("s_waitcnt lgkmcnt(0)" ::: "memory");
    __builtin_amdgcn_s_barrier();                 // pair staged, visible to all waves

    // S^T: lane holds q=qc, 16 kv values; 16 MFMA
    f32x4_t st[4];
    st[0] = (f32x4_t)0.f; st[1] = (f32x4_t)0.f;
    st[2] = (f32x4_t)0.f; st[3] = (f32x4_t)0.f;
    const int kr0 = qc, kr1 = 16 + qc;
    __builtin_amdgcn_s_setprio(1);
#pragma unroll
    for (int ks = 0; ks < 4; ++ks) {
      const bf16x8_t k00 = *(const bf16x8_t*)&Ks[sb][(kr0 * 128 + ks * 32 + (lane >> 4) * 8) ^ ((kr0 & 7) << 3)];
      st[0] = __builtin_amdgcn_mfma_f32_16x16x32_bf16(k00, qf[ks], st[0], 0, 0, 0);
      const bf16x8_t k01 = *(const bf16x8_t*)&Ks[sb][(kr1 * 128 + ks * 32 + (lane >> 4) * 8) ^ ((kr1 & 7) << 3)];
      st[1] = __builtin_amdgcn_mfma_f32_16x16x32_bf16(k01, qf[ks], st[1], 0, 0, 0);
      const bf16x8_t k10 = *(const bf16x8_t*)&Ks[sb + 1][(kr0 * 128 + ks * 32 + (lane >> 4) * 8) ^ ((kr0 & 7) << 3)];
      st[2] = __builtin_amdgcn_mfma_f32_16x16x32_bf16(k10, qf[ks], st[2], 0, 0, 0);
      const bf16x8_t k11 = *(const bf16x8_t*)&Ks[sb + 1][(kr1 * 128 + ks * 32 + (lane >> 4) * 8) ^ ((kr1 & 7) << 3)];
      st[3] = __builtin_amdgcn_mfma_f32_16x16x32_bf16(k11, qf[ks], st[3], 0, 0, 0);
    }
    __builtin_amdgcn_s_setprio(0);

    // softmax: in-lane reduce + 2 shfl_xor
    float mx01 = fmaxf(fmaxf(st[0][0], st[0][1]), fmaxf(st[0][2], st[0][3]));
    float mx23 = fmaxf(fmaxf(st[1][0], st[1][1]), fmaxf(st[1][2], st[1][3]));
    float mx45 = fmaxf(fmaxf(st[2][0], st[2][1]), fmaxf(st[2][2], st[2][3]));
    float mx67 = fmaxf(fmaxf(st[3][0], st[3][1]), fmaxf(st[3][2], st[3][3]));
    float pm = fmaxf(fmaxf(mx01, mx23), fmaxf(mx45, mx67)) * rs;
    pm = fmaxf(pm, __shfl_xor(pm, 16, 64));
    pm = fmaxf(pm, __shfl_xor(pm, 32, 64));

    const int grow = __any(pm > mrun);
    if (grow) {
      const float mnew = fmaxf(mrun, pm);
      const float corr = __expf(mrun - mnew);
      mrun = mnew;
      lrun *= corr;
      float c4[4];
#pragma unroll
      for (int r = 0; r < 4; ++r) c4[r] = __shfl(corr, (lane >> 4) * 4 + r, 16);
#pragma unroll
      for (int i = 0; i < 8; ++i)
#pragma unroll
        for (int r = 0; r < 4; ++r) oa[i][r] *= c4[r];
    }

    float ssum = 0.f;
#pragma unroll
    for (int tt = 0; tt < 4; ++tt)
#pragma unroll
      for (int r = 0; r < 4; ++r) {
        st[tt][r] = __expf(st[tt][r] * rs - mrun);
        ssum += st[tt][r];
      }
    ssum += __shfl_xor(ssum, 16, 64);
    ssum += __shfl_xor(ssum, 32, 64);
    lrun += ssum;

    // P^T half 0 (kv 0..31): packed u32 writes, read pa0
    *(unsigned int*)&Ps[pwr]      = pack2(st[0][0], st[0][1]);
    *(unsigned int*)&Ps[pwr + 2]  = pack2(st[0][2], st[0][3]);
    *(unsigned int*)&Ps[pwr + 16] = pack2(st[1][0], st[1][1]);
    *(unsigned int*)&Ps[pwr + 18] = pack2(st[1][2], st[1][3]);
    const bf16x8_t pa0 = *(const bf16x8_t*)&Ps[pbase + (lane >> 4) * 8];
    asm volatile("s_waitcnt lgkmcnt(0)" ::: "memory");   // pa0 read drained (WAR guard)
    // P^T half 1 (kv 32..63) overwrites the same region, read pa1
    *(unsigned int*)&Ps[pwr]      = pack2(st[2][0], st[2][1]);
    *(unsigned int*)&Ps[pwr + 2]  = pack2(st[2][2], st[2][3]);
    *(unsigned int*)&Ps[pwr + 16] = pack2(st[3][0], st[3][1]);
    *(unsigned int*)&Ps[pwr + 18] = pack2(st[3][2], st[3][3]);
    const bf16x8_t pa1 = *(const bf16x8_t*)&Ps[pbase + (lane >> 4) * 8];

    __builtin_amdgcn_s_setprio(1);
#pragma unroll
    for (int nt2 = 0; nt2 < 8; ++nt2) {
      const bf16x8_t vf0 = *(const bf16x8_t*)&Vt[0][(nt2 * 16 + (lane & 15)) * 32 + (((lane >> 4) ^ (nt2 & 3)) << 3)];
      oa[nt2] = __builtin_amdgcn_mfma_f32_16x16x32_bf16(pa0, vf0, oa[nt2], 0, 0, 0);
      const bf16x8_t vf1 = *(const bf16x8_t*)&Vt[1][(nt2 * 16 + (lane & 15)) * 32 + (((lane >> 4) ^ (nt2 & 3)) << 3)];
      oa[nt2] = __builtin_amdgcn_mfma_f32_16x16x32_bf16(pa1, vf1, oa[nt2], 0, 0, 0);
    }
    __builtin_amdgcn_s_setprio(0);
    __builtin_amdgcn_s_barrier();                 // all waves done with Ks[sb..sb+1], Vt
    // interleaved wo|w1|w3 cvt chunk (pairs 0..12; hidden under pair latency)
    if (p < 13) {
      const size_t e = ((size_t)bx * 512 + t) * 8 + (size_t)p * 8388608ull;
      if (e < 106954752ull) {
        const float* src; unsigned short* dst; size_t o;
        if (e < 16777216ull)      { src = woS; dst = woD; o = e; }
        else if (e < 61865984ull) { src = w1S; dst = w1D; o = e - 16777216ull; }
        else                      { src = w3S; dst = w3D; o = e - 61865984ull; }
        const float4 va = *(const float4*)&src[o];
        const float4 vb = *(const float4*)&src[o + 4];
        union { int4 v; unsigned short u[8]; } ov;
        ov.u[0] = f2b(va.x); ov.u[1] = f2b(va.y); ov.u[2] = f2b(va.z); ov.u[3] = f2b(va.w);
        ov.u[4] = f2b(vb.x); ov.u[5] = f2b(vb.y); ov.u[6] = f2b(vb.z); ov.u[7] = f2b(vb.w);
        *(int4*)&dst[o] = ov.v;
      }
    }
    if (p + 2 < NPAIR) {
      stK(2 * p + 4, sb);     stK(2 * p + 5, sb + 1);
      ldV(2 * p + 4, l0);     ldV(2 * p + 5, l1);
    }
  };

  for (int j = 0; j < NPAIR / 2; ++j) {
    pairIter(2 * j,     0, a0, a1);
    pairIter(2 * j + 1, 2, b0, b1);
  }

  // broadcast l (q-layout) into oa row layout, normalize, store
  float inv[4];
#pragma unroll
  for (int r = 0; r < 4; ++r) inv[r] = 1.f / __shfl(lrun, (lane >> 4) * 4 + r, 16);
#pragma unroll
  for (int nt2 = 0; nt2 < 8; ++nt2) {
    const int col = h * HD + nt2 * 16 + (lane & 15);
#pragma unroll
    for (int r = 0; r < 4; ++r) {
      const int row = qt * 128 + q0 + (lane >> 4) * 4 + r;
      O[(size_t)(b * SEQ + row) * DIM + col] = f2b(oa[nt2][r] * inv[r]);
    }
  }
}

// ---------------- launch ----------------
extern "C" void kernel_launch(void* const* d_in, const int* in_sizes, int n_in,
                              void* d_out, int out_size, void* d_ws, size_t ws_size,
                              hipStream_t stream)
{
  (void)in_sizes; (void)n_in; (void)out_size;
  const float* x   = (const float*)d_in[0];
  const float* fr  = (const float*)d_in[1];
  const float* ga  = (const float*)d_in[3];
  const float* gf  = (const float*)d_in[4];
  const float* wq  = (const float*)d_in[5];
  const float* wqb = (const float*)d_in[6];
  const float* wk  = (const float*)d_in[7];
  const float* wkb = (const float*)d_in[8];
  const float* wv  = (const float*)d_in[9];
  const float* wvb = (const float*)d_in[10];
  const float* wo  = (const float*)d_in[11];
  const float* wob = (const float*)d_in[12];
  const float* w1  = (const float*)d_in[13];
  const float* w3  = (const float*)d_in[14];
  const float* w2  = (const float*)d_in[15];
  float* out = (float*)d_out;

  constexpr size_t MB = 1ull << 20;
  char* ws = (char*)d_ws;
  unsigned short* xn = (unsigned short*)(ws);              // [0,64) MiB
  unsigned short* qb = (unsigned short*)(ws + 64*MB);      // [64,128)
  unsigned short* kb = (unsigned short*)(ws + 128*MB);     // [128,144)
  unsigned short* vb = (unsigned short*)(ws + 144*MB);     // [144,160)
  unsigned short* ao = (unsigned short*)(ws + 160*MB);     // [160,224)
  unsigned short* hn = (unsigned short*)(ws + 224*MB);     // [224,288)
  unsigned short* g  = (unsigned short*)(ws);              // [0,172) alias (dead by FFN time)
  unsigned short* wscr = (unsigned short*)(ws + 288*MB);   // JIT bf16 weights
  unsigned short* wqB = wscr;                               // bytes [288,320)
  unsigned short* wkB = wscr + 16*MB;                       // bytes [320,328)
  unsigned short* wvB = wscr + 20*MB;                       // bytes [328,336)
  unsigned short* woB = (unsigned short*)(ws);              // 32 MiB, in dead xn (attn fills)
  unsigned short* w1B = wscr;                               // bytes [288,374) (attn fills)
  unsigned short* w3B = wscr + 46*MB;                       // bytes [380,466) (attn fills)
  const bool bigws = ws_size >= 560ull * MB;
  unsigned short* w2B = bigws ? (unsigned short*)(ws + 466*MB)  // bytes [466,552) (w13 fills)
                              : wscr;                           // alias w1B (dedicated cvt after w13)

  rmsnorm_k<<<MTOT, 256, 0, stream>>>(x, ga, xn);
  cvt_bf16_k<<<(NH*HD*DIM)/2048,  256, 0, stream>>>(wq, wqB);
  cvt_bf16_k<<<(NKV*HD*DIM)/2048, 256, 0, stream>>>(wk, wkB);
  cvt_bf16_k<<<(NKV*HD*DIM)/2048, 256, 0, stream>>>(wv, wvB);
  gemm256<0><<<(MTOT/256)*((DIM+2*NKV*HD)/256), 512, 0, stream>>>(
      xn, wqB, nullptr, wqb, nullptr, nullptr, qb,
      wkB, wvB, wkb, wvb, kb, vb, nullptr, nullptr, DIM);
  rope_k<NH><<<(MTOT*NH*16)/256,  256, 0, stream>>>(qb, fr);
  rope_k<NKV><<<(MTOT*NKV*16)/256,256, 0, stream>>>(kb, fr);
  attn_k<<<BATCH*NH*(SEQ/128), 512, 0, stream>>>(qb, kb, vb, ao,
      wo, woB, w1, w1B, w3, w3B);
  gemm256<1><<<(MTOT/256)*(DIM/256), 512, 0, stream>>>(
      ao, woB, nullptr, wob, x, out, nullptr,
      nullptr, nullptr, nullptr, nullptr, nullptr, nullptr, nullptr, nullptr, DIM);
  rmsnorm_k<<<MTOT, 256, 0, stream>>>(out, gf, hn);
  gemm256<3><<<(MTOT/256)*(FFNH/128), 512, 0, stream>>>(
      hn, w1B, w3B, nullptr, nullptr, nullptr, g,
      nullptr, nullptr, nullptr, nullptr, nullptr, nullptr,
      bigws ? w2 : nullptr, bigws ? w2B : nullptr, DIM);
  if (!bigws)
    cvt_bf16_k<<<(FFNH*DIM)/2048, 256, 0, stream>>>(w2, w2B);
  gemm256<2><<<(MTOT/256)*(DIM/256), 512, 0, stream>>>(
      g, w2B, nullptr, nullptr, out, out, nullptr,
      nullptr, nullptr, nullptr, nullptr, nullptr, nullptr, nullptr, nullptr, FFNH);
}

// Round 18
// 3399.010 us; speedup vs baseline: 1.1171x; 1.0039x over previous
//
#include <hip/hip_runtime.h>
#include <hip/hip_bf16.h>

#define DIM   4096
#define NH    32
#define NKV   8
#define HD    128
#define FFNH  11008
#define BATCH 4
#define SEQ   2048
#define MTOT  (BATCH*SEQ)   // 8192

using bf16x8_t = __attribute__((ext_vector_type(8))) short;
using f32x4_t  = __attribute__((ext_vector_type(4))) float;

typedef const __attribute__((address_space(1))) unsigned int GlbU32;
typedef __attribute__((address_space(3))) unsigned int LdsU32;

__device__ __forceinline__ unsigned short f2b(float f) {
  union { float f; unsigned int u; } v; v.f = f;
  return (unsigned short)((v.u + 0x7fffu + ((v.u >> 16) & 1u)) >> 16);
}
__device__ __forceinline__ float b2f(unsigned short b) {
  union { unsigned int u; float f; } v; v.u = ((unsigned int)b) << 16;
  return v.f;
}
__device__ __forceinline__ void gll16(const void* g, void* l) {
  __builtin_amdgcn_global_load_lds((GlbU32*)g, (LdsU32*)l, 16, 0, 0);
}

#define VM8  asm volatile("s_waitcnt vmcnt(8)" ::: "memory")
#define VM4M asm volatile("s_waitcnt vmcnt(4)" ::: "memory")
#define VM0  asm volatile("s_waitcnt vmcnt(0)" ::: "memory")

// ---------------- fp32 -> bf16 bulk convert ----------------
__global__ __launch_bounds__(256)
void cvt_bf16_k(const float* __restrict__ src, unsigned short* __restrict__ dst)
{
  const size_t i = ((size_t)blockIdx.x * 256 + threadIdx.x) * 8;
  const float4 a = *(const float4*)&src[i];
  const float4 b = *(const float4*)&src[i + 4];
  union { int4 v; unsigned short u[8]; } o;
  o.u[0] = f2b(a.x); o.u[1] = f2b(a.y); o.u[2] = f2b(a.z); o.u[3] = f2b(a.w);
  o.u[4] = f2b(b.x); o.u[5] = f2b(b.y); o.u[6] = f2b(b.z); o.u[7] = f2b(b.w);
  *(int4*)&dst[i] = o.v;
}

// ---------------- RMSNorm: fp32 in -> bf16 out ----------------
__global__ __launch_bounds__(256)
void rmsnorm_k(const float* __restrict__ X, const float* __restrict__ gamma,
               unsigned short* __restrict__ Y)
{
  const int row = blockIdx.x, t = threadIdx.x;
  const float* xr = X + (size_t)row * DIM;
  float4 v[4];
  float ss = 0.f;
#pragma unroll
  for (int p = 0; p < 4; ++p) {
    v[p] = *(const float4*)&xr[p * 1024 + t * 4];
    ss += v[p].x*v[p].x + v[p].y*v[p].y + v[p].z*v[p].z + v[p].w*v[p].w;
  }
#pragma unroll
  for (int off = 32; off >= 1; off >>= 1) ss += __shfl_xor(ss, off, 64);
  __shared__ float red[4];
  if ((t & 63) == 0) red[t >> 6] = ss;
  __syncthreads();
  const float tot = red[0] + red[1] + red[2] + red[3];
  const float rn = rsqrtf(tot * (1.f / DIM) + 1e-6f);
  unsigned short* yr = Y + (size_t)row * DIM;
#pragma unroll
  for (int p = 0; p < 4; ++p) {
    const float4 gv = *(const float4*)&gamma[p * 1024 + t * 4];
    short4 o;
    o.x = (short)f2b(v[p].x * gv.x * rn);
    o.y = (short)f2b(v[p].y * gv.y * rn);
    o.z = (short)f2b(v[p].z * gv.z * rn);
    o.w = (short)f2b(v[p].w * gv.w * rn);
    *(short4*)&yr[p * 1024 + t * 4] = o;
  }
}

// ---------------- RoPE in-place on bf16 [rows][NHT*128] ----------------
template<int NHT>
__global__ __launch_bounds__(256)
void rope_k(unsigned short* __restrict__ buf, const float* __restrict__ fr)
{
  const int u = blockIdx.x * 256 + threadIdx.x;
  const int per_row = NHT * 16;
  const int row  = u / per_row;
  const int rem  = u - row * per_row;
  const int head = rem >> 4;
  const int i4   = (rem & 15) << 2;
  const int s    = row & (SEQ - 1);
  unsigned short* p = buf + (size_t)row * (NHT * HD) + head * HD + i4 * 2;
  union { int4 v; unsigned short u16[8]; } d;
  d.v = *(const int4*)p;
  const float4 f = *(const float4*)&fr[s * 64 + i4];
  const float fa[4] = {f.x, f.y, f.z, f.w};
#pragma unroll
  for (int i = 0; i < 4; ++i) {
    float sn, c;
    __sincosf(fa[i], &sn, &c);
    const float x0 = b2f(d.u16[2*i]), x1 = b2f(d.u16[2*i+1]);
    d.u16[2*i]   = f2b(x0 * c - x1 * sn);
    d.u16[2*i+1] = f2b(x0 * sn + x1 * c);
  }
  *(int4*)p = d.v;
}

// ======================= 256x256 GEMM, 2 barriers / K=32 phase (round-6 proven) ===========
template<int MODE>
__global__ __launch_bounds__(512)
void gemm256(const unsigned short* __restrict__ A,
             const unsigned short* __restrict__ W,
             const unsigned short* __restrict__ W3p,
             const float* __restrict__ bias,
             const float* res,
             float* outF,
             unsigned short* __restrict__ outH,
             const unsigned short* __restrict__ wkp,
             const unsigned short* __restrict__ wvp,
             const float* __restrict__ bkp,
             const float* __restrict__ bvp,
             unsigned short* __restrict__ okp,
             unsigned short* __restrict__ ovp,
             int K)
{
  __shared__ __align__(16) char smem[131072];
  const int t = threadIdx.x, lane = t & 63, wid = t >> 6;
  const int wr = wid >> 2, wc = wid & 3;
  const int G = gridDim.x, bid = blockIdx.x;
  const int wg = (bid & 7) * (G >> 3) + (bid >> 3);   // XCD-chunked
  const int NBN = G >> 5;                             // NBM = 32 (M = 8192)
  const int span = NBN << 3;                          // TMG = 8
  const int tmg = wg / span, rr = wg - tmg * span;
  const int tn = rr >> 3, tm = (tmg << 3) + (rr & 7);
  const int m0 = tm << 8;
  const int NSUB = K >> 5;

  const unsigned short *P1, *P2;
  const float* bp = bias;
  unsigned short* oh = outH;
  int nloc = 0, colsN = 4096;
  if constexpr (MODE == 0) {
    const int n0 = tn << 8;
    if (n0 < 4096)      { nloc = n0;        P1 = W   + (size_t)nloc * K; bp = bias; oh = outH; colsN = 4096; }
    else if (n0 < 5120) { nloc = n0 - 4096; P1 = wkp + (size_t)nloc * K; bp = bkp;  oh = okp;  colsN = 1024; }
    else                { nloc = n0 - 5120; P1 = wvp + (size_t)nloc * K; bp = bvp;  oh = ovp;  colsN = 1024; }
    P2 = P1 + (size_t)128 * K;
  } else if constexpr (MODE == 3) {
    const int n0w = tn << 7;
    P1 = W   + (size_t)n0w * K;
    P2 = W3p + (size_t)n0w * K;
    nloc = n0w;
  } else {
    const int n0 = tn << 8;
    P1 = W + (size_t)n0 * K;
    P2 = P1 + (size_t)128 * K;
    nloc = n0;
  }

  const int r0 = t >> 2, gg = t & 3;
  const int gsw = gg ^ ((r0 >> 1) & 3);

  auto stA = [&](int sig) {
    if (sig < NSUB) {
      const int slot = sig & 3;
      gll16(A + (size_t)(m0 + r0) * K + sig * 32 + gsw * 8,
            smem + slot * 16384 + wid * 1024);
      gll16(A + (size_t)(m0 + 128 + r0) * K + sig * 32 + gsw * 8,
            smem + slot * 16384 + 8192 + wid * 1024);
    }
  };
  auto stB = [&](int sig) {
    if (sig < NSUB) {
      const int slot = sig & 3;
      gll16(P1 + (size_t)r0 * K + sig * 32 + gsw * 8,
            smem + 65536 + slot * 16384 + wid * 1024);
      gll16(P2 + (size_t)r0 * K + sig * 32 + gsw * 8,
            smem + 65536 + slot * 16384 + 8192 + wid * 1024);
    }
  };
  auto rdA = [&](int slot, int mo) -> bf16x8_t {
    const int lrow = wr * 128 + mo + (lane & 15);
    const int g = (lane >> 4) ^ ((lrow >> 1) & 3);
    return *(const bf16x8_t*)(smem + slot * 16384 + lrow * 64 + g * 16);
  };
  auto rdB = [&](int slot, int nf) -> bf16x8_t {
    const int brow = wc * 64 + nf * 16 + (lane & 15);
    const int g = (lane >> 4) ^ ((brow >> 1) & 3);
    return *(const bf16x8_t*)(smem + 65536 + slot * 16384 + brow * 64 + g * 16);
  };

  f32x4_t acc[8][4];
#pragma unroll
  for (int i = 0; i < 8; ++i)
#pragma unroll
    for (int j = 0; j < 4; ++j) acc[i][j] = (f32x4_t)0.f;

  stA(0); stB(0); stA(1); stB(1); stA(2); stB(2);
  VM8;
  __builtin_amdgcn_s_barrier();

  for (int p = 0; p < NSUB; ++p) {
    const int slot = p & 3;
    bf16x8_t bfv[4], afv[8];
#pragma unroll
    for (int n = 0; n < 4; ++n) bfv[n] = rdB(slot, n);
#pragma unroll
    for (int m = 0; m < 8; ++m) afv[m] = rdA(slot, m * 16);
    stA(p + 3); stB(p + 3);
    __builtin_amdgcn_s_setprio(1);
#pragma unroll
    for (int m = 0; m < 8; ++m)
#pragma unroll
      for (int n = 0; n < 4; ++n)
        acc[m][n] = __builtin_amdgcn_mfma_f32_16x16x32_bf16(afv[m], bfv[n], acc[m][n], 0, 0, 0);
    __builtin_amdgcn_s_setprio(0);
    if (p < NSUB - 3)      { VM8; }
    else if (p == NSUB - 3){ VM4M; }
    else                   { VM0; }
    __builtin_amdgcn_s_barrier();
  }

  if constexpr (MODE == 0) {
#pragma unroll
    for (int ni = 0; ni < 4; ++ni) {
      const int col = nloc + wc * 64 + ni * 16 + (lane & 15);
      const float bv = bp[col];
#pragma unroll
      for (int mi = 0; mi < 8; ++mi)
#pragma unroll
        for (int r = 0; r < 4; ++r) {
          const int row = m0 + wr * 128 + mi * 16 + (lane >> 4) * 4 + r;
          oh[(size_t)row * colsN + col] = f2b(acc[mi][ni][r] + bv);
        }
    }
  } else if constexpr (MODE == 1 || MODE == 2) {
#pragma unroll
    for (int ni = 0; ni < 4; ++ni) {
      const int col = nloc + wc * 64 + ni * 16 + (lane & 15);
      float bv = 0.f;
      if constexpr (MODE == 1) bv = bias[col];
#pragma unroll
      for (int mi = 0; mi < 8; ++mi)
#pragma unroll
        for (int r = 0; r < 4; ++r) {
          const int row = m0 + wr * 128 + mi * 16 + (lane >> 4) * 4 + r;
          const size_t idx = (size_t)row * 4096 + col;
          outF[idx] = acc[mi][ni][r] + bv + res[idx];
        }
    }
  } else {
    if (wc >= 2) {
      const int widx = wr * 2 + (wc - 2);
#pragma unroll
      for (int ni = 0; ni < 4; ++ni)
#pragma unroll
        for (int mi = 0; mi < 8; ++mi)
#pragma unroll
          for (int r = 0; r < 4; ++r) {
            const int lrow = mi * 16 + (lane >> 4) * 4 + r;
            const int ncol = ni * 16 + (lane & 15);
            *(unsigned short*)(smem + widx * 16384 + lrow * 128 + ncol * 2) =
                f2b(acc[mi][ni][r]);
          }
    }
    __syncthreads();
    if (wc < 2) {
      const int widx = wr * 2 + wc;
#pragma unroll
      for (int ni = 0; ni < 4; ++ni)
#pragma unroll
        for (int mi = 0; mi < 8; ++mi)
#pragma unroll
          for (int r = 0; r < 4; ++r) {
            const int lrow = mi * 16 + (lane >> 4) * 4 + r;
            const int ncol = ni * 16 + (lane & 15);
            const float s3 = b2f(*(const unsigned short*)(smem + widx * 16384 + lrow * 128 + ncol * 2));
            const float s1 = acc[mi][ni][r];
            const float sig = 1.f / (1.f + __expf(-s1));
            const int row = m0 + wr * 128 + lrow;
            outH[(size_t)row * FFNH + nloc + wc * 64 + ncol] = f2b(s1 * sig * s3);
          }
    }
  }
}

// ---------------- Flash attention: QBLK=128, 8 waves (round-14 proven) ----------------
// wo|w1|w3|w2 cvt interleaved into pairs 0..18 (hidden under pair latency; vmcnt
// ledger safe: pair p's loads are always >=5th-oldest at the VM4 wait).
__global__ __launch_bounds__(512, 4)
void attn_k(const unsigned short* __restrict__ Q, const unsigned short* __restrict__ Kb,
            const unsigned short* __restrict__ Vb, unsigned short* __restrict__ O,
            const float* __restrict__ woS, unsigned short* __restrict__ woD,
            const float* __restrict__ w1S, unsigned short* __restrict__ w1D,
            const float* __restrict__ w3S, unsigned short* __restrict__ w3D,
            const float* __restrict__ w2S, unsigned short* __restrict__ w2D)
{
  __shared__ unsigned short Ks[4][4096];   // ring-4 K tiles (32x128 swizzled) 32 KB
  __shared__ unsigned short Vt[2][4096];   // V^T pair                          16 KB
  __shared__ unsigned short Ps[5120];      // 8 waves x 16q x 32kv stride 40    10 KB
  const int t = threadIdx.x, lane = t & 63, wid = t >> 6;   // wid 0..7
  const int bx = blockIdx.x;
  const int qt = bx & 15, h = (bx >> 4) & 31, b = bx >> 9;
  const int kvh = h >> 2;
  const float rs = 0.08838834764831845f;   // 1/sqrt(128)
  constexpr int NPAIR = SEQ / 64;          // 32

  const int q0 = wid * 16;                 // 0..112
  const int qc = lane & 15;                // this lane's q (softmax layout)

  // Q fragments in registers: B-operand of swapped QK^T (issued first = oldest vmem)
  bf16x8_t qf[4];
  {
    const unsigned short* qrow = Q + (size_t)(b * SEQ + qt * 128 + q0 + qc) * DIM
                                   + h * HD + (lane >> 4) * 8;
#pragma unroll
    for (int ks = 0; ks < 4; ++ks) qf[ks] = *(const bf16x8_t*)(qrow + ks * 32);
  }

  const unsigned short* Kbase = Kb + (size_t)(b * SEQ) * (NKV * HD) + kvh * HD;
  const unsigned short* Vbase = Vb + (size_t)(b * SEQ) * (NKV * HD) + kvh * HD;

  auto stK = [&](int kt, int slot) {       // 512 threads x 16B = 8KB tile
    const int row = t >> 4;                // 0..31
    const int gl  = (t & 15) ^ (row & 7);  // pre-swizzled source granule
    gll16(Kbase + (size_t)(kt * 32 + row) * (NKV * HD) + gl * 8, &Ks[slot][(size_t)t * 8]);
  };
  const int kv = t >> 4;                   // 0..31
  const int d0 = (t & 15) * 8;             // 0..120 (8-row span, never crosses 16)
  const int colv = kv ^ (((d0 >> 4) & 3) << 3);
  auto ldV = [&](int kt, int4& w) {
    w = *(const int4*)(Vbase + (size_t)(kt * 32 + kv) * (NKV * HD) + d0);
  };
  auto wrV = [&](int slot, int4 w) {
    union { int4 v; unsigned short u[8]; } u; u.v = w;
#pragma unroll
    for (int j = 0; j < 8; ++j) Vt[slot][(d0 + j) * 32 + colv] = u.u[j];
  };

  // prologue: pair 0 (K slots 0,1) and pair 1 (K slots 2,3)
  int4 a0, a1, b0, b1;
  stK(0, 0); stK(1, 1); ldV(0, a0); ldV(1, a1);
  stK(2, 2); stK(3, 3); ldV(2, b0); ldV(3, b1);

  f32x4_t oa[8];
#pragma unroll
  for (int i = 0; i < 8; ++i) oa[i] = (f32x4_t)0.f;
  float mrun = -1e30f, lrun = 0.f;         // per-lane state for q = qc
  const int pbase = wid * 640 + qc * 40;   // Ps row base (stride-40 ushorts)
  const int pwr   = pbase + (lane >> 4) * 4;

  auto pack2 = [&](float x, float y) -> unsigned int {
    return (unsigned int)f2b(x) | ((unsigned int)f2b(y) << 16);
  };

  auto pairIter = [&](int p, int sb, int4& l0, int4& l1) {
    if (p == NPAIR - 1) { VM0; } else { VM4M; }   // pair p (and qf at p=0) landed
    wrV(0, l0);
    wrV(1, l1);
    asm volatile("s_waitcnt lgkmcnt(0)" ::: "memory");
    __builtin_amdgcn_s_barrier();                 // pair staged, visible to all waves

    // S^T: lane holds q=qc, 16 kv values; 16 MFMA
    f32x4_t st[4];
    st[0] = (f32x4_t)0.f; st[1] = (f32x4_t)0.f;
    st[2] = (f32x4_t)0.f; st[3] = (f32x4_t)0.f;
    const int kr0 = qc, kr1 = 16 + qc;
    __builtin_amdgcn_s_setprio(1);
#pragma unroll
    for (int ks = 0; ks < 4; ++ks) {
      const bf16x8_t k00 = *(const bf16x8_t*)&Ks[sb][(kr0 * 128 + ks * 32 + (lane >> 4) * 8) ^ ((kr0 & 7) << 3)];
      st[0] = __builtin_amdgcn_mfma_f32_16x16x32_bf16(k00, qf[ks], st[0], 0, 0, 0);
      const bf16x8_t k01 = *(const bf16x8_t*)&Ks[sb][(kr1 * 128 + ks * 32 + (lane >> 4) * 8) ^ ((kr1 & 7) << 3)];
      st[1] = __builtin_amdgcn_mfma_f32_16x16x32_bf16(k01, qf[ks], st[1], 0, 0, 0);
      const bf16x8_t k10 = *(const bf16x8_t*)&Ks[sb + 1][(kr0 * 128 + ks * 32 + (lane >> 4) * 8) ^ ((kr0 & 7) << 3)];
      st[2] = __builtin_amdgcn_mfma_f32_16x16x32_bf16(k10, qf[ks], st[2], 0, 0, 0);
      const bf16x8_t k11 = *(const bf16x8_t*)&Ks[sb + 1][(kr1 * 128 + ks * 32 + (lane >> 4) * 8) ^ ((kr1 & 7) << 3)];
      st[3] = __builtin_amdgcn_mfma_f32_16x16x32_bf16(k11, qf[ks], st[3], 0, 0, 0);
    }
    __builtin_amdgcn_s_setprio(0);

    // softmax: in-lane reduce + 2 shfl_xor
    float mx01 = fmaxf(fmaxf(st[0][0], st[0][1]), fmaxf(st[0][2], st[0][3]));
    float mx23 = fmaxf(fmaxf(st[1][0], st[1][1]), fmaxf(st[1][2], st[1][3]));
    float mx45 = fmaxf(fmaxf(st[2][0], st[2][1]), fmaxf(st[2][2], st[2][3]));
    float mx67 = fmaxf(fmaxf(st[3][0], st[3][1]), fmaxf(st[3][2], st[3][3]));
    float pm = fmaxf(fmaxf(mx01, mx23), fmaxf(mx45, mx67)) * rs;
    pm = fmaxf(pm, __shfl_xor(pm, 16, 64));
    pm = fmaxf(pm, __shfl_xor(pm, 32, 64));

    const int grow = __any(pm > mrun);
    if (grow) {
      const float mnew = fmaxf(mrun, pm);
      const float corr = __expf(mrun - mnew);
      mrun = mnew;
      lrun *= corr;
      float c4[4];
#pragma unroll
      for (int r = 0; r < 4; ++r) c4[r] = __shfl(corr, (lane >> 4) * 4 + r, 16);
#pragma unroll
      for (int i = 0; i < 8; ++i)
#pragma unroll
        for (int r = 0; r < 4; ++r) oa[i][r] *= c4[r];
    }

    float ssum = 0.f;
#pragma unroll
    for (int tt = 0; tt < 4; ++tt)
#pragma unroll
      for (int r = 0; r < 4; ++r) {
        st[tt][r] = __expf(st[tt][r] * rs - mrun);
        ssum += st[tt][r];
      }
    ssum += __shfl_xor(ssum, 16, 64);
    ssum += __shfl_xor(ssum, 32, 64);
    lrun += ssum;

    // P^T half 0 (kv 0..31): packed u32 writes, read pa0
    *(unsigned int*)&Ps[pwr]      = pack2(st[0][0], st[0][1]);
    *(unsigned int*)&Ps[pwr + 2]  = pack2(st[0][2], st[0][3]);
    *(unsigned int*)&Ps[pwr + 16] = pack2(st[1][0], st[1][1]);
    *(unsigned int*)&Ps[pwr + 18] = pack2(st[1][2], st[1][3]);
    const bf16x8_t pa0 = *(const bf16x8_t*)&Ps[pbase + (lane >> 4) * 8];
    asm volatile("s_waitcnt lgkmcnt(0)" ::: "memory");   // pa0 read drained (WAR guard)
    // P^T half 1 (kv 32..63) overwrites the same region, read pa1
    *(unsigned int*)&Ps[pwr]      = pack2(st[2][0], st[2][1]);
    *(unsigned int*)&Ps[pwr + 2]  = pack2(st[2][2], st[2][3]);
    *(unsigned int*)&Ps[pwr + 16] = pack2(st[3][0], st[3][1]);
    *(unsigned int*)&Ps[pwr + 18] = pack2(st[3][2], st[3][3]);
    const bf16x8_t pa1 = *(const bf16x8_t*)&Ps[pbase + (lane >> 4) * 8];

    __builtin_amdgcn_s_setprio(1);
#pragma unroll
    for (int nt2 = 0; nt2 < 8; ++nt2) {
      const bf16x8_t vf0 = *(const bf16x8_t*)&Vt[0][(nt2 * 16 + (lane & 15)) * 32 + (((lane >> 4) ^ (nt2 & 3)) << 3)];
      oa[nt2] = __builtin_amdgcn_mfma_f32_16x16x32_bf16(pa0, vf0, oa[nt2], 0, 0, 0);
      const bf16x8_t vf1 = *(const bf16x8_t*)&Vt[1][(nt2 * 16 + (lane & 15)) * 32 + (((lane >> 4) ^ (nt2 & 3)) << 3)];
      oa[nt2] = __builtin_amdgcn_mfma_f32_16x16x32_bf16(pa1, vf1, oa[nt2], 0, 0, 0);
    }
    __builtin_amdgcn_s_setprio(0);
    __builtin_amdgcn_s_barrier();                 // all waves done with Ks[sb..sb+1], Vt
    // interleaved weight cvt: pairs 0..12 = wo|w1|w3; pairs 13..18 = w2
    if (p < 13) {
      const size_t e = ((size_t)bx * 512 + t) * 8 + (size_t)p * 8388608ull;
      if (e < 106954752ull) {
        const float* src; unsigned short* dst; size_t o;
        if (e < 16777216ull)      { src = woS; dst = woD; o = e; }
        else if (e < 61865984ull) { src = w1S; dst = w1D; o = e - 16777216ull; }
        else                      { src = w3S; dst = w3D; o = e - 61865984ull; }
        const float4 va = *(const float4*)&src[o];
        const float4 vb = *(const float4*)&src[o + 4];
        union { int4 v; unsigned short u[8]; } ov;
        ov.u[0] = f2b(va.x); ov.u[1] = f2b(va.y); ov.u[2] = f2b(va.z); ov.u[3] = f2b(va.w);
        ov.u[4] = f2b(vb.x); ov.u[5] = f2b(vb.y); ov.u[6] = f2b(vb.z); ov.u[7] = f2b(vb.w);
        *(int4*)&dst[o] = ov.v;
      }
    } else if (p < 19 && w2S) {
      const size_t o = ((size_t)bx * 512 + t) * 8 + (size_t)(p - 13) * 8388608ull;
      if (o < 45088768ull) {
        const float4 va = *(const float4*)&w2S[o];
        const float4 vb = *(const float4*)&w2S[o + 4];
        union { int4 v; unsigned short u[8]; } ov;
        ov.u[0] = f2b(va.x); ov.u[1] = f2b(va.y); ov.u[2] = f2b(va.z); ov.u[3] = f2b(va.w);
        ov.u[4] = f2b(vb.x); ov.u[5] = f2b(vb.y); ov.u[6] = f2b(vb.z); ov.u[7] = f2b(vb.w);
        *(int4*)&w2D[o] = ov.v;
      }
    }
    if (p + 2 < NPAIR) {
      stK(2 * p + 4, sb);     stK(2 * p + 5, sb + 1);
      ldV(2 * p + 4, l0);     ldV(2 * p + 5, l1);
    }
  };

  for (int j = 0; j < NPAIR / 2; ++j) {
    pairIter(2 * j,     0, a0, a1);
    pairIter(2 * j + 1, 2, b0, b1);
  }

  // broadcast l (q-layout) into oa row layout, normalize, store
  float inv[4];
#pragma unroll
  for (int r = 0; r < 4; ++r) inv[r] = 1.f / __shfl(lrun, (lane >> 4) * 4 + r, 16);
#pragma unroll
  for (int nt2 = 0; nt2 < 8; ++nt2) {
    const int col = h * HD + nt2 * 16 + (lane & 15);
#pragma unroll
    for (int r = 0; r < 4; ++r) {
      const int row = qt * 128 + q0 + (lane >> 4) * 4 + r;
      O[(size_t)(b * SEQ + row) * DIM + col] = f2b(oa[nt2][r] * inv[r]);
    }
  }
}

// ---------------- launch ----------------
extern "C" void kernel_launch(void* const* d_in, const int* in_sizes, int n_in,
                              void* d_out, int out_size, void* d_ws, size_t ws_size,
                              hipStream_t stream)
{
  (void)in_sizes; (void)n_in; (void)out_size;
  const float* x   = (const float*)d_in[0];
  const float* fr  = (const float*)d_in[1];
  const float* ga  = (const float*)d_in[3];
  const float* gf  = (const float*)d_in[4];
  const float* wq  = (const float*)d_in[5];
  const float* wqb = (const float*)d_in[6];
  const float* wk  = (const float*)d_in[7];
  const float* wkb = (const float*)d_in[8];
  const float* wv  = (const float*)d_in[9];
  const float* wvb = (const float*)d_in[10];
  const float* wo  = (const float*)d_in[11];
  const float* wob = (const float*)d_in[12];
  const float* w1  = (const float*)d_in[13];
  const float* w3  = (const float*)d_in[14];
  const float* w2  = (const float*)d_in[15];
  float* out = (float*)d_out;

  constexpr size_t MB = 1ull << 20;
  char* ws = (char*)d_ws;
  unsigned short* xn = (unsigned short*)(ws);              // [0,64) MiB
  unsigned short* qb = (unsigned short*)(ws + 64*MB);      // [64,128)
  unsigned short* kb = (unsigned short*)(ws + 128*MB);     // [128,144)
  unsigned short* vb = (unsigned short*)(ws + 144*MB);     // [144,160)
  unsigned short* ao = (unsigned short*)(ws + 160*MB);     // [160,224)
  unsigned short* hn = (unsigned short*)(ws + 224*MB);     // [224,288)
  unsigned short* g  = (unsigned short*)(ws);              // [0,172) alias (dead by FFN time)
  unsigned short* wscr = (unsigned short*)(ws + 288*MB);   // JIT bf16 weights
  unsigned short* wqB = wscr;                               // bytes [288,320)
  unsigned short* wkB = wscr + 16*MB;                       // bytes [320,328)
  unsigned short* wvB = wscr + 20*MB;                       // bytes [328,336)
  unsigned short* woB = (unsigned short*)(ws);              // 32 MiB, in dead xn (attn fills)
  unsigned short* w1B = wscr;                               // bytes [288,374) (attn fills)
  unsigned short* w3B = wscr + 46*MB;                       // bytes [380,466) (attn fills)
  const bool bigws = ws_size >= 560ull * MB;
  unsigned short* w2B = bigws ? (unsigned short*)(ws + 466*MB)  // bytes [466,552) (attn fills)
                              : wscr;                           // alias w1B (dedicated cvt after w13)

  rmsnorm_k<<<MTOT, 256, 0, stream>>>(x, ga, xn);
  cvt_bf16_k<<<(NH*HD*DIM)/2048,  256, 0, stream>>>(wq, wqB);
  cvt_bf16_k<<<(NKV*HD*DIM)/2048, 256, 0, stream>>>(wk, wkB);
  cvt_bf16_k<<<(NKV*HD*DIM)/2048, 256, 0, stream>>>(wv, wvB);
  gemm256<0><<<(MTOT/256)*((DIM+2*NKV*HD)/256), 512, 0, stream>>>(
      xn, wqB, nullptr, wqb, nullptr, nullptr, qb,
      wkB, wvB, wkb, wvb, kb, vb, DIM);
  rope_k<NH><<<(MTOT*NH*16)/256,  256, 0, stream>>>(qb, fr);
  rope_k<NKV><<<(MTOT*NKV*16)/256,256, 0, stream>>>(kb, fr);
  attn_k<<<BATCH*NH*(SEQ/128), 512, 0, stream>>>(qb, kb, vb, ao,
      wo, woB, w1, w1B, w3, w3B,
      bigws ? w2 : nullptr, bigws ? w2B : nullptr);
  gemm256<1><<<(MTOT/256)*(DIM/256), 512, 0, stream>>>(
      ao, woB, nullptr, wob, x, out, nullptr,
      nullptr, nullptr, nullptr, nullptr, nullptr, nullptr, DIM);
  rmsnorm_k<<<MTOT, 256, 0, stream>>>(out, gf, hn);
  gemm256<3><<<(MTOT/256)*(FFNH/128), 512, 0, stream>>>(
      hn, w1B, w3B, nullptr, nullptr, nullptr, g,
      nullptr, nullptr, nullptr, nullptr, nullptr, nullptr, DIM);
  if (!bigws)
    cvt_bf16_k<<<(FFNH*DIM)/2048, 256, 0, stream>>>(w2, w2B);
  gemm256<2><<<(MTOT/256)*(DIM/256), 512, 0, stream>>>(
      g, w2B, nullptr, nullptr, out, out, nullptr,
      nullptr, nullptr, nullptr, nullptr, nullptr, nullptr, FFNH);
}